// Round 8
// baseline (414.206 us; speedup 1.0000x reference)
//
#include <hip/hip_runtime.h>
#include <cstdint>
#include <cstddef>

#define NN 100000
#define EE 1000000
#define EPSF 1e-5f
#define NBUK 391          // node buckets per relation: ceil(100000/256), dst>>8
#define NBUK2 (2*NBUK)    // both relations
#define NBLK 256          // edge-chunk blocks for hist/binscatter
#define EPB 7813          // ceil(2*EE / NBLK)
#define GSB 782           // scan blocks over NBUK2*NBLK entries (=200192/256)
#define GTILES ((NN + 63) / 64)   // 1563 64-node GEMM tiles
#define GTILES32 ((NN + 31) / 32) // 3125 32-node GEMM tiles

__device__ __forceinline__ void fatomic(float* p, float v) { unsafeAtomicAdd(p, v); }

// edge slot s in [0,2EE): rel 0 = pos, rel 1 = neg
__device__ __forceinline__ void edge_of(const int* __restrict__ pe, const int* __restrict__ ne,
                                        int s, int& src, int& dst, int& bucket) {
    if (s < EE) { src = pe[s]; dst = pe[EE + s]; bucket = dst >> 8; }
    else        { src = ne[s - EE]; dst = ne[s]; bucket = NBUK + (dst >> 8); }
}

// ---- pass 1: per-block bucket histogram ----
__global__ __launch_bounds__(256) void k_hist(const int* __restrict__ pe,
                                              const int* __restrict__ ne,
                                              int* __restrict__ hist) {
    __shared__ int lh[NBUK2];
    for (int i = threadIdx.x; i < NBUK2; i += 256) lh[i] = 0;
    __syncthreads();
    int start = blockIdx.x * EPB, end = min(start + EPB, 2 * EE);
    for (int s = start + threadIdx.x; s < end; s += 256) {
        int src, dst, bucket;
        edge_of(pe, ne, s, src, dst, bucket);
        atomicAdd(&lh[bucket], 1);
    }
    __syncthreads();
    for (int i = threadIdx.x; i < NBUK2; i += 256)
        hist[i * NBLK + blockIdx.x] = lh[i];   // bucket-major
}

// ---- generic hierarchical exclusive scan over NBUK2*NBLK ints ----
__global__ __launch_bounds__(256) void k_gscan1(const int* __restrict__ in,
                                                int* __restrict__ out,
                                                int* __restrict__ partials) {
    int i = blockIdx.x * 256 + threadIdx.x;
    int v = in[i];
    __shared__ int s[256];
    s[threadIdx.x] = v;
    __syncthreads();
    for (int off = 1; off < 256; off <<= 1) {
        int u = (threadIdx.x >= off) ? s[threadIdx.x - off] : 0;
        __syncthreads();
        s[threadIdx.x] += u;
        __syncthreads();
    }
    out[i] = s[threadIdx.x] - v;
    if (threadIdx.x == 255) partials[blockIdx.x] = s[255];
}

__global__ __launch_bounds__(1024) void k_gscan2(int* __restrict__ partials) {
    __shared__ int s[1024];
    int v = (threadIdx.x < GSB) ? partials[threadIdx.x] : 0;
    s[threadIdx.x] = v;
    __syncthreads();
    for (int off = 1; off < 1024; off <<= 1) {
        int u = (threadIdx.x >= off) ? s[threadIdx.x - off] : 0;
        __syncthreads();
        s[threadIdx.x] += u;
        __syncthreads();
    }
    if (threadIdx.x < GSB) partials[threadIdx.x] = s[threadIdx.x] - v;
}

__global__ __launch_bounds__(256) void k_gscan3(const int* __restrict__ partials,
                                                int* __restrict__ out) {
    out[blockIdx.x * 256 + threadIdx.x] += partials[blockIdx.x];
}

// ---- pass 2: scatter edges into bucket-grouped staging (block-exclusive runs) ----
__global__ __launch_bounds__(256) void k_binscatter(const int* __restrict__ pe,
                                                    const int* __restrict__ ne,
                                                    const int* __restrict__ soff,
                                                    unsigned long long* __restrict__ staging) {
    __shared__ int cur[NBUK2];
    for (int i = threadIdx.x; i < NBUK2; i += 256)
        cur[i] = soff[i * NBLK + blockIdx.x];
    __syncthreads();
    int start = blockIdx.x * EPB, end = min(start + EPB, 2 * EE);
    for (int s = start + threadIdx.x; s < end; s += 256) {
        int src, dst, bucket;
        edge_of(pe, ne, s, src, dst, bucket);
        int pos = atomicAdd(&cur[bucket], 1);
        staging[pos] = ((unsigned long long)(unsigned)dst << 32) | (unsigned)src;
    }
}

// ---- pass 3: per-bucket local build: rp (degree+scan in LDS) + csr scatter ----
__global__ __launch_bounds__(256) void k_local(const unsigned long long* __restrict__ staging,
                                               const int* __restrict__ soff,
                                               int* __restrict__ rpP,
                                               int* __restrict__ rpN,
                                               int* __restrict__ csrAll) {
    int bucket = blockIdx.x;
    int rel = bucket >= NBUK;
    int nodeBase = (bucket - rel * NBUK) << 8;
    int bstart = soff[bucket * NBLK];
    int bend = (bucket == NBUK2 - 1) ? 2 * EE : soff[(bucket + 1) * NBLK];
    int tid = threadIdx.x;
    __shared__ int deg[256], sc[256];
    deg[tid] = 0;
    __syncthreads();
    for (int i = bstart + tid; i < bend; i += 256) {
        int d = (int)(staging[i] >> 32) & 255;
        atomicAdd(&deg[d], 1);
    }
    __syncthreads();
    int dv = deg[tid];
    sc[tid] = dv;
    __syncthreads();
    for (int off = 1; off < 256; off <<= 1) {
        int u = (tid >= off) ? sc[tid - off] : 0;
        __syncthreads();
        sc[tid] += u;
        __syncthreads();
    }
    int lrp = sc[tid] - dv;  // bucket-local exclusive prefix
    int nCount = min(256, NN - nodeBase);
    int relbase = rel ? EE : 0;
    if (tid < nCount) (rel ? rpN : rpP)[nodeBase + tid] = bstart - relbase + lrp;
    if (bucket == NBUK - 1 && tid == 0) rpP[NN] = EE;
    if (bucket == NBUK2 - 1 && tid == 0) rpN[NN] = EE;
    deg[tid] = lrp;          // reuse as cursor
    __syncthreads();
    for (int i = bstart + tid; i < bend; i += 256) {
        unsigned long long v = staging[i];
        int d = (int)(v >> 32) & 255;
        int src = (int)(v & 0xffffffffu);
        int slot = atomicAdd(&deg[d], 1);
        csrAll[bstart + slot] = src;
    }
}

// ---- pre-transform 64->32 x3: xp=x@Wp, xn=x@Wn, xs=x@Ws ----
__global__ __launch_bounds__(256) void k_xf1(const float* __restrict__ x,
                                             const float* __restrict__ Wp,
                                             const float* __restrict__ Wn,
                                             const float* __restrict__ Ws,
                                             float* __restrict__ xp,
                                             float* __restrict__ xn,
                                             float* __restrict__ xs) {
    __shared__ float sWp[64 * 32], sWn[64 * 32], sWs[64 * 32];
    for (int i = threadIdx.x; i < 64 * 32; i += 256) { sWp[i] = Wp[i]; sWn[i] = Wn[i]; sWs[i] = Ws[i]; }
    __syncthreads();
    int lane = threadIdx.x & 63;
    int j = lane & 31;
    int half = lane >> 5;
    int wid = (blockIdx.x * 256 + threadIdx.x) >> 6;
    const int nw = (2048 * 256) >> 6;
    for (int p = wid; 2 * p < NN; p += nw) {
        int n = 2 * p + half;
        float vlo = x[(size_t)n * 64 + j];
        float vhi = x[(size_t)n * 64 + 32 + j];
        float ap = 0.f, an = 0.f, as = 0.f;
        #pragma unroll
        for (int k = 0; k < 64; k++) {
            float xv = (k < 32) ? __shfl(vlo, k, 32) : __shfl(vhi, k - 32, 32);
            ap += xv * sWp[k * 32 + j];
            an += xv * sWn[k * 32 + j];
            as += xv * sWs[k * 32 + j];
        }
        xp[(size_t)n * 32 + j] = ap;
        xn[(size_t)n * 32 + j] = an;
        xs[(size_t)n * 32 + j] = as;
    }
}

// ---- pre-transform 32->32 x3 ----
__global__ __launch_bounds__(256) void k_xf2(const float* __restrict__ z,
                                             const float* __restrict__ Wp,
                                             const float* __restrict__ Wn,
                                             const float* __restrict__ Ws,
                                             float* __restrict__ xp,
                                             float* __restrict__ xn,
                                             float* __restrict__ xs) {
    __shared__ float sWp[32 * 32], sWn[32 * 32], sWs[32 * 32];
    for (int i = threadIdx.x; i < 32 * 32; i += 256) { sWp[i] = Wp[i]; sWn[i] = Wn[i]; sWs[i] = Ws[i]; }
    __syncthreads();
    int lane = threadIdx.x & 63;
    int j = lane & 31;
    int half = lane >> 5;
    int wid = (blockIdx.x * 256 + threadIdx.x) >> 6;
    const int nw = (2048 * 256) >> 6;
    for (int p = wid; 2 * p < NN; p += nw) {
        int n = 2 * p + half;
        float v = z[(size_t)n * 32 + j];
        float ap = 0.f, an = 0.f, as = 0.f;
        #pragma unroll
        for (int k = 0; k < 32; k++) {
            float xv = __shfl(v, k, 32);
            ap += xv * sWp[k * 32 + j];
            an += xv * sWn[k * 32 + j];
            as += xv * sWs[k * 32 + j];
        }
        xp[(size_t)n * 32 + j] = ap;
        xn[(size_t)n * 32 + j] = an;
        xs[(size_t)n * 32 + j] = as;
    }
}

// ---- accumulate one relation's neighbors ----
__device__ __forceinline__ float pull_rel(const float* __restrict__ xsrc,
                                          const int* __restrict__ csr,
                                          int b0, int b1, int j, float acc) {
    for (int base = b0; base < b1; base += 32) {
        int rem = b1 - base;
        int cnt = min(rem, 32);
        int idx = (j < rem) ? csr[base + j] : 0;
        int i = 0;
        for (; i + 4 <= cnt; i += 4) {
            int s0 = __shfl(idx, i, 32);
            int s1 = __shfl(idx, i + 1, 32);
            int s2 = __shfl(idx, i + 2, 32);
            int s3 = __shfl(idx, i + 3, 32);
            float v0 = xsrc[(size_t)s0 * 32 + j];
            float v1 = xsrc[(size_t)s1 * 32 + j];
            float v2 = xsrc[(size_t)s2 * 32 + j];
            float v3 = xsrc[(size_t)s3 * 32 + j];
            acc += v0; acc += v1; acc += v2; acc += v3;
        }
        for (; i < cnt; i++) {
            int s = __shfl(idx, i, 32);
            acc += xsrc[(size_t)s * 32 + j];
        }
    }
    return acc;
}

// ---- pull aggregation + combine + tanh ----
__global__ __launch_bounds__(256) void k_pull(const float* __restrict__ xp,
                                              const float* __restrict__ xn,
                                              const float* __restrict__ xs,
                                              const int* __restrict__ rpP,
                                              const int* __restrict__ csrP,
                                              const int* __restrict__ rpN,
                                              const int* __restrict__ csrN,
                                              const float* __restrict__ bp,
                                              const float* __restrict__ bn,
                                              const float* __restrict__ bs,
                                              float* __restrict__ out) {
    int j = threadIdx.x & 31;
    int hw = (blockIdx.x * 256 + threadIdx.x) >> 5;
    const int nhw = (2048 * 256) >> 5;
    float bpj = bp[j], bnj = bn[j], bsj = bs[j];
    for (int n = hw; n < NN; n += nhw) {
        int p0 = rpP[n], p1 = rpP[n + 1];
        int n0 = rpN[n], n1 = rpN[n + 1];
        float acc = xs[(size_t)n * 32 + j] + bsj
                  + (float)(p1 - p0) * bpj + (float)(n1 - n0) * bnj;
        acc = pull_rel(xp, csrP, p0, p1, j, acc);
        acc = pull_rel(xn, csrN, n0, n1, j, acc);
        out[(size_t)n * 32 + j] = tanhf(acc);
    }
}

// ---- fused tiled GEMM: z = tanh(z2@Wl + bl) [N,64], t1 = z@W1 + b1, BN stats ----
// one block per 64-node tile; lane = output col; W cols in VGPRs; X via LDS broadcast
// sz is per-wave (same-wave producer/consumer) -> only 4*64 floats
__global__ __launch_bounds__(256) void k_wlin_mlp1(const float* __restrict__ z2,
                                                   const float* __restrict__ Wl,
                                                   const float* __restrict__ bl,
                                                   const float* __restrict__ W1,
                                                   const float* __restrict__ b1_,
                                                   float* __restrict__ z,
                                                   float* __restrict__ t1,
                                                   float* __restrict__ colsum,
                                                   float* __restrict__ colsq) {
    __shared__ float sx[64 * 32];   // z2 tile (8KB)
    __shared__ float sz[4 * 64];    // per-wave z-row bounce (1KB)
    __shared__ float red[256], red2[256];
    int base = blockIdx.x * 64;
    int tid = threadIdx.x;
    int lane = tid & 63;
    int wv = tid >> 6;
    // stage z2 tile: 64 rows x 32 cols, coalesced float4; zero OOB rows
    {
        int row = tid >> 2, c4 = tid & 3;   // 4 threads/row, 2 float4 each
        int n = base + row;
        #pragma unroll
        for (int m = 0; m < 2; m++) {
            int f = c4 + 4 * m;             // float4 index 0..7
            float4 v = (n < NN) ? *(const float4*)&z2[(size_t)n * 32 + f * 4]
                                : make_float4(0.f, 0.f, 0.f, 0.f);
            *(float4*)&sx[row * 32 + f * 4] = v;
        }
    }
    float wl[32];
    #pragma unroll
    for (int k = 0; k < 32; k++) wl[k] = Wl[k * 64 + lane];
    float w1[64];
    #pragma unroll
    for (int k = 0; k < 64; k++) w1[k] = W1[k * 64 + lane];
    float blj = bl[lane], b1j = b1_[lane];
    __syncthreads();
    float lsum = 0.f, lsq = 0.f;
    #pragma unroll 1
    for (int i = 0; i < 16; i++) {
        int nl = i * 4 + wv;
        int n = base + nl;
        float a0 = 0.f, a1c = 0.f, a2 = 0.f, a3 = 0.f;
        #pragma unroll
        for (int q = 0; q < 8; q++) {
            float4 xv = *(const float4*)&sx[nl * 32 + q * 4];
            a0 += xv.x * wl[q * 4 + 0];
            a1c += xv.y * wl[q * 4 + 1];
            a2 += xv.z * wl[q * 4 + 2];
            a3 += xv.w * wl[q * 4 + 3];
        }
        float zv = tanhf(blj + ((a0 + a1c) + (a2 + a3)));
        if (n < NN) z[(size_t)n * 64 + lane] = zv;
        sz[wv * 64 + lane] = zv;            // same-wave bounce (no barrier needed)
        float t0 = 0.f, t1a = 0.f, t2a = 0.f, t3a = 0.f;
        #pragma unroll
        for (int q = 0; q < 16; q++) {
            float4 zv4 = *(const float4*)&sz[wv * 64 + q * 4];
            t0 += zv4.x * w1[q * 4 + 0];
            t1a += zv4.y * w1[q * 4 + 1];
            t2a += zv4.z * w1[q * 4 + 2];
            t3a += zv4.w * w1[q * 4 + 3];
        }
        float t = b1j + ((t0 + t1a) + (t2a + t3a));
        if (n < NN) {
            t1[(size_t)n * 64 + lane] = t;
            lsum += t; lsq += t * t;
        }
    }
    red[tid] = lsum; red2[tid] = lsq;
    __syncthreads();
    if (tid < 64) {
        float a = red[tid] + red[tid + 64] + red[tid + 128] + red[tid + 192];
        float q = red2[tid] + red2[tid + 64] + red2[tid + 128] + red2[tid + 192];
        fatomic(&colsum[tid], a);
        fatomic(&colsq[tid], q);
    }
}

// ---- BN stats -> affine coefficients a, c (h_norm = t*a + c) ----
__global__ void k_bnstats(const float* __restrict__ colsum, const float* __restrict__ colsq,
                          const float* __restrict__ g, const float* __restrict__ beta,
                          float* __restrict__ a, float* __restrict__ c) {
    int j = threadIdx.x;
    if (j < 64) {
        float m = colsum[j] * (1.f / NN);
        float v = colsq[j] * (1.f / NN) - m * m;
        float aj = g[j] * rsqrtf(v + EPSF);
        a[j] = aj;
        c[j] = beta[j] - m * aj;
    }
}

// ---- tiled GEMM: t2 = relu(t1*a1+c1) @ m2_W + m2_b, BN stats; 32-row tiles for occupancy ----
__global__ __launch_bounds__(256) void k_mlp2(const float* __restrict__ t1,
                                              const float* __restrict__ a1,
                                              const float* __restrict__ c1,
                                              const float* __restrict__ W,
                                              const float* __restrict__ b,
                                              float* __restrict__ t2,
                                              float* __restrict__ colsum,
                                              float* __restrict__ colsq) {
    __shared__ float sh[32 * 64];   // h tile = relu(t1*a+c) (8KB)
    __shared__ float red[256], red2[256];
    int base = blockIdx.x * 32;
    int tid = threadIdx.x;
    int lane = tid & 63;
    int wv = tid >> 6;
    {
        int row = tid >> 3, c8 = tid & 7;   // 8 threads/row, 2 float4 each
        int n = base + row;
        #pragma unroll
        for (int m = 0; m < 2; m++) {
            int f = c8 + 8 * m;             // float4 index 0..15
            float4 tv = (n < NN) ? *(const float4*)&t1[(size_t)n * 64 + f * 4]
                                 : make_float4(0.f, 0.f, 0.f, 0.f);
            float4 av = *(const float4*)&a1[f * 4];
            float4 cv = *(const float4*)&c1[f * 4];
            float4 hv;
            hv.x = fmaxf(tv.x * av.x + cv.x, 0.f);
            hv.y = fmaxf(tv.y * av.y + cv.y, 0.f);
            hv.z = fmaxf(tv.z * av.z + cv.z, 0.f);
            hv.w = fmaxf(tv.w * av.w + cv.w, 0.f);
            *(float4*)&sh[row * 64 + f * 4] = hv;
        }
    }
    float w[64];
    #pragma unroll
    for (int k = 0; k < 64; k++) w[k] = W[k * 64 + lane];
    float bj = b[lane];
    __syncthreads();
    float lsum = 0.f, lsq = 0.f;
    #pragma unroll 1
    for (int i = 0; i < 8; i++) {
        int nl = i * 4 + wv;
        int n = base + nl;
        float a0 = 0.f, a1c = 0.f, a2 = 0.f, a3 = 0.f;
        #pragma unroll
        for (int q = 0; q < 16; q++) {
            float4 xv = *(const float4*)&sh[nl * 64 + q * 4];
            a0 += xv.x * w[q * 4 + 0];
            a1c += xv.y * w[q * 4 + 1];
            a2 += xv.z * w[q * 4 + 2];
            a3 += xv.w * w[q * 4 + 3];
        }
        float s = bj + ((a0 + a1c) + (a2 + a3));
        if (n < NN) {
            t2[(size_t)n * 64 + lane] = s;
            lsum += s; lsq += s * s;
        }
    }
    red[tid] = lsum; red2[tid] = lsq;
    __syncthreads();
    if (tid < 64) {
        float a = red[tid] + red[tid + 64] + red[tid + 128] + red[tid + 192];
        float q = red2[tid] + red2[tid + 64] + red2[tid + 128] + red2[tid + 192];
        fatomic(&colsum[tid], a);
        fatomic(&colsq[tid], q);
    }
}

// ---- prob = sigmoid(relu(t2*a2+c2) @ m3_W + m3_b) ----
__global__ __launch_bounds__(256) void k_mlp3(const float* __restrict__ t2,
                                              const float* __restrict__ a2,
                                              const float* __restrict__ c2,
                                              const float* __restrict__ W3,
                                              const float* __restrict__ b3,
                                              float* __restrict__ prob) {
    int j = threadIdx.x & 63;
    int r = threadIdx.x >> 6;
    float aj = a2[j], cj = c2[j], wj = W3[j], bb = b3[0];
    for (int n = blockIdx.x * 4 + r; n < NN; n += 2048 * 4) {
        float h = fmaxf(t2[(size_t)n * 64 + j] * aj + cj, 0.f) * wj;
        #pragma unroll
        for (int off = 32; off > 0; off >>= 1) h += __shfl_xor(h, off, 64);
        if (j == 0) prob[n] = 1.f / (1.f + expf(-(h + bb)));
    }
}

extern "C" void kernel_launch(void* const* d_in, const int* in_sizes, int n_in,
                              void* d_out, int out_size, void* d_ws, size_t ws_size,
                              hipStream_t stream) {
    const float* init_emb = (const float*)d_in[0];
    const int* pe = (const int*)d_in[1];
    const int* ne = (const int*)d_in[2];
    const float* c1_Wp = (const float*)d_in[3];  const float* c1_bp = (const float*)d_in[4];
    const float* c1_Wn = (const float*)d_in[5];  const float* c1_bn = (const float*)d_in[6];
    const float* c1_Ws = (const float*)d_in[7];  const float* c1_bs = (const float*)d_in[8];
    const float* c2_Wp = (const float*)d_in[9];  const float* c2_bp = (const float*)d_in[10];
    const float* c2_Wn = (const float*)d_in[11]; const float* c2_bn = (const float*)d_in[12];
    const float* c2_Ws = (const float*)d_in[13]; const float* c2_bs = (const float*)d_in[14];
    const float* w_W = (const float*)d_in[15];   const float* w_b = (const float*)d_in[16];
    const float* m1_W = (const float*)d_in[17];  const float* m1_b = (const float*)d_in[18];
    const float* g1 = (const float*)d_in[19];    const float* b1 = (const float*)d_in[20];
    const float* m2_W = (const float*)d_in[21];  const float* m2_b = (const float*)d_in[22];
    const float* g2 = (const float*)d_in[23];    const float* b2 = (const float*)d_in[24];
    const float* m3_W = (const float*)d_in[25];  const float* m3_b = (const float*)d_in[26];

    // ---- workspace arena ----
    size_t off = 0;
    auto alloc = [&](size_t bytes) -> void* {
        void* r = (char*)d_ws + off;
        off += (bytes + 255) & ~(size_t)255;
        return r;
    };
    // zero region (front): only BN stat accumulators
    float* sums = (float*)alloc(256 * 4);               // colsum1, colsq1, colsum2, colsq2
    size_t zero_bytes = off;
    // CSR-build region (dead after second k_pull; t2 aliases it later)
    size_t csr_region = off;
    int*   hist = (int*)alloc((size_t)NBUK2 * NBLK * 4);        // 800KB
    int*   soff = (int*)alloc((size_t)NBUK2 * NBLK * 4);        // 800KB
    int*   part = (int*)alloc((size_t)1024 * 4);
    unsigned long long* staging = (unsigned long long*)alloc((size_t)2 * EE * 8);  // 16MB
    int*   csrAll = (int*)alloc((size_t)2 * EE * 4);            // 8MB
    // persistent
    int*   rpP  = (int*)alloc((size_t)(NN + 1) * 4);
    int*   rpN  = (int*)alloc((size_t)(NN + 1) * 4);
    float* R1   = (float*)alloc((size_t)NN * 96 * 4);   // {xp,xn,xs} layer1 -> layer2 -> t1
    float* z1   = (float*)alloc((size_t)NN * 32 * 4);
    float* z2   = (float*)alloc((size_t)NN * 32 * 4);
    float* abc  = (float*)alloc(256 * 4);               // a1, c1, a2, c2

    int* csrP = csrAll;
    int* csrN = csrAll + (size_t)EE;
    float* xp = R1;
    float* xn = R1 + (size_t)NN * 32;
    float* xs = R1 + (size_t)NN * 64;
    float* t1 = R1;                                     // dead xp/xn region after wlin
    float* t2 = (float*)((char*)d_ws + csr_region);     // aliases CSR-build scratch (25.6MB fits)

    float* z_out = (float*)d_out;                       // [N,64]
    float* prob  = (float*)d_out + (size_t)NN * 64;     // [N,1]

    hipMemsetAsync(d_ws, 0, zero_bytes, stream);

    // ---- CSR build: hist -> scan -> bin scatter -> per-bucket local build ----
    k_hist<<<NBLK, 256, 0, stream>>>(pe, ne, hist);
    k_gscan1<<<GSB, 256, 0, stream>>>(hist, soff, part);
    k_gscan2<<<1, 1024, 0, stream>>>(part);
    k_gscan3<<<GSB, 256, 0, stream>>>(part, soff);
    k_binscatter<<<NBLK, 256, 0, stream>>>(pe, ne, soff, staging);
    k_local<<<NBUK2, 256, 0, stream>>>(staging, soff, rpP, rpN, csrAll);

    // layer 1
    k_xf1<<<2048, 256, 0, stream>>>(init_emb, c1_Wp, c1_Wn, c1_Ws, xp, xn, xs);
    k_pull<<<2048, 256, 0, stream>>>(xp, xn, xs, rpP, csrP, rpN, csrN, c1_bp, c1_bn, c1_bs, z1);
    // layer 2
    k_xf2<<<2048, 256, 0, stream>>>(z1, c2_Wp, c2_Wn, c2_Ws, xp, xn, xs);
    k_pull<<<2048, 256, 0, stream>>>(xp, xn, xs, rpP, csrP, rpN, csrN, c2_bp, c2_bn, c2_bs, z2);
    // readout
    k_wlin_mlp1<<<GTILES, 256, 0, stream>>>(z2, w_W, w_b, m1_W, m1_b, z_out, t1, sums + 0, sums + 64);
    k_bnstats<<<1, 64, 0, stream>>>(sums + 0, sums + 64, g1, b1, abc + 0, abc + 64);
    k_mlp2<<<GTILES32, 256, 0, stream>>>(t1, abc + 0, abc + 64, m2_W, m2_b, t2, sums + 128, sums + 192);
    k_bnstats<<<1, 64, 0, stream>>>(sums + 128, sums + 192, g2, b2, abc + 128, abc + 192);
    k_mlp3<<<2048, 256, 0, stream>>>(t2, abc + 128, abc + 192, m3_W, m3_b, prob);
}

// Round 9
// 412.293 us; speedup vs baseline: 1.0046x; 1.0046x over previous
//
#include <hip/hip_runtime.h>
#include <cstdint>
#include <cstddef>

#define NN 100000
#define EE 1000000
#define EPSF 1e-5f
#define NBUK 391          // node buckets per relation: ceil(100000/256), dst>>8
#define NBUK2 (2*NBUK)    // both relations
#define NBLK 256          // edge-chunk blocks for hist/binscatter
#define EPB 7813          // ceil(2*EE / NBLK)
#define GSB 782           // scan blocks over NBUK2*NBLK entries (=200192/256)
#define GTILES ((NN + 63) / 64)   // 1563 64-node GEMM tiles
#define GTILES32 ((NN + 31) / 32) // 3125 32-node GEMM tiles

__device__ __forceinline__ void fatomic(float* p, float v) { unsafeAtomicAdd(p, v); }

// edge slot s in [0,2EE): rel 0 = pos, rel 1 = neg
__device__ __forceinline__ void edge_of(const int* __restrict__ pe, const int* __restrict__ ne,
                                        int s, int& src, int& dst, int& bucket) {
    if (s < EE) { src = pe[s]; dst = pe[EE + s]; bucket = dst >> 8; }
    else        { src = ne[s - EE]; dst = ne[s]; bucket = NBUK + (dst >> 8); }
}

// ---- pass 1: per-block bucket histogram ----
__global__ __launch_bounds__(256) void k_hist(const int* __restrict__ pe,
                                              const int* __restrict__ ne,
                                              int* __restrict__ hist) {
    __shared__ int lh[NBUK2];
    for (int i = threadIdx.x; i < NBUK2; i += 256) lh[i] = 0;
    __syncthreads();
    int start = blockIdx.x * EPB, end = min(start + EPB, 2 * EE);
    for (int s = start + threadIdx.x; s < end; s += 256) {
        int src, dst, bucket;
        edge_of(pe, ne, s, src, dst, bucket);
        atomicAdd(&lh[bucket], 1);
    }
    __syncthreads();
    for (int i = threadIdx.x; i < NBUK2; i += 256)
        hist[i * NBLK + blockIdx.x] = lh[i];   // bucket-major
}

// ---- generic hierarchical exclusive scan over NBUK2*NBLK ints ----
__global__ __launch_bounds__(256) void k_gscan1(const int* __restrict__ in,
                                                int* __restrict__ out,
                                                int* __restrict__ partials) {
    int i = blockIdx.x * 256 + threadIdx.x;
    int v = in[i];
    __shared__ int s[256];
    s[threadIdx.x] = v;
    __syncthreads();
    for (int off = 1; off < 256; off <<= 1) {
        int u = (threadIdx.x >= off) ? s[threadIdx.x - off] : 0;
        __syncthreads();
        s[threadIdx.x] += u;
        __syncthreads();
    }
    out[i] = s[threadIdx.x] - v;
    if (threadIdx.x == 255) partials[blockIdx.x] = s[255];
}

__global__ __launch_bounds__(1024) void k_gscan2(int* __restrict__ partials) {
    __shared__ int s[1024];
    int v = (threadIdx.x < GSB) ? partials[threadIdx.x] : 0;
    s[threadIdx.x] = v;
    __syncthreads();
    for (int off = 1; off < 1024; off <<= 1) {
        int u = (threadIdx.x >= off) ? s[threadIdx.x - off] : 0;
        __syncthreads();
        s[threadIdx.x] += u;
        __syncthreads();
    }
    if (threadIdx.x < GSB) partials[threadIdx.x] = s[threadIdx.x] - v;
}

__global__ __launch_bounds__(256) void k_gscan3(const int* __restrict__ partials,
                                                int* __restrict__ out) {
    out[blockIdx.x * 256 + threadIdx.x] += partials[blockIdx.x];
}

// ---- pass 2: scatter edges into bucket-grouped staging (block-exclusive runs) ----
__global__ __launch_bounds__(256) void k_binscatter(const int* __restrict__ pe,
                                                    const int* __restrict__ ne,
                                                    const int* __restrict__ soff,
                                                    unsigned long long* __restrict__ staging) {
    __shared__ int cur[NBUK2];
    for (int i = threadIdx.x; i < NBUK2; i += 256)
        cur[i] = soff[i * NBLK + blockIdx.x];
    __syncthreads();
    int start = blockIdx.x * EPB, end = min(start + EPB, 2 * EE);
    for (int s = start + threadIdx.x; s < end; s += 256) {
        int src, dst, bucket;
        edge_of(pe, ne, s, src, dst, bucket);
        int pos = atomicAdd(&cur[bucket], 1);
        staging[pos] = ((unsigned long long)(unsigned)dst << 32) | (unsigned)src;
    }
}

// ---- pass 3: per-bucket local build: rp (degree+scan in LDS) + csr scatter ----
__global__ __launch_bounds__(256) void k_local(const unsigned long long* __restrict__ staging,
                                               const int* __restrict__ soff,
                                               int* __restrict__ rpP,
                                               int* __restrict__ rpN,
                                               int* __restrict__ csrAll) {
    int bucket = blockIdx.x;
    int rel = bucket >= NBUK;
    int nodeBase = (bucket - rel * NBUK) << 8;
    int bstart = soff[bucket * NBLK];
    int bend = (bucket == NBUK2 - 1) ? 2 * EE : soff[(bucket + 1) * NBLK];
    int tid = threadIdx.x;
    __shared__ int deg[256], sc[256];
    deg[tid] = 0;
    __syncthreads();
    for (int i = bstart + tid; i < bend; i += 256) {
        int d = (int)(staging[i] >> 32) & 255;
        atomicAdd(&deg[d], 1);
    }
    __syncthreads();
    int dv = deg[tid];
    sc[tid] = dv;
    __syncthreads();
    for (int off = 1; off < 256; off <<= 1) {
        int u = (tid >= off) ? sc[tid - off] : 0;
        __syncthreads();
        sc[tid] += u;
        __syncthreads();
    }
    int lrp = sc[tid] - dv;  // bucket-local exclusive prefix
    int nCount = min(256, NN - nodeBase);
    int relbase = rel ? EE : 0;
    if (tid < nCount) (rel ? rpN : rpP)[nodeBase + tid] = bstart - relbase + lrp;
    if (bucket == NBUK - 1 && tid == 0) rpP[NN] = EE;
    if (bucket == NBUK2 - 1 && tid == 0) rpN[NN] = EE;
    deg[tid] = lrp;          // reuse as cursor
    __syncthreads();
    for (int i = bstart + tid; i < bend; i += 256) {
        unsigned long long v = staging[i];
        int d = (int)(v >> 32) & 255;
        int src = (int)(v & 0xffffffffu);
        int slot = atomicAdd(&deg[d], 1);
        csrAll[bstart + slot] = src;
    }
}

// ---- pre-transform 64->32 x3: xp=x@Wp, xn=x@Wn, xs=x@Ws ----
__global__ __launch_bounds__(256) void k_xf1(const float* __restrict__ x,
                                             const float* __restrict__ Wp,
                                             const float* __restrict__ Wn,
                                             const float* __restrict__ Ws,
                                             float* __restrict__ xp,
                                             float* __restrict__ xn,
                                             float* __restrict__ xs) {
    __shared__ float sWp[64 * 32], sWn[64 * 32], sWs[64 * 32];
    for (int i = threadIdx.x; i < 64 * 32; i += 256) { sWp[i] = Wp[i]; sWn[i] = Wn[i]; sWs[i] = Ws[i]; }
    __syncthreads();
    int lane = threadIdx.x & 63;
    int j = lane & 31;
    int half = lane >> 5;
    int wid = (blockIdx.x * 256 + threadIdx.x) >> 6;
    const int nw = (2048 * 256) >> 6;
    for (int p = wid; 2 * p < NN; p += nw) {
        int n = 2 * p + half;
        float vlo = x[(size_t)n * 64 + j];
        float vhi = x[(size_t)n * 64 + 32 + j];
        float ap = 0.f, an = 0.f, as = 0.f;
        #pragma unroll
        for (int k = 0; k < 64; k++) {
            float xv = (k < 32) ? __shfl(vlo, k, 32) : __shfl(vhi, k - 32, 32);
            ap += xv * sWp[k * 32 + j];
            an += xv * sWn[k * 32 + j];
            as += xv * sWs[k * 32 + j];
        }
        xp[(size_t)n * 32 + j] = ap;
        xn[(size_t)n * 32 + j] = an;
        xs[(size_t)n * 32 + j] = as;
    }
}

// ---- pre-transform 32->32 x3 ----
__global__ __launch_bounds__(256) void k_xf2(const float* __restrict__ z,
                                             const float* __restrict__ Wp,
                                             const float* __restrict__ Wn,
                                             const float* __restrict__ Ws,
                                             float* __restrict__ xp,
                                             float* __restrict__ xn,
                                             float* __restrict__ xs) {
    __shared__ float sWp[32 * 32], sWn[32 * 32], sWs[32 * 32];
    for (int i = threadIdx.x; i < 32 * 32; i += 256) { sWp[i] = Wp[i]; sWn[i] = Wn[i]; sWs[i] = Ws[i]; }
    __syncthreads();
    int lane = threadIdx.x & 63;
    int j = lane & 31;
    int half = lane >> 5;
    int wid = (blockIdx.x * 256 + threadIdx.x) >> 6;
    const int nw = (2048 * 256) >> 6;
    for (int p = wid; 2 * p < NN; p += nw) {
        int n = 2 * p + half;
        float v = z[(size_t)n * 32 + j];
        float ap = 0.f, an = 0.f, as = 0.f;
        #pragma unroll
        for (int k = 0; k < 32; k++) {
            float xv = __shfl(v, k, 32);
            ap += xv * sWp[k * 32 + j];
            an += xv * sWn[k * 32 + j];
            as += xv * sWs[k * 32 + j];
        }
        xp[(size_t)n * 32 + j] = ap;
        xn[(size_t)n * 32 + j] = an;
        xs[(size_t)n * 32 + j] = as;
    }
}

// ---- accumulate one relation's neighbors ----
__device__ __forceinline__ float pull_rel(const float* __restrict__ xsrc,
                                          const int* __restrict__ csr,
                                          int b0, int b1, int j, float acc) {
    for (int base = b0; base < b1; base += 32) {
        int rem = b1 - base;
        int cnt = min(rem, 32);
        int idx = (j < rem) ? csr[base + j] : 0;
        int i = 0;
        for (; i + 4 <= cnt; i += 4) {
            int s0 = __shfl(idx, i, 32);
            int s1 = __shfl(idx, i + 1, 32);
            int s2 = __shfl(idx, i + 2, 32);
            int s3 = __shfl(idx, i + 3, 32);
            float v0 = xsrc[(size_t)s0 * 32 + j];
            float v1 = xsrc[(size_t)s1 * 32 + j];
            float v2 = xsrc[(size_t)s2 * 32 + j];
            float v3 = xsrc[(size_t)s3 * 32 + j];
            acc += v0; acc += v1; acc += v2; acc += v3;
        }
        for (; i < cnt; i++) {
            int s = __shfl(idx, i, 32);
            acc += xsrc[(size_t)s * 32 + j];
        }
    }
    return acc;
}

// ---- pull aggregation + combine + tanh ----
__global__ __launch_bounds__(256) void k_pull(const float* __restrict__ xp,
                                              const float* __restrict__ xn,
                                              const float* __restrict__ xs,
                                              const int* __restrict__ rpP,
                                              const int* __restrict__ csrP,
                                              const int* __restrict__ rpN,
                                              const int* __restrict__ csrN,
                                              const float* __restrict__ bp,
                                              const float* __restrict__ bn,
                                              const float* __restrict__ bs,
                                              float* __restrict__ out) {
    int j = threadIdx.x & 31;
    int hw = (blockIdx.x * 256 + threadIdx.x) >> 5;
    const int nhw = (2048 * 256) >> 5;
    float bpj = bp[j], bnj = bn[j], bsj = bs[j];
    for (int n = hw; n < NN; n += nhw) {
        int p0 = rpP[n], p1 = rpP[n + 1];
        int n0 = rpN[n], n1 = rpN[n + 1];
        float acc = xs[(size_t)n * 32 + j] + bsj
                  + (float)(p1 - p0) * bpj + (float)(n1 - n0) * bnj;
        acc = pull_rel(xp, csrP, p0, p1, j, acc);
        acc = pull_rel(xn, csrN, n0, n1, j, acc);
        out[(size_t)n * 32 + j] = tanhf(acc);
    }
}

// ---- fused tiled GEMM: z = tanh(z2@Wl + bl) [N,64], t1 = z@W1 + b1, BN stats ----
// launch_bounds(256,2): VGPR cap 256 so wl[32]+w1[64] stay register-resident
__global__ __launch_bounds__(256, 2) void k_wlin_mlp1(const float* __restrict__ z2,
                                                      const float* __restrict__ Wl,
                                                      const float* __restrict__ bl,
                                                      const float* __restrict__ W1,
                                                      const float* __restrict__ b1_,
                                                      float* __restrict__ z,
                                                      float* __restrict__ t1,
                                                      float* __restrict__ colsum,
                                                      float* __restrict__ colsq) {
    __shared__ float sx[64 * 32];   // z2 tile (8KB)
    __shared__ float sz[4 * 64];    // per-wave z-row bounce (1KB)
    __shared__ float red[256], red2[256];
    int base = blockIdx.x * 64;
    int tid = threadIdx.x;
    int lane = tid & 63;
    int wv = tid >> 6;
    // stage z2 tile: 64 rows x 32 cols, coalesced float4; zero OOB rows
    {
        int row = tid >> 2, c4 = tid & 3;   // 4 threads/row, 2 float4 each
        int n = base + row;
        #pragma unroll
        for (int m = 0; m < 2; m++) {
            int f = c4 + 4 * m;             // float4 index 0..7
            float4 v = (n < NN) ? *(const float4*)&z2[(size_t)n * 32 + f * 4]
                                : make_float4(0.f, 0.f, 0.f, 0.f);
            *(float4*)&sx[row * 32 + f * 4] = v;
        }
    }
    float wl[32];
    #pragma unroll
    for (int k = 0; k < 32; k++) wl[k] = Wl[k * 64 + lane];
    float w1[64];
    #pragma unroll
    for (int k = 0; k < 64; k++) w1[k] = W1[k * 64 + lane];
    float blj = bl[lane], b1j = b1_[lane];
    __syncthreads();
    float lsum = 0.f, lsq = 0.f;
    #pragma unroll 1
    for (int i = 0; i < 16; i++) {
        int nl = i * 4 + wv;
        int n = base + nl;
        float a0 = 0.f, a1c = 0.f, a2 = 0.f, a3 = 0.f;
        #pragma unroll
        for (int q = 0; q < 8; q++) {
            float4 xv = *(const float4*)&sx[nl * 32 + q * 4];
            a0 += xv.x * wl[q * 4 + 0];
            a1c += xv.y * wl[q * 4 + 1];
            a2 += xv.z * wl[q * 4 + 2];
            a3 += xv.w * wl[q * 4 + 3];
        }
        float zv = tanhf(blj + ((a0 + a1c) + (a2 + a3)));
        if (n < NN) z[(size_t)n * 64 + lane] = zv;
        sz[wv * 64 + lane] = zv;            // same-wave bounce (no barrier needed)
        float t0 = 0.f, t1a = 0.f, t2a = 0.f, t3a = 0.f;
        #pragma unroll
        for (int q = 0; q < 16; q++) {
            float4 zv4 = *(const float4*)&sz[wv * 64 + q * 4];
            t0 += zv4.x * w1[q * 4 + 0];
            t1a += zv4.y * w1[q * 4 + 1];
            t2a += zv4.z * w1[q * 4 + 2];
            t3a += zv4.w * w1[q * 4 + 3];
        }
        float t = b1j + ((t0 + t1a) + (t2a + t3a));
        if (n < NN) {
            t1[(size_t)n * 64 + lane] = t;
            lsum += t; lsq += t * t;
        }
    }
    red[tid] = lsum; red2[tid] = lsq;
    __syncthreads();
    if (tid < 64) {
        float a = red[tid] + red[tid + 64] + red[tid + 128] + red[tid + 192];
        float q = red2[tid] + red2[tid + 64] + red2[tid + 128] + red2[tid + 192];
        fatomic(&colsum[tid], a);
        fatomic(&colsq[tid], q);
    }
}

// ---- BN stats -> affine coefficients a, c (h_norm = t*a + c) ----
__global__ void k_bnstats(const float* __restrict__ colsum, const float* __restrict__ colsq,
                          const float* __restrict__ g, const float* __restrict__ beta,
                          float* __restrict__ a, float* __restrict__ c) {
    int j = threadIdx.x;
    if (j < 64) {
        float m = colsum[j] * (1.f / NN);
        float v = colsq[j] * (1.f / NN) - m * m;
        float aj = g[j] * rsqrtf(v + EPSF);
        a[j] = aj;
        c[j] = beta[j] - m * aj;
    }
}

// ---- tiled GEMM: t2 = relu(t1*a1+c1) @ m2_W + m2_b, BN stats; launch_bounds(256,2) for w[64] residency ----
__global__ __launch_bounds__(256, 2) void k_mlp2(const float* __restrict__ t1,
                                                 const float* __restrict__ a1,
                                                 const float* __restrict__ c1,
                                                 const float* __restrict__ W,
                                                 const float* __restrict__ b,
                                                 float* __restrict__ t2,
                                                 float* __restrict__ colsum,
                                                 float* __restrict__ colsq) {
    __shared__ float sh[32 * 64];   // h tile = relu(t1*a+c) (8KB)
    __shared__ float red[256], red2[256];
    int base = blockIdx.x * 32;
    int tid = threadIdx.x;
    int lane = tid & 63;
    int wv = tid >> 6;
    {
        int row = tid >> 3, c8 = tid & 7;   // 8 threads/row, 2 float4 each
        int n = base + row;
        #pragma unroll
        for (int m = 0; m < 2; m++) {
            int f = c8 + 8 * m;             // float4 index 0..15
            float4 tv = (n < NN) ? *(const float4*)&t1[(size_t)n * 64 + f * 4]
                                 : make_float4(0.f, 0.f, 0.f, 0.f);
            float4 av = *(const float4*)&a1[f * 4];
            float4 cv = *(const float4*)&c1[f * 4];
            float4 hv;
            hv.x = fmaxf(tv.x * av.x + cv.x, 0.f);
            hv.y = fmaxf(tv.y * av.y + cv.y, 0.f);
            hv.z = fmaxf(tv.z * av.z + cv.z, 0.f);
            hv.w = fmaxf(tv.w * av.w + cv.w, 0.f);
            *(float4*)&sh[row * 64 + f * 4] = hv;
        }
    }
    float w[64];
    #pragma unroll
    for (int k = 0; k < 64; k++) w[k] = W[k * 64 + lane];
    float bj = b[lane];
    __syncthreads();
    float lsum = 0.f, lsq = 0.f;
    #pragma unroll 1
    for (int i = 0; i < 8; i++) {
        int nl = i * 4 + wv;
        int n = base + nl;
        float a0 = 0.f, a1c = 0.f, a2 = 0.f, a3 = 0.f;
        #pragma unroll
        for (int q = 0; q < 16; q++) {
            float4 xv = *(const float4*)&sh[nl * 64 + q * 4];
            a0 += xv.x * w[q * 4 + 0];
            a1c += xv.y * w[q * 4 + 1];
            a2 += xv.z * w[q * 4 + 2];
            a3 += xv.w * w[q * 4 + 3];
        }
        float s = bj + ((a0 + a1c) + (a2 + a3));
        if (n < NN) {
            t2[(size_t)n * 64 + lane] = s;
            lsum += s; lsq += s * s;
        }
    }
    red[tid] = lsum; red2[tid] = lsq;
    __syncthreads();
    if (tid < 64) {
        float a = red[tid] + red[tid + 64] + red[tid + 128] + red[tid + 192];
        float q = red2[tid] + red2[tid + 64] + red2[tid + 128] + red2[tid + 192];
        fatomic(&colsum[tid], a);
        fatomic(&colsq[tid], q);
    }
}

// ---- prob = sigmoid(relu(t2*a2+c2) @ m3_W + m3_b) ----
__global__ __launch_bounds__(256) void k_mlp3(const float* __restrict__ t2,
                                              const float* __restrict__ a2,
                                              const float* __restrict__ c2,
                                              const float* __restrict__ W3,
                                              const float* __restrict__ b3,
                                              float* __restrict__ prob) {
    int j = threadIdx.x & 63;
    int r = threadIdx.x >> 6;
    float aj = a2[j], cj = c2[j], wj = W3[j], bb = b3[0];
    for (int n = blockIdx.x * 4 + r; n < NN; n += 2048 * 4) {
        float h = fmaxf(t2[(size_t)n * 64 + j] * aj + cj, 0.f) * wj;
        #pragma unroll
        for (int off = 32; off > 0; off >>= 1) h += __shfl_xor(h, off, 64);
        if (j == 0) prob[n] = 1.f / (1.f + expf(-(h + bb)));
    }
}

extern "C" void kernel_launch(void* const* d_in, const int* in_sizes, int n_in,
                              void* d_out, int out_size, void* d_ws, size_t ws_size,
                              hipStream_t stream) {
    const float* init_emb = (const float*)d_in[0];
    const int* pe = (const int*)d_in[1];
    const int* ne = (const int*)d_in[2];
    const float* c1_Wp = (const float*)d_in[3];  const float* c1_bp = (const float*)d_in[4];
    const float* c1_Wn = (const float*)d_in[5];  const float* c1_bn = (const float*)d_in[6];
    const float* c1_Ws = (const float*)d_in[7];  const float* c1_bs = (const float*)d_in[8];
    const float* c2_Wp = (const float*)d_in[9];  const float* c2_bp = (const float*)d_in[10];
    const float* c2_Wn = (const float*)d_in[11]; const float* c2_bn = (const float*)d_in[12];
    const float* c2_Ws = (const float*)d_in[13]; const float* c2_bs = (const float*)d_in[14];
    const float* w_W = (const float*)d_in[15];   const float* w_b = (const float*)d_in[16];
    const float* m1_W = (const float*)d_in[17];  const float* m1_b = (const float*)d_in[18];
    const float* g1 = (const float*)d_in[19];    const float* b1 = (const float*)d_in[20];
    const float* m2_W = (const float*)d_in[21];  const float* m2_b = (const float*)d_in[22];
    const float* g2 = (const float*)d_in[23];    const float* b2 = (const float*)d_in[24];
    const float* m3_W = (const float*)d_in[25];  const float* m3_b = (const float*)d_in[26];

    // ---- workspace arena ----
    size_t off = 0;
    auto alloc = [&](size_t bytes) -> void* {
        void* r = (char*)d_ws + off;
        off += (bytes + 255) & ~(size_t)255;
        return r;
    };
    // zero region (front): only BN stat accumulators
    float* sums = (float*)alloc(256 * 4);               // colsum1, colsq1, colsum2, colsq2
    size_t zero_bytes = off;
    // CSR-build region (dead after second k_pull; t2 aliases it later)
    size_t csr_region = off;
    int*   hist = (int*)alloc((size_t)NBUK2 * NBLK * 4);        // 800KB
    int*   soff = (int*)alloc((size_t)NBUK2 * NBLK * 4);        // 800KB
    int*   part = (int*)alloc((size_t)1024 * 4);
    unsigned long long* staging = (unsigned long long*)alloc((size_t)2 * EE * 8);  // 16MB
    int*   csrAll = (int*)alloc((size_t)2 * EE * 4);            // 8MB
    // persistent
    int*   rpP  = (int*)alloc((size_t)(NN + 1) * 4);
    int*   rpN  = (int*)alloc((size_t)(NN + 1) * 4);
    float* R1   = (float*)alloc((size_t)NN * 96 * 4);   // {xp,xn,xs} layer1 -> layer2 -> t1
    float* z1   = (float*)alloc((size_t)NN * 32 * 4);
    float* z2   = (float*)alloc((size_t)NN * 32 * 4);
    float* abc  = (float*)alloc(256 * 4);               // a1, c1, a2, c2

    int* csrP = csrAll;
    int* csrN = csrAll + (size_t)EE;
    float* xp = R1;
    float* xn = R1 + (size_t)NN * 32;
    float* xs = R1 + (size_t)NN * 64;
    float* t1 = R1;                                     // dead xp/xn region after wlin
    float* t2 = (float*)((char*)d_ws + csr_region);     // aliases CSR-build scratch (25.6MB fits)

    float* z_out = (float*)d_out;                       // [N,64]
    float* prob  = (float*)d_out + (size_t)NN * 64;     // [N,1]

    hipMemsetAsync(d_ws, 0, zero_bytes, stream);

    // ---- CSR build: hist -> scan -> bin scatter -> per-bucket local build ----
    k_hist<<<NBLK, 256, 0, stream>>>(pe, ne, hist);
    k_gscan1<<<GSB, 256, 0, stream>>>(hist, soff, part);
    k_gscan2<<<1, 1024, 0, stream>>>(part);
    k_gscan3<<<GSB, 256, 0, stream>>>(part, soff);
    k_binscatter<<<NBLK, 256, 0, stream>>>(pe, ne, soff, staging);
    k_local<<<NBUK2, 256, 0, stream>>>(staging, soff, rpP, rpN, csrAll);

    // layer 1
    k_xf1<<<2048, 256, 0, stream>>>(init_emb, c1_Wp, c1_Wn, c1_Ws, xp, xn, xs);
    k_pull<<<2048, 256, 0, stream>>>(xp, xn, xs, rpP, csrP, rpN, csrN, c1_bp, c1_bn, c1_bs, z1);
    // layer 2
    k_xf2<<<2048, 256, 0, stream>>>(z1, c2_Wp, c2_Wn, c2_Ws, xp, xn, xs);
    k_pull<<<2048, 256, 0, stream>>>(xp, xn, xs, rpP, csrP, rpN, csrN, c2_bp, c2_bn, c2_bs, z2);
    // readout
    k_wlin_mlp1<<<GTILES, 256, 0, stream>>>(z2, w_W, w_b, m1_W, m1_b, z_out, t1, sums + 0, sums + 64);
    k_bnstats<<<1, 64, 0, stream>>>(sums + 0, sums + 64, g1, b1, abc + 0, abc + 64);
    k_mlp2<<<GTILES32, 256, 0, stream>>>(t1, abc + 0, abc + 64, m2_W, m2_b, t2, sums + 128, sums + 192);
    k_bnstats<<<1, 64, 0, stream>>>(sums + 128, sums + 192, g2, b2, abc + 128, abc + 192);
    k_mlp3<<<2048, 256, 0, stream>>>(t2, abc + 128, abc + 192, m3_W, m3_b, prob);
}

// Round 10
// 375.878 us; speedup vs baseline: 1.1020x; 1.0969x over previous
//
#include <hip/hip_runtime.h>
#include <cstdint>
#include <cstddef>

#define NN 100000
#define EE 1000000
#define EPSF 1e-5f
#define NBUK 391          // node buckets per relation: ceil(100000/256), dst>>8
#define NBUK2 (2*NBUK)    // both relations
#define NBLK 256          // edge-chunk blocks for hist/binscatter
#define EPB 7813          // ceil(2*EE / NBLK)
#define GSB 782           // scan blocks over NBUK2*NBLK entries (=200192/256)
#define GTILES ((NN + 63) / 64)   // 1563 64-node GEMM tiles

__device__ __forceinline__ void fatomic(float* p, float v) { unsafeAtomicAdd(p, v); }

// edge slot s in [0,2EE): rel 0 = pos, rel 1 = neg
__device__ __forceinline__ void edge_of(const int* __restrict__ pe, const int* __restrict__ ne,
                                        int s, int& src, int& dst, int& bucket) {
    if (s < EE) { src = pe[s]; dst = pe[EE + s]; bucket = dst >> 8; }
    else        { src = ne[s - EE]; dst = ne[s]; bucket = NBUK + (dst >> 8); }
}

// ---- pass 1: per-block bucket histogram ----
__global__ __launch_bounds__(256) void k_hist(const int* __restrict__ pe,
                                              const int* __restrict__ ne,
                                              int* __restrict__ hist) {
    __shared__ int lh[NBUK2];
    for (int i = threadIdx.x; i < NBUK2; i += 256) lh[i] = 0;
    __syncthreads();
    int start = blockIdx.x * EPB, end = min(start + EPB, 2 * EE);
    for (int s = start + threadIdx.x; s < end; s += 256) {
        int src, dst, bucket;
        edge_of(pe, ne, s, src, dst, bucket);
        atomicAdd(&lh[bucket], 1);
    }
    __syncthreads();
    for (int i = threadIdx.x; i < NBUK2; i += 256)
        hist[i * NBLK + blockIdx.x] = lh[i];   // bucket-major
}

// ---- generic hierarchical exclusive scan over NBUK2*NBLK ints ----
__global__ __launch_bounds__(256) void k_gscan1(const int* __restrict__ in,
                                                int* __restrict__ out,
                                                int* __restrict__ partials) {
    int i = blockIdx.x * 256 + threadIdx.x;
    int v = in[i];
    __shared__ int s[256];
    s[threadIdx.x] = v;
    __syncthreads();
    for (int off = 1; off < 256; off <<= 1) {
        int u = (threadIdx.x >= off) ? s[threadIdx.x - off] : 0;
        __syncthreads();
        s[threadIdx.x] += u;
        __syncthreads();
    }
    out[i] = s[threadIdx.x] - v;
    if (threadIdx.x == 255) partials[blockIdx.x] = s[255];
}

__global__ __launch_bounds__(1024) void k_gscan2(int* __restrict__ partials) {
    __shared__ int s[1024];
    int v = (threadIdx.x < GSB) ? partials[threadIdx.x] : 0;
    s[threadIdx.x] = v;
    __syncthreads();
    for (int off = 1; off < 1024; off <<= 1) {
        int u = (threadIdx.x >= off) ? s[threadIdx.x - off] : 0;
        __syncthreads();
        s[threadIdx.x] += u;
        __syncthreads();
    }
    if (threadIdx.x < GSB) partials[threadIdx.x] = s[threadIdx.x] - v;
}

__global__ __launch_bounds__(256) void k_gscan3(const int* __restrict__ partials,
                                                int* __restrict__ out) {
    out[blockIdx.x * 256 + threadIdx.x] += partials[blockIdx.x];
}

// ---- pass 2: scatter edges into bucket-grouped staging (block-exclusive runs) ----
__global__ __launch_bounds__(256) void k_binscatter(const int* __restrict__ pe,
                                                    const int* __restrict__ ne,
                                                    const int* __restrict__ soff,
                                                    unsigned long long* __restrict__ staging) {
    __shared__ int cur[NBUK2];
    for (int i = threadIdx.x; i < NBUK2; i += 256)
        cur[i] = soff[i * NBLK + blockIdx.x];
    __syncthreads();
    int start = blockIdx.x * EPB, end = min(start + EPB, 2 * EE);
    for (int s = start + threadIdx.x; s < end; s += 256) {
        int src, dst, bucket;
        edge_of(pe, ne, s, src, dst, bucket);
        int pos = atomicAdd(&cur[bucket], 1);
        staging[pos] = ((unsigned long long)(unsigned)dst << 32) | (unsigned)src;
    }
}

// ---- pass 3: per-bucket local build: rp (degree+scan in LDS) + csr scatter ----
__global__ __launch_bounds__(256) void k_local(const unsigned long long* __restrict__ staging,
                                               const int* __restrict__ soff,
                                               int* __restrict__ rpP,
                                               int* __restrict__ rpN,
                                               int* __restrict__ csrAll) {
    int bucket = blockIdx.x;
    int rel = bucket >= NBUK;
    int nodeBase = (bucket - rel * NBUK) << 8;
    int bstart = soff[bucket * NBLK];
    int bend = (bucket == NBUK2 - 1) ? 2 * EE : soff[(bucket + 1) * NBLK];
    int tid = threadIdx.x;
    __shared__ int deg[256], sc[256];
    deg[tid] = 0;
    __syncthreads();
    for (int i = bstart + tid; i < bend; i += 256) {
        int d = (int)(staging[i] >> 32) & 255;
        atomicAdd(&deg[d], 1);
    }
    __syncthreads();
    int dv = deg[tid];
    sc[tid] = dv;
    __syncthreads();
    for (int off = 1; off < 256; off <<= 1) {
        int u = (tid >= off) ? sc[tid - off] : 0;
        __syncthreads();
        sc[tid] += u;
        __syncthreads();
    }
    int lrp = sc[tid] - dv;  // bucket-local exclusive prefix
    int nCount = min(256, NN - nodeBase);
    int relbase = rel ? EE : 0;
    if (tid < nCount) (rel ? rpN : rpP)[nodeBase + tid] = bstart - relbase + lrp;
    if (bucket == NBUK - 1 && tid == 0) rpP[NN] = EE;
    if (bucket == NBUK2 - 1 && tid == 0) rpN[NN] = EE;
    deg[tid] = lrp;          // reuse as cursor
    __syncthreads();
    for (int i = bstart + tid; i < bend; i += 256) {
        unsigned long long v = staging[i];
        int d = (int)(v >> 32) & 255;
        int src = (int)(v & 0xffffffffu);
        int slot = atomicAdd(&deg[d], 1);
        csrAll[bstart + slot] = src;
    }
}

// ---- pre-transform 64->32 x3: xp=x@Wp, xn=x@Wn, xs=x@Ws ----
__global__ __launch_bounds__(256) void k_xf1(const float* __restrict__ x,
                                             const float* __restrict__ Wp,
                                             const float* __restrict__ Wn,
                                             const float* __restrict__ Ws,
                                             float* __restrict__ xp,
                                             float* __restrict__ xn,
                                             float* __restrict__ xs) {
    __shared__ float sWp[64 * 32], sWn[64 * 32], sWs[64 * 32];
    for (int i = threadIdx.x; i < 64 * 32; i += 256) { sWp[i] = Wp[i]; sWn[i] = Wn[i]; sWs[i] = Ws[i]; }
    __syncthreads();
    int lane = threadIdx.x & 63;
    int j = lane & 31;
    int half = lane >> 5;
    int wid = (blockIdx.x * 256 + threadIdx.x) >> 6;
    const int nw = (2048 * 256) >> 6;
    for (int p = wid; 2 * p < NN; p += nw) {
        int n = 2 * p + half;
        float vlo = x[(size_t)n * 64 + j];
        float vhi = x[(size_t)n * 64 + 32 + j];
        float ap = 0.f, an = 0.f, as = 0.f;
        #pragma unroll
        for (int k = 0; k < 64; k++) {
            float xv = (k < 32) ? __shfl(vlo, k, 32) : __shfl(vhi, k - 32, 32);
            ap += xv * sWp[k * 32 + j];
            an += xv * sWn[k * 32 + j];
            as += xv * sWs[k * 32 + j];
        }
        xp[(size_t)n * 32 + j] = ap;
        xn[(size_t)n * 32 + j] = an;
        xs[(size_t)n * 32 + j] = as;
    }
}

// ---- pre-transform 32->32 x3 ----
__global__ __launch_bounds__(256) void k_xf2(const float* __restrict__ z,
                                             const float* __restrict__ Wp,
                                             const float* __restrict__ Wn,
                                             const float* __restrict__ Ws,
                                             float* __restrict__ xp,
                                             float* __restrict__ xn,
                                             float* __restrict__ xs) {
    __shared__ float sWp[32 * 32], sWn[32 * 32], sWs[32 * 32];
    for (int i = threadIdx.x; i < 32 * 32; i += 256) { sWp[i] = Wp[i]; sWn[i] = Wn[i]; sWs[i] = Ws[i]; }
    __syncthreads();
    int lane = threadIdx.x & 63;
    int j = lane & 31;
    int half = lane >> 5;
    int wid = (blockIdx.x * 256 + threadIdx.x) >> 6;
    const int nw = (2048 * 256) >> 6;
    for (int p = wid; 2 * p < NN; p += nw) {
        int n = 2 * p + half;
        float v = z[(size_t)n * 32 + j];
        float ap = 0.f, an = 0.f, as = 0.f;
        #pragma unroll
        for (int k = 0; k < 32; k++) {
            float xv = __shfl(v, k, 32);
            ap += xv * sWp[k * 32 + j];
            an += xv * sWn[k * 32 + j];
            as += xv * sWs[k * 32 + j];
        }
        xp[(size_t)n * 32 + j] = ap;
        xn[(size_t)n * 32 + j] = an;
        xs[(size_t)n * 32 + j] = as;
    }
}

// ---- accumulate one relation's neighbors ----
__device__ __forceinline__ float pull_rel(const float* __restrict__ xsrc,
                                          const int* __restrict__ csr,
                                          int b0, int b1, int j, float acc) {
    for (int base = b0; base < b1; base += 32) {
        int rem = b1 - base;
        int cnt = min(rem, 32);
        int idx = (j < rem) ? csr[base + j] : 0;
        int i = 0;
        for (; i + 4 <= cnt; i += 4) {
            int s0 = __shfl(idx, i, 32);
            int s1 = __shfl(idx, i + 1, 32);
            int s2 = __shfl(idx, i + 2, 32);
            int s3 = __shfl(idx, i + 3, 32);
            float v0 = xsrc[(size_t)s0 * 32 + j];
            float v1 = xsrc[(size_t)s1 * 32 + j];
            float v2 = xsrc[(size_t)s2 * 32 + j];
            float v3 = xsrc[(size_t)s3 * 32 + j];
            acc += v0; acc += v1; acc += v2; acc += v3;
        }
        for (; i < cnt; i++) {
            int s = __shfl(idx, i, 32);
            acc += xsrc[(size_t)s * 32 + j];
        }
    }
    return acc;
}

// ---- pull aggregation + combine + tanh ----
__global__ __launch_bounds__(256) void k_pull(const float* __restrict__ xp,
                                              const float* __restrict__ xn,
                                              const float* __restrict__ xs,
                                              const int* __restrict__ rpP,
                                              const int* __restrict__ csrP,
                                              const int* __restrict__ rpN,
                                              const int* __restrict__ csrN,
                                              const float* __restrict__ bp,
                                              const float* __restrict__ bn,
                                              const float* __restrict__ bs,
                                              float* __restrict__ out) {
    int j = threadIdx.x & 31;
    int hw = (blockIdx.x * 256 + threadIdx.x) >> 5;
    const int nhw = (2048 * 256) >> 5;
    float bpj = bp[j], bnj = bn[j], bsj = bs[j];
    for (int n = hw; n < NN; n += nhw) {
        int p0 = rpP[n], p1 = rpP[n + 1];
        int n0 = rpN[n], n1 = rpN[n + 1];
        float acc = xs[(size_t)n * 32 + j] + bsj
                  + (float)(p1 - p0) * bpj + (float)(n1 - n0) * bnj;
        acc = pull_rel(xp, csrP, p0, p1, j, acc);
        acc = pull_rel(xn, csrN, n0, n1, j, acc);
        out[(size_t)n * 32 + j] = tanhf(acc);
    }
}

// ---- z = tanh(z2 @ Wl + bl): 32->64, 64-row tiles (output 0) ----
__global__ __launch_bounds__(256) __attribute__((amdgpu_waves_per_eu(2, 4)))
void k_wlin(const float* __restrict__ z2,
            const float* __restrict__ Wl,
            const float* __restrict__ bl,
            float* __restrict__ z) {
    __shared__ float sx[64 * 32];   // z2 tile (8KB)
    int base = blockIdx.x * 64;
    int tid = threadIdx.x;
    int lane = tid & 63;
    int wv = tid >> 6;
    {
        int row = tid >> 2, c4 = tid & 3;
        int n = base + row;
        #pragma unroll
        for (int m = 0; m < 2; m++) {
            int f = c4 + 4 * m;
            float4 v = (n < NN) ? *(const float4*)&z2[(size_t)n * 32 + f * 4]
                                : make_float4(0.f, 0.f, 0.f, 0.f);
            *(float4*)&sx[row * 32 + f * 4] = v;
        }
    }
    float wl[32];
    #pragma unroll
    for (int k = 0; k < 32; k++) wl[k] = Wl[k * 64 + lane];
    float blj = bl[lane];
    __syncthreads();
    #pragma unroll 1
    for (int i = 0; i < 16; i++) {
        int nl = i * 4 + wv;
        int n = base + nl;
        float a0 = 0.f, a1c = 0.f, a2 = 0.f, a3 = 0.f;
        #pragma unroll
        for (int q = 0; q < 8; q++) {
            float4 xv = *(const float4*)&sx[nl * 32 + q * 4];
            a0 += xv.x * wl[q * 4 + 0];
            a1c += xv.y * wl[q * 4 + 1];
            a2 += xv.z * wl[q * 4 + 2];
            a3 += xv.w * wl[q * 4 + 3];
        }
        if (n < NN) z[(size_t)n * 64 + lane] = tanhf(blj + ((a0 + a1c) + (a2 + a3)));
    }
}

// ---- shared MLP GEMM: out = [relu(in*a+c) or in] @ W + b, column stats ----
// 64-row tiles; w[64] register-resident via amdgpu_waves_per_eu(2,4) (VGPR budget 128)
__global__ __launch_bounds__(256) __attribute__((amdgpu_waves_per_eu(2, 4)))
void k_mlp(const float* __restrict__ in,
           const float* __restrict__ a1,
           const float* __restrict__ c1,
           int doBN,
           const float* __restrict__ W,
           const float* __restrict__ b,
           float* __restrict__ out,
           float* __restrict__ colsum,
           float* __restrict__ colsq) {
    __shared__ float sh[64 * 64];   // staged (optionally BN+ReLU'd) input tile (16KB)
    __shared__ float red[256], red2[256];
    int base = blockIdx.x * 64;
    int tid = threadIdx.x;
    int lane = tid & 63;
    int wv = tid >> 6;
    {
        int row = tid >> 2, c4 = tid & 3;   // 4 threads/row, 4 float4 each
        int n = base + row;
        #pragma unroll
        for (int m = 0; m < 4; m++) {
            int f = c4 + 4 * m;             // float4 index 0..15
            float4 tv = (n < NN) ? *(const float4*)&in[(size_t)n * 64 + f * 4]
                                 : make_float4(0.f, 0.f, 0.f, 0.f);
            if (doBN) {
                float4 av = *(const float4*)&a1[f * 4];
                float4 cv = *(const float4*)&c1[f * 4];
                tv.x = fmaxf(tv.x * av.x + cv.x, 0.f);
                tv.y = fmaxf(tv.y * av.y + cv.y, 0.f);
                tv.z = fmaxf(tv.z * av.z + cv.z, 0.f);
                tv.w = fmaxf(tv.w * av.w + cv.w, 0.f);
            }
            *(float4*)&sh[row * 64 + f * 4] = tv;
        }
    }
    float w[64];
    #pragma unroll
    for (int k = 0; k < 64; k++) w[k] = W[k * 64 + lane];
    float bj = b[lane];
    __syncthreads();
    float lsum = 0.f, lsq = 0.f;
    #pragma unroll 1
    for (int i = 0; i < 16; i++) {
        int nl = i * 4 + wv;
        int n = base + nl;
        float a0 = 0.f, a1c = 0.f, a2 = 0.f, a3 = 0.f;
        #pragma unroll
        for (int q = 0; q < 16; q++) {
            float4 xv = *(const float4*)&sh[nl * 64 + q * 4];
            a0 += xv.x * w[q * 4 + 0];
            a1c += xv.y * w[q * 4 + 1];
            a2 += xv.z * w[q * 4 + 2];
            a3 += xv.w * w[q * 4 + 3];
        }
        float s = bj + ((a0 + a1c) + (a2 + a3));
        if (n < NN) {
            out[(size_t)n * 64 + lane] = s;
            lsum += s; lsq += s * s;
        }
    }
    red[tid] = lsum; red2[tid] = lsq;
    __syncthreads();
    if (tid < 64) {
        float a = red[tid] + red[tid + 64] + red[tid + 128] + red[tid + 192];
        float q = red2[tid] + red2[tid + 64] + red2[tid + 128] + red2[tid + 192];
        fatomic(&colsum[tid], a);
        fatomic(&colsq[tid], q);
    }
}

// ---- BN stats -> affine coefficients a, c (h_norm = t*a + c) ----
__global__ void k_bnstats(const float* __restrict__ colsum, const float* __restrict__ colsq,
                          const float* __restrict__ g, const float* __restrict__ beta,
                          float* __restrict__ a, float* __restrict__ c) {
    int j = threadIdx.x;
    if (j < 64) {
        float m = colsum[j] * (1.f / NN);
        float v = colsq[j] * (1.f / NN) - m * m;
        float aj = g[j] * rsqrtf(v + EPSF);
        a[j] = aj;
        c[j] = beta[j] - m * aj;
    }
}

// ---- prob = sigmoid(relu(t2*a2+c2) @ m3_W + m3_b) ----
__global__ __launch_bounds__(256) void k_mlp3(const float* __restrict__ t2,
                                              const float* __restrict__ a2,
                                              const float* __restrict__ c2,
                                              const float* __restrict__ W3,
                                              const float* __restrict__ b3,
                                              float* __restrict__ prob) {
    int j = threadIdx.x & 63;
    int r = threadIdx.x >> 6;
    float aj = a2[j], cj = c2[j], wj = W3[j], bb = b3[0];
    for (int n = blockIdx.x * 4 + r; n < NN; n += 2048 * 4) {
        float h = fmaxf(t2[(size_t)n * 64 + j] * aj + cj, 0.f) * wj;
        #pragma unroll
        for (int off = 32; off > 0; off >>= 1) h += __shfl_xor(h, off, 64);
        if (j == 0) prob[n] = 1.f / (1.f + expf(-(h + bb)));
    }
}

extern "C" void kernel_launch(void* const* d_in, const int* in_sizes, int n_in,
                              void* d_out, int out_size, void* d_ws, size_t ws_size,
                              hipStream_t stream) {
    const float* init_emb = (const float*)d_in[0];
    const int* pe = (const int*)d_in[1];
    const int* ne = (const int*)d_in[2];
    const float* c1_Wp = (const float*)d_in[3];  const float* c1_bp = (const float*)d_in[4];
    const float* c1_Wn = (const float*)d_in[5];  const float* c1_bn = (const float*)d_in[6];
    const float* c1_Ws = (const float*)d_in[7];  const float* c1_bs = (const float*)d_in[8];
    const float* c2_Wp = (const float*)d_in[9];  const float* c2_bp = (const float*)d_in[10];
    const float* c2_Wn = (const float*)d_in[11]; const float* c2_bn = (const float*)d_in[12];
    const float* c2_Ws = (const float*)d_in[13]; const float* c2_bs = (const float*)d_in[14];
    const float* w_W = (const float*)d_in[15];   const float* w_b = (const float*)d_in[16];
    const float* m1_W = (const float*)d_in[17];  const float* m1_b = (const float*)d_in[18];
    const float* g1 = (const float*)d_in[19];    const float* b1 = (const float*)d_in[20];
    const float* m2_W = (const float*)d_in[21];  const float* m2_b = (const float*)d_in[22];
    const float* g2 = (const float*)d_in[23];    const float* b2 = (const float*)d_in[24];
    const float* m3_W = (const float*)d_in[25];  const float* m3_b = (const float*)d_in[26];

    // ---- workspace arena ----
    size_t off = 0;
    auto alloc = [&](size_t bytes) -> void* {
        void* r = (char*)d_ws + off;
        off += (bytes + 255) & ~(size_t)255;
        return r;
    };
    // zero region (front): only BN stat accumulators
    float* sums = (float*)alloc(256 * 4);               // colsum1, colsq1, colsum2, colsq2
    size_t zero_bytes = off;
    // CSR-build region (dead after second k_pull; t2 aliases it later)
    size_t csr_region = off;
    int*   hist = (int*)alloc((size_t)NBUK2 * NBLK * 4);        // 800KB
    int*   soff = (int*)alloc((size_t)NBUK2 * NBLK * 4);        // 800KB
    int*   part = (int*)alloc((size_t)1024 * 4);
    unsigned long long* staging = (unsigned long long*)alloc((size_t)2 * EE * 8);  // 16MB
    int*   csrAll = (int*)alloc((size_t)2 * EE * 4);            // 8MB
    // persistent
    int*   rpP  = (int*)alloc((size_t)(NN + 1) * 4);
    int*   rpN  = (int*)alloc((size_t)(NN + 1) * 4);
    float* R1   = (float*)alloc((size_t)NN * 96 * 4);   // {xp,xn,xs} layer1 -> layer2 -> t1
    float* z1   = (float*)alloc((size_t)NN * 32 * 4);
    float* z2   = (float*)alloc((size_t)NN * 32 * 4);
    float* abc  = (float*)alloc(256 * 4);               // a1, c1, a2, c2

    int* csrP = csrAll;
    int* csrN = csrAll + (size_t)EE;
    float* xp = R1;
    float* xn = R1 + (size_t)NN * 32;
    float* xs = R1 + (size_t)NN * 64;
    float* t1 = R1;                                     // dead xp/xn region after wlin
    float* t2 = (float*)((char*)d_ws + csr_region);     // aliases CSR-build scratch (25.6MB fits)

    float* z_out = (float*)d_out;                       // [N,64]
    float* prob  = (float*)d_out + (size_t)NN * 64;     // [N,1]

    hipMemsetAsync(d_ws, 0, zero_bytes, stream);

    // ---- CSR build: hist -> scan -> bin scatter -> per-bucket local build ----
    k_hist<<<NBLK, 256, 0, stream>>>(pe, ne, hist);
    k_gscan1<<<GSB, 256, 0, stream>>>(hist, soff, part);
    k_gscan2<<<1, 1024, 0, stream>>>(part);
    k_gscan3<<<GSB, 256, 0, stream>>>(part, soff);
    k_binscatter<<<NBLK, 256, 0, stream>>>(pe, ne, soff, staging);
    k_local<<<NBUK2, 256, 0, stream>>>(staging, soff, rpP, rpN, csrAll);

    // layer 1
    k_xf1<<<2048, 256, 0, stream>>>(init_emb, c1_Wp, c1_Wn, c1_Ws, xp, xn, xs);
    k_pull<<<2048, 256, 0, stream>>>(xp, xn, xs, rpP, csrP, rpN, csrN, c1_bp, c1_bn, c1_bs, z1);
    // layer 2
    k_xf2<<<2048, 256, 0, stream>>>(z1, c2_Wp, c2_Wn, c2_Ws, xp, xn, xs);
    k_pull<<<2048, 256, 0, stream>>>(xp, xn, xs, rpP, csrP, rpN, csrN, c2_bp, c2_bn, c2_bs, z2);
    // readout
    k_wlin<<<GTILES, 256, 0, stream>>>(z2, w_W, w_b, z_out);
    k_mlp<<<GTILES, 256, 0, stream>>>(z_out, nullptr, nullptr, 0, m1_W, m1_b, t1, sums + 0, sums + 64);
    k_bnstats<<<1, 64, 0, stream>>>(sums + 0, sums + 64, g1, b1, abc + 0, abc + 64);
    k_mlp<<<GTILES, 256, 0, stream>>>(t1, abc + 0, abc + 64, 1, m2_W, m2_b, t2, sums + 128, sums + 192);
    k_bnstats<<<1, 64, 0, stream>>>(sums + 128, sums + 192, g2, b2, abc + 128, abc + 192);
    k_mlp3<<<2048, 256, 0, stream>>>(t2, abc + 128, abc + 192, m3_W, m3_b, prob);
}

// Round 11
// 357.776 us; speedup vs baseline: 1.1577x; 1.0506x over previous
//
#include <hip/hip_runtime.h>
#include <cstdint>
#include <cstddef>

#define NN 100000
#define EE 1000000
#define EPSF 1e-5f
#define NBUK 391          // node buckets per relation: ceil(100000/256), dst>>8
#define NBUK2 (2*NBUK)    // both relations
#define NBLK 256          // edge-chunk blocks for hist/binscatter
#define EPB 7813          // ceil(2*EE / NBLK)
#define GSB 782           // scan blocks over NBUK2*NBLK entries (=200192/256)
#define GTILES ((NN + 63) / 64)   // 1563 64-node tiles

__device__ __forceinline__ void fatomic(float* p, float v) { unsafeAtomicAdd(p, v); }

// edge slot s in [0,2EE): rel 0 = pos, rel 1 = neg
__device__ __forceinline__ void edge_of(const int* __restrict__ pe, const int* __restrict__ ne,
                                        int s, int& src, int& dst, int& bucket) {
    if (s < EE) { src = pe[s]; dst = pe[EE + s]; bucket = dst >> 8; }
    else        { src = ne[s - EE]; dst = ne[s]; bucket = NBUK + (dst >> 8); }
}

// ---- pass 1: per-block bucket histogram ----
__global__ __launch_bounds__(256) void k_hist(const int* __restrict__ pe,
                                              const int* __restrict__ ne,
                                              int* __restrict__ hist) {
    __shared__ int lh[NBUK2];
    for (int i = threadIdx.x; i < NBUK2; i += 256) lh[i] = 0;
    __syncthreads();
    int start = blockIdx.x * EPB, end = min(start + EPB, 2 * EE);
    for (int s = start + threadIdx.x; s < end; s += 256) {
        int src, dst, bucket;
        edge_of(pe, ne, s, src, dst, bucket);
        atomicAdd(&lh[bucket], 1);
    }
    __syncthreads();
    for (int i = threadIdx.x; i < NBUK2; i += 256)
        hist[i * NBLK + blockIdx.x] = lh[i];   // bucket-major
}

// ---- generic hierarchical exclusive scan over NBUK2*NBLK ints ----
__global__ __launch_bounds__(256) void k_gscan1(const int* __restrict__ in,
                                                int* __restrict__ out,
                                                int* __restrict__ partials) {
    int i = blockIdx.x * 256 + threadIdx.x;
    int v = in[i];
    __shared__ int s[256];
    s[threadIdx.x] = v;
    __syncthreads();
    for (int off = 1; off < 256; off <<= 1) {
        int u = (threadIdx.x >= off) ? s[threadIdx.x - off] : 0;
        __syncthreads();
        s[threadIdx.x] += u;
        __syncthreads();
    }
    out[i] = s[threadIdx.x] - v;
    if (threadIdx.x == 255) partials[blockIdx.x] = s[255];
}

__global__ __launch_bounds__(1024) void k_gscan2(int* __restrict__ partials) {
    __shared__ int s[1024];
    int v = (threadIdx.x < GSB) ? partials[threadIdx.x] : 0;
    s[threadIdx.x] = v;
    __syncthreads();
    for (int off = 1; off < 1024; off <<= 1) {
        int u = (threadIdx.x >= off) ? s[threadIdx.x - off] : 0;
        __syncthreads();
        s[threadIdx.x] += u;
        __syncthreads();
    }
    if (threadIdx.x < GSB) partials[threadIdx.x] = s[threadIdx.x] - v;
}

__global__ __launch_bounds__(256) void k_gscan3(const int* __restrict__ partials,
                                                int* __restrict__ out) {
    out[blockIdx.x * 256 + threadIdx.x] += partials[blockIdx.x];
}

// ---- pass 2: scatter edges into bucket-grouped staging (block-exclusive runs) ----
__global__ __launch_bounds__(256) void k_binscatter(const int* __restrict__ pe,
                                                    const int* __restrict__ ne,
                                                    const int* __restrict__ soff,
                                                    unsigned long long* __restrict__ staging) {
    __shared__ int cur[NBUK2];
    for (int i = threadIdx.x; i < NBUK2; i += 256)
        cur[i] = soff[i * NBLK + blockIdx.x];
    __syncthreads();
    int start = blockIdx.x * EPB, end = min(start + EPB, 2 * EE);
    for (int s = start + threadIdx.x; s < end; s += 256) {
        int src, dst, bucket;
        edge_of(pe, ne, s, src, dst, bucket);
        int pos = atomicAdd(&cur[bucket], 1);
        staging[pos] = ((unsigned long long)(unsigned)dst << 32) | (unsigned)src;
    }
}

// ---- pass 3: per-bucket local build: rp (degree+scan in LDS) + csr scatter ----
__global__ __launch_bounds__(256) void k_local(const unsigned long long* __restrict__ staging,
                                               const int* __restrict__ soff,
                                               int* __restrict__ rpP,
                                               int* __restrict__ rpN,
                                               int* __restrict__ csrAll) {
    int bucket = blockIdx.x;
    int rel = bucket >= NBUK;
    int nodeBase = (bucket - rel * NBUK) << 8;
    int bstart = soff[bucket * NBLK];
    int bend = (bucket == NBUK2 - 1) ? 2 * EE : soff[(bucket + 1) * NBLK];
    int tid = threadIdx.x;
    __shared__ int deg[256], sc[256];
    deg[tid] = 0;
    __syncthreads();
    for (int i = bstart + tid; i < bend; i += 256) {
        int d = (int)(staging[i] >> 32) & 255;
        atomicAdd(&deg[d], 1);
    }
    __syncthreads();
    int dv = deg[tid];
    sc[tid] = dv;
    __syncthreads();
    for (int off = 1; off < 256; off <<= 1) {
        int u = (tid >= off) ? sc[tid - off] : 0;
        __syncthreads();
        sc[tid] += u;
        __syncthreads();
    }
    int lrp = sc[tid] - dv;  // bucket-local exclusive prefix
    int nCount = min(256, NN - nodeBase);
    int relbase = rel ? EE : 0;
    if (tid < nCount) (rel ? rpN : rpP)[nodeBase + tid] = bstart - relbase + lrp;
    if (bucket == NBUK - 1 && tid == 0) rpP[NN] = EE;
    if (bucket == NBUK2 - 1 && tid == 0) rpN[NN] = EE;
    deg[tid] = lrp;          // reuse as cursor
    __syncthreads();
    for (int i = bstart + tid; i < bend; i += 256) {
        unsigned long long v = staging[i];
        int d = (int)(v >> 32) & 255;
        int src = (int)(v & 0xffffffffu);
        int slot = atomicAdd(&deg[d], 1);
        csrAll[bstart + slot] = src;
    }
}

// ---- pre-transform 64->32 x3: xp=x@Wp, xn=x@Wn, xs=x@Ws ----
// 192 threads: wave m owns matrix m; lane holds col (l&31) weights in VGPRs;
// half-waves process 2 nodes/iter via LDS float4 broadcast (4 FMA / LDS op, no shuffles)
__global__ __launch_bounds__(192) __attribute__((amdgpu_waves_per_eu(2, 4)))
void k_xf1(const float* __restrict__ x,
           const float* __restrict__ Wp,
           const float* __restrict__ Wn,
           const float* __restrict__ Ws,
           float* __restrict__ xp,
           float* __restrict__ xn,
           float* __restrict__ xs) {
    __shared__ float sx[64 * 64];   // x tile (16KB)
    int base = blockIdx.x * 64;
    int tid = threadIdx.x;
    int wvm = tid >> 6;             // 0,1,2 -> matrix p,n,s
    int l = tid & 63;
    int j = l & 31;                 // output col
    int half = l >> 5;              // node parity
    // stage x tile: 64 rows x 64 cols = 1024 float4, strided over 192 threads
    for (int idx = tid; idx < 1024; idx += 192) {
        int row = idx >> 4, f = idx & 15;
        int n = base + row;
        float4 v = (n < NN) ? *(const float4*)&x[(size_t)n * 64 + f * 4]
                            : make_float4(0.f, 0.f, 0.f, 0.f);
        *(float4*)&sx[row * 64 + f * 4] = v;
    }
    const float* W = (wvm == 0) ? Wp : (wvm == 1) ? Wn : Ws;
    float* outm = (wvm == 0) ? xp : (wvm == 1) ? xn : xs;
    float w[64];
    #pragma unroll
    for (int k = 0; k < 64; k++) w[k] = W[k * 32 + j];
    __syncthreads();
    #pragma unroll 1
    for (int i = 0; i < 32; i++) {
        int nl = 2 * i + half;
        int n = base + nl;
        float a0 = 0.f, a1 = 0.f, a2 = 0.f, a3 = 0.f;
        #pragma unroll
        for (int q = 0; q < 16; q++) {
            float4 xv = *(const float4*)&sx[nl * 64 + q * 4];
            a0 += xv.x * w[q * 4 + 0];
            a1 += xv.y * w[q * 4 + 1];
            a2 += xv.z * w[q * 4 + 2];
            a3 += xv.w * w[q * 4 + 3];
        }
        if (n < NN) outm[(size_t)n * 32 + j] = (a0 + a1) + (a2 + a3);
    }
}

// ---- pre-transform 32->32 x3, same structure ----
__global__ __launch_bounds__(192) __attribute__((amdgpu_waves_per_eu(2, 4)))
void k_xf2(const float* __restrict__ z,
           const float* __restrict__ Wp,
           const float* __restrict__ Wn,
           const float* __restrict__ Ws,
           float* __restrict__ xp,
           float* __restrict__ xn,
           float* __restrict__ xs) {
    __shared__ float sx[64 * 32];   // z tile (8KB)
    int base = blockIdx.x * 64;
    int tid = threadIdx.x;
    int wvm = tid >> 6;
    int l = tid & 63;
    int j = l & 31;
    int half = l >> 5;
    for (int idx = tid; idx < 512; idx += 192) {
        int row = idx >> 3, f = idx & 7;
        int n = base + row;
        float4 v = (n < NN) ? *(const float4*)&z[(size_t)n * 32 + f * 4]
                            : make_float4(0.f, 0.f, 0.f, 0.f);
        *(float4*)&sx[row * 32 + f * 4] = v;
    }
    const float* W = (wvm == 0) ? Wp : (wvm == 1) ? Wn : Ws;
    float* outm = (wvm == 0) ? xp : (wvm == 1) ? xn : xs;
    float w[32];
    #pragma unroll
    for (int k = 0; k < 32; k++) w[k] = W[k * 32 + j];
    __syncthreads();
    #pragma unroll 1
    for (int i = 0; i < 32; i++) {
        int nl = 2 * i + half;
        int n = base + nl;
        float a0 = 0.f, a1 = 0.f, a2 = 0.f, a3 = 0.f;
        #pragma unroll
        for (int q = 0; q < 8; q++) {
            float4 xv = *(const float4*)&sx[nl * 32 + q * 4];
            a0 += xv.x * w[q * 4 + 0];
            a1 += xv.y * w[q * 4 + 1];
            a2 += xv.z * w[q * 4 + 2];
            a3 += xv.w * w[q * 4 + 3];
        }
        if (n < NN) outm[(size_t)n * 32 + j] = (a0 + a1) + (a2 + a3);
    }
}

// ---- accumulate one relation's neighbors ----
__device__ __forceinline__ float pull_rel(const float* __restrict__ xsrc,
                                          const int* __restrict__ csr,
                                          int b0, int b1, int j, float acc) {
    for (int base = b0; base < b1; base += 32) {
        int rem = b1 - base;
        int cnt = min(rem, 32);
        int idx = (j < rem) ? csr[base + j] : 0;
        int i = 0;
        for (; i + 4 <= cnt; i += 4) {
            int s0 = __shfl(idx, i, 32);
            int s1 = __shfl(idx, i + 1, 32);
            int s2 = __shfl(idx, i + 2, 32);
            int s3 = __shfl(idx, i + 3, 32);
            float v0 = xsrc[(size_t)s0 * 32 + j];
            float v1 = xsrc[(size_t)s1 * 32 + j];
            float v2 = xsrc[(size_t)s2 * 32 + j];
            float v3 = xsrc[(size_t)s3 * 32 + j];
            acc += v0; acc += v1; acc += v2; acc += v3;
        }
        for (; i < cnt; i++) {
            int s = __shfl(idx, i, 32);
            acc += xsrc[(size_t)s * 32 + j];
        }
    }
    return acc;
}

// ---- pull aggregation + combine + tanh ----
__global__ __launch_bounds__(256) void k_pull(const float* __restrict__ xp,
                                              const float* __restrict__ xn,
                                              const float* __restrict__ xs,
                                              const int* __restrict__ rpP,
                                              const int* __restrict__ csrP,
                                              const int* __restrict__ rpN,
                                              const int* __restrict__ csrN,
                                              const float* __restrict__ bp,
                                              const float* __restrict__ bn,
                                              const float* __restrict__ bs,
                                              float* __restrict__ out) {
    int j = threadIdx.x & 31;
    int hw = (blockIdx.x * 256 + threadIdx.x) >> 5;
    const int nhw = (2048 * 256) >> 5;
    float bpj = bp[j], bnj = bn[j], bsj = bs[j];
    for (int n = hw; n < NN; n += nhw) {
        int p0 = rpP[n], p1 = rpP[n + 1];
        int n0 = rpN[n], n1 = rpN[n + 1];
        float acc = xs[(size_t)n * 32 + j] + bsj
                  + (float)(p1 - p0) * bpj + (float)(n1 - n0) * bnj;
        acc = pull_rel(xp, csrP, p0, p1, j, acc);
        acc = pull_rel(xn, csrN, n0, n1, j, acc);
        out[(size_t)n * 32 + j] = tanhf(acc);
    }
}

// ---- z = tanh(z2 @ Wl + bl): 32->64, 64-row tiles (output 0) ----
__global__ __launch_bounds__(256) __attribute__((amdgpu_waves_per_eu(2, 4)))
void k_wlin(const float* __restrict__ z2,
            const float* __restrict__ Wl,
            const float* __restrict__ bl,
            float* __restrict__ z) {
    __shared__ float sx[64 * 32];   // z2 tile (8KB)
    int base = blockIdx.x * 64;
    int tid = threadIdx.x;
    int lane = tid & 63;
    int wv = tid >> 6;
    {
        int row = tid >> 2, c4 = tid & 3;
        int n = base + row;
        #pragma unroll
        for (int m = 0; m < 2; m++) {
            int f = c4 + 4 * m;
            float4 v = (n < NN) ? *(const float4*)&z2[(size_t)n * 32 + f * 4]
                                : make_float4(0.f, 0.f, 0.f, 0.f);
            *(float4*)&sx[row * 32 + f * 4] = v;
        }
    }
    float wl[32];
    #pragma unroll
    for (int k = 0; k < 32; k++) wl[k] = Wl[k * 64 + lane];
    float blj = bl[lane];
    __syncthreads();
    #pragma unroll 1
    for (int i = 0; i < 16; i++) {
        int nl = i * 4 + wv;
        int n = base + nl;
        float a0 = 0.f, a1c = 0.f, a2 = 0.f, a3 = 0.f;
        #pragma unroll
        for (int q = 0; q < 8; q++) {
            float4 xv = *(const float4*)&sx[nl * 32 + q * 4];
            a0 += xv.x * wl[q * 4 + 0];
            a1c += xv.y * wl[q * 4 + 1];
            a2 += xv.z * wl[q * 4 + 2];
            a3 += xv.w * wl[q * 4 + 3];
        }
        if (n < NN) z[(size_t)n * 64 + lane] = tanhf(blj + ((a0 + a1c) + (a2 + a3)));
    }
}

// ---- shared MLP GEMM: out = [relu(in*a+c) or in] @ W + b, column stats ----
__global__ __launch_bounds__(256) __attribute__((amdgpu_waves_per_eu(2, 4)))
void k_mlp(const float* __restrict__ in,
           const float* __restrict__ a1,
           const float* __restrict__ c1,
           int doBN,
           const float* __restrict__ W,
           const float* __restrict__ b,
           float* __restrict__ out,
           float* __restrict__ colsum,
           float* __restrict__ colsq) {
    __shared__ float sh[64 * 64];   // staged (optionally BN+ReLU'd) input tile (16KB)
    __shared__ float red[256], red2[256];
    int base = blockIdx.x * 64;
    int tid = threadIdx.x;
    int lane = tid & 63;
    int wv = tid >> 6;
    {
        int row = tid >> 2, c4 = tid & 3;   // 4 threads/row, 4 float4 each
        int n = base + row;
        #pragma unroll
        for (int m = 0; m < 4; m++) {
            int f = c4 + 4 * m;             // float4 index 0..15
            float4 tv = (n < NN) ? *(const float4*)&in[(size_t)n * 64 + f * 4]
                                 : make_float4(0.f, 0.f, 0.f, 0.f);
            if (doBN) {
                float4 av = *(const float4*)&a1[f * 4];
                float4 cv = *(const float4*)&c1[f * 4];
                tv.x = fmaxf(tv.x * av.x + cv.x, 0.f);
                tv.y = fmaxf(tv.y * av.y + cv.y, 0.f);
                tv.z = fmaxf(tv.z * av.z + cv.z, 0.f);
                tv.w = fmaxf(tv.w * av.w + cv.w, 0.f);
            }
            *(float4*)&sh[row * 64 + f * 4] = tv;
        }
    }
    float w[64];
    #pragma unroll
    for (int k = 0; k < 64; k++) w[k] = W[k * 64 + lane];
    float bj = b[lane];
    __syncthreads();
    float lsum = 0.f, lsq = 0.f;
    #pragma unroll 1
    for (int i = 0; i < 16; i++) {
        int nl = i * 4 + wv;
        int n = base + nl;
        float a0 = 0.f, a1c = 0.f, a2 = 0.f, a3 = 0.f;
        #pragma unroll
        for (int q = 0; q < 16; q++) {
            float4 xv = *(const float4*)&sh[nl * 64 + q * 4];
            a0 += xv.x * w[q * 4 + 0];
            a1c += xv.y * w[q * 4 + 1];
            a2 += xv.z * w[q * 4 + 2];
            a3 += xv.w * w[q * 4 + 3];
        }
        float s = bj + ((a0 + a1c) + (a2 + a3));
        if (n < NN) {
            out[(size_t)n * 64 + lane] = s;
            lsum += s; lsq += s * s;
        }
    }
    red[tid] = lsum; red2[tid] = lsq;
    __syncthreads();
    if (tid < 64) {
        float a = red[tid] + red[tid + 64] + red[tid + 128] + red[tid + 192];
        float q = red2[tid] + red2[tid + 64] + red2[tid + 128] + red2[tid + 192];
        fatomic(&colsum[tid], a);
        fatomic(&colsq[tid], q);
    }
}

// ---- BN stats -> affine coefficients a, c (h_norm = t*a + c) ----
__global__ void k_bnstats(const float* __restrict__ colsum, const float* __restrict__ colsq,
                          const float* __restrict__ g, const float* __restrict__ beta,
                          float* __restrict__ a, float* __restrict__ c) {
    int j = threadIdx.x;
    if (j < 64) {
        float m = colsum[j] * (1.f / NN);
        float v = colsq[j] * (1.f / NN) - m * m;
        float aj = g[j] * rsqrtf(v + EPSF);
        a[j] = aj;
        c[j] = beta[j] - m * aj;
    }
}

// ---- prob = sigmoid(relu(t2*a2+c2) @ m3_W + m3_b) ----
__global__ __launch_bounds__(256) void k_mlp3(const float* __restrict__ t2,
                                              const float* __restrict__ a2,
                                              const float* __restrict__ c2,
                                              const float* __restrict__ W3,
                                              const float* __restrict__ b3,
                                              float* __restrict__ prob) {
    int j = threadIdx.x & 63;
    int r = threadIdx.x >> 6;
    float aj = a2[j], cj = c2[j], wj = W3[j], bb = b3[0];
    for (int n = blockIdx.x * 4 + r; n < NN; n += 2048 * 4) {
        float h = fmaxf(t2[(size_t)n * 64 + j] * aj + cj, 0.f) * wj;
        #pragma unroll
        for (int off = 32; off > 0; off >>= 1) h += __shfl_xor(h, off, 64);
        if (j == 0) prob[n] = 1.f / (1.f + expf(-(h + bb)));
    }
}

extern "C" void kernel_launch(void* const* d_in, const int* in_sizes, int n_in,
                              void* d_out, int out_size, void* d_ws, size_t ws_size,
                              hipStream_t stream) {
    const float* init_emb = (const float*)d_in[0];
    const int* pe = (const int*)d_in[1];
    const int* ne = (const int*)d_in[2];
    const float* c1_Wp = (const float*)d_in[3];  const float* c1_bp = (const float*)d_in[4];
    const float* c1_Wn = (const float*)d_in[5];  const float* c1_bn = (const float*)d_in[6];
    const float* c1_Ws = (const float*)d_in[7];  const float* c1_bs = (const float*)d_in[8];
    const float* c2_Wp = (const float*)d_in[9];  const float* c2_bp = (const float*)d_in[10];
    const float* c2_Wn = (const float*)d_in[11]; const float* c2_bn = (const float*)d_in[12];
    const float* c2_Ws = (const float*)d_in[13]; const float* c2_bs = (const float*)d_in[14];
    const float* w_W = (const float*)d_in[15];   const float* w_b = (const float*)d_in[16];
    const float* m1_W = (const float*)d_in[17];  const float* m1_b = (const float*)d_in[18];
    const float* g1 = (const float*)d_in[19];    const float* b1 = (const float*)d_in[20];
    const float* m2_W = (const float*)d_in[21];  const float* m2_b = (const float*)d_in[22];
    const float* g2 = (const float*)d_in[23];    const float* b2 = (const float*)d_in[24];
    const float* m3_W = (const float*)d_in[25];  const float* m3_b = (const float*)d_in[26];

    // ---- workspace arena ----
    size_t off = 0;
    auto alloc = [&](size_t bytes) -> void* {
        void* r = (char*)d_ws + off;
        off += (bytes + 255) & ~(size_t)255;
        return r;
    };
    // zero region (front): only BN stat accumulators
    float* sums = (float*)alloc(256 * 4);               // colsum1, colsq1, colsum2, colsq2
    size_t zero_bytes = off;
    // CSR-build region (dead after second k_pull; t2 aliases it later)
    size_t csr_region = off;
    int*   hist = (int*)alloc((size_t)NBUK2 * NBLK * 4);        // 800KB
    int*   soff = (int*)alloc((size_t)NBUK2 * NBLK * 4);        // 800KB
    int*   part = (int*)alloc((size_t)1024 * 4);
    unsigned long long* staging = (unsigned long long*)alloc((size_t)2 * EE * 8);  // 16MB
    int*   csrAll = (int*)alloc((size_t)2 * EE * 4);            // 8MB
    // persistent
    int*   rpP  = (int*)alloc((size_t)(NN + 1) * 4);
    int*   rpN  = (int*)alloc((size_t)(NN + 1) * 4);
    float* R1   = (float*)alloc((size_t)NN * 96 * 4);   // {xp,xn,xs} layer1 -> layer2 -> t1
    float* z1   = (float*)alloc((size_t)NN * 32 * 4);
    float* z2   = (float*)alloc((size_t)NN * 32 * 4);
    float* abc  = (float*)alloc(256 * 4);               // a1, c1, a2, c2

    int* csrP = csrAll;
    int* csrN = csrAll + (size_t)EE;
    float* xp = R1;
    float* xn = R1 + (size_t)NN * 32;
    float* xs = R1 + (size_t)NN * 64;
    float* t1 = R1;                                     // dead xp/xn region after wlin
    float* t2 = (float*)((char*)d_ws + csr_region);     // aliases CSR-build scratch (25.6MB fits)

    float* z_out = (float*)d_out;                       // [N,64]
    float* prob  = (float*)d_out + (size_t)NN * 64;     // [N,1]

    hipMemsetAsync(d_ws, 0, zero_bytes, stream);

    // ---- CSR build: hist -> scan -> bin scatter -> per-bucket local build ----
    k_hist<<<NBLK, 256, 0, stream>>>(pe, ne, hist);
    k_gscan1<<<GSB, 256, 0, stream>>>(hist, soff, part);
    k_gscan2<<<1, 1024, 0, stream>>>(part);
    k_gscan3<<<GSB, 256, 0, stream>>>(part, soff);
    k_binscatter<<<NBLK, 256, 0, stream>>>(pe, ne, soff, staging);
    k_local<<<NBUK2, 256, 0, stream>>>(staging, soff, rpP, rpN, csrAll);

    // layer 1
    k_xf1<<<GTILES, 192, 0, stream>>>(init_emb, c1_Wp, c1_Wn, c1_Ws, xp, xn, xs);
    k_pull<<<2048, 256, 0, stream>>>(xp, xn, xs, rpP, csrP, rpN, csrN, c1_bp, c1_bn, c1_bs, z1);
    // layer 2
    k_xf2<<<GTILES, 192, 0, stream>>>(z1, c2_Wp, c2_Wn, c2_Ws, xp, xn, xs);
    k_pull<<<2048, 256, 0, stream>>>(xp, xn, xs, rpP, csrP, rpN, csrN, c2_bp, c2_bn, c2_bs, z2);
    // readout
    k_wlin<<<GTILES, 256, 0, stream>>>(z2, w_W, w_b, z_out);
    k_mlp<<<GTILES, 256, 0, stream>>>(z_out, nullptr, nullptr, 0, m1_W, m1_b, t1, sums + 0, sums + 64);
    k_bnstats<<<1, 64, 0, stream>>>(sums + 0, sums + 64, g1, b1, abc + 0, abc + 64);
    k_mlp<<<GTILES, 256, 0, stream>>>(t1, abc + 0, abc + 64, 1, m2_W, m2_b, t2, sums + 128, sums + 192);
    k_bnstats<<<1, 64, 0, stream>>>(sums + 128, sums + 192, g2, b2, abc + 128, abc + 192);
    k_mlp3<<<2048, 256, 0, stream>>>(t2, abc + 128, abc + 192, m3_W, m3_b, prob);
}

// Round 12
// 356.431 us; speedup vs baseline: 1.1621x; 1.0038x over previous
//
#include <hip/hip_runtime.h>
#include <cstdint>
#include <cstddef>

#define NN 100000
#define EE 1000000
#define EPSF 1e-5f
#define NBUK 391          // node buckets per relation: ceil(100000/256), dst>>8
#define NBUK2 (2*NBUK)    // both relations
#define NBLK 256          // edge-chunk blocks for hist/binscatter
#define EPB 7813          // ceil(2*EE / NBLK)
#define GSB 782           // scan blocks over NBUK2*NBLK entries (=200192/256)
#define GTILES ((NN + 63) / 64)   // 1563 64-node tiles

typedef __attribute__((ext_vector_type(8))) short bf16x8;
typedef __attribute__((ext_vector_type(4))) float f32x4;

__device__ __forceinline__ void fatomic(float* p, float v) { unsafeAtomicAdd(p, v); }

__device__ __forceinline__ short f2bf(float f) {
    unsigned u = __float_as_uint(f);
    u += 0x7FFF + ((u >> 16) & 1);   // round-to-nearest-even
    return (short)(u >> 16);
}

// edge slot s in [0,2EE): rel 0 = pos, rel 1 = neg
__device__ __forceinline__ void edge_of(const int* __restrict__ pe, const int* __restrict__ ne,
                                        int s, int& src, int& dst, int& bucket) {
    if (s < EE) { src = pe[s]; dst = pe[EE + s]; bucket = dst >> 8; }
    else        { src = ne[s - EE]; dst = ne[s]; bucket = NBUK + (dst >> 8); }
}

// ---- pass 1: per-block bucket histogram ----
__global__ __launch_bounds__(256) void k_hist(const int* __restrict__ pe,
                                              const int* __restrict__ ne,
                                              int* __restrict__ hist) {
    __shared__ int lh[NBUK2];
    for (int i = threadIdx.x; i < NBUK2; i += 256) lh[i] = 0;
    __syncthreads();
    int start = blockIdx.x * EPB, end = min(start + EPB, 2 * EE);
    for (int s = start + threadIdx.x; s < end; s += 256) {
        int src, dst, bucket;
        edge_of(pe, ne, s, src, dst, bucket);
        atomicAdd(&lh[bucket], 1);
    }
    __syncthreads();
    for (int i = threadIdx.x; i < NBUK2; i += 256)
        hist[i * NBLK + blockIdx.x] = lh[i];   // bucket-major
}

// ---- generic hierarchical exclusive scan over NBUK2*NBLK ints ----
__global__ __launch_bounds__(256) void k_gscan1(const int* __restrict__ in,
                                                int* __restrict__ out,
                                                int* __restrict__ partials) {
    int i = blockIdx.x * 256 + threadIdx.x;
    int v = in[i];
    __shared__ int s[256];
    s[threadIdx.x] = v;
    __syncthreads();
    for (int off = 1; off < 256; off <<= 1) {
        int u = (threadIdx.x >= off) ? s[threadIdx.x - off] : 0;
        __syncthreads();
        s[threadIdx.x] += u;
        __syncthreads();
    }
    out[i] = s[threadIdx.x] - v;
    if (threadIdx.x == 255) partials[blockIdx.x] = s[255];
}

__global__ __launch_bounds__(1024) void k_gscan2(int* __restrict__ partials) {
    __shared__ int s[1024];
    int v = (threadIdx.x < GSB) ? partials[threadIdx.x] : 0;
    s[threadIdx.x] = v;
    __syncthreads();
    for (int off = 1; off < 1024; off <<= 1) {
        int u = (threadIdx.x >= off) ? s[threadIdx.x - off] : 0;
        __syncthreads();
        s[threadIdx.x] += u;
        __syncthreads();
    }
    if (threadIdx.x < GSB) partials[threadIdx.x] = s[threadIdx.x] - v;
}

__global__ __launch_bounds__(256) void k_gscan3(const int* __restrict__ partials,
                                                int* __restrict__ out) {
    out[blockIdx.x * 256 + threadIdx.x] += partials[blockIdx.x];
}

// ---- pass 2: scatter edges into bucket-grouped staging (block-exclusive runs) ----
__global__ __launch_bounds__(256) void k_binscatter(const int* __restrict__ pe,
                                                    const int* __restrict__ ne,
                                                    const int* __restrict__ soff,
                                                    unsigned long long* __restrict__ staging) {
    __shared__ int cur[NBUK2];
    for (int i = threadIdx.x; i < NBUK2; i += 256)
        cur[i] = soff[i * NBLK + blockIdx.x];
    __syncthreads();
    int start = blockIdx.x * EPB, end = min(start + EPB, 2 * EE);
    for (int s = start + threadIdx.x; s < end; s += 256) {
        int src, dst, bucket;
        edge_of(pe, ne, s, src, dst, bucket);
        int pos = atomicAdd(&cur[bucket], 1);
        staging[pos] = ((unsigned long long)(unsigned)dst << 32) | (unsigned)src;
    }
}

// ---- pass 3: per-bucket local build: rp (degree+scan in LDS) + csr scatter ----
__global__ __launch_bounds__(256) void k_local(const unsigned long long* __restrict__ staging,
                                               const int* __restrict__ soff,
                                               int* __restrict__ rpP,
                                               int* __restrict__ rpN,
                                               int* __restrict__ csrAll) {
    int bucket = blockIdx.x;
    int rel = bucket >= NBUK;
    int nodeBase = (bucket - rel * NBUK) << 8;
    int bstart = soff[bucket * NBLK];
    int bend = (bucket == NBUK2 - 1) ? 2 * EE : soff[(bucket + 1) * NBLK];
    int tid = threadIdx.x;
    __shared__ int deg[256], sc[256];
    deg[tid] = 0;
    __syncthreads();
    for (int i = bstart + tid; i < bend; i += 256) {
        int d = (int)(staging[i] >> 32) & 255;
        atomicAdd(&deg[d], 1);
    }
    __syncthreads();
    int dv = deg[tid];
    sc[tid] = dv;
    __syncthreads();
    for (int off = 1; off < 256; off <<= 1) {
        int u = (tid >= off) ? sc[tid - off] : 0;
        __syncthreads();
        sc[tid] += u;
        __syncthreads();
    }
    int lrp = sc[tid] - dv;  // bucket-local exclusive prefix
    int nCount = min(256, NN - nodeBase);
    int relbase = rel ? EE : 0;
    if (tid < nCount) (rel ? rpN : rpP)[nodeBase + tid] = bstart - relbase + lrp;
    if (bucket == NBUK - 1 && tid == 0) rpP[NN] = EE;
    if (bucket == NBUK2 - 1 && tid == 0) rpN[NN] = EE;
    deg[tid] = lrp;          // reuse as cursor
    __syncthreads();
    for (int i = bstart + tid; i < bend; i += 256) {
        unsigned long long v = staging[i];
        int d = (int)(v >> 32) & 255;
        int src = (int)(v & 0xffffffffu);
        int slot = atomicAdd(&deg[d], 1);
        csrAll[bstart + slot] = src;
    }
}

// ---- pre-transform 64->32 x3: xp=x@Wp, xn=x@Wn, xs=x@Ws ----
__global__ __launch_bounds__(192) __attribute__((amdgpu_waves_per_eu(2, 4)))
void k_xf1(const float* __restrict__ x,
           const float* __restrict__ Wp,
           const float* __restrict__ Wn,
           const float* __restrict__ Ws,
           float* __restrict__ xp,
           float* __restrict__ xn,
           float* __restrict__ xs) {
    __shared__ float sx[64 * 64];   // x tile (16KB)
    int base = blockIdx.x * 64;
    int tid = threadIdx.x;
    int wvm = tid >> 6;             // 0,1,2 -> matrix p,n,s
    int l = tid & 63;
    int j = l & 31;                 // output col
    int half = l >> 5;              // node parity
    for (int idx = tid; idx < 1024; idx += 192) {
        int row = idx >> 4, f = idx & 15;
        int n = base + row;
        float4 v = (n < NN) ? *(const float4*)&x[(size_t)n * 64 + f * 4]
                            : make_float4(0.f, 0.f, 0.f, 0.f);
        *(float4*)&sx[row * 64 + f * 4] = v;
    }
    const float* W = (wvm == 0) ? Wp : (wvm == 1) ? Wn : Ws;
    float* outm = (wvm == 0) ? xp : (wvm == 1) ? xn : xs;
    float w[64];
    #pragma unroll
    for (int k = 0; k < 64; k++) w[k] = W[k * 32 + j];
    __syncthreads();
    #pragma unroll 1
    for (int i = 0; i < 32; i++) {
        int nl = 2 * i + half;
        int n = base + nl;
        float a0 = 0.f, a1 = 0.f, a2 = 0.f, a3 = 0.f;
        #pragma unroll
        for (int q = 0; q < 16; q++) {
            float4 xv = *(const float4*)&sx[nl * 64 + q * 4];
            a0 += xv.x * w[q * 4 + 0];
            a1 += xv.y * w[q * 4 + 1];
            a2 += xv.z * w[q * 4 + 2];
            a3 += xv.w * w[q * 4 + 3];
        }
        if (n < NN) outm[(size_t)n * 32 + j] = (a0 + a1) + (a2 + a3);
    }
}

// ---- pre-transform 32->32 x3, same structure ----
__global__ __launch_bounds__(192) __attribute__((amdgpu_waves_per_eu(2, 4)))
void k_xf2(const float* __restrict__ z,
           const float* __restrict__ Wp,
           const float* __restrict__ Wn,
           const float* __restrict__ Ws,
           float* __restrict__ xp,
           float* __restrict__ xn,
           float* __restrict__ xs) {
    __shared__ float sx[64 * 32];   // z tile (8KB)
    int base = blockIdx.x * 64;
    int tid = threadIdx.x;
    int wvm = tid >> 6;
    int l = tid & 63;
    int j = l & 31;
    int half = l >> 5;
    for (int idx = tid; idx < 512; idx += 192) {
        int row = idx >> 3, f = idx & 7;
        int n = base + row;
        float4 v = (n < NN) ? *(const float4*)&z[(size_t)n * 32 + f * 4]
                            : make_float4(0.f, 0.f, 0.f, 0.f);
        *(float4*)&sx[row * 32 + f * 4] = v;
    }
    const float* W = (wvm == 0) ? Wp : (wvm == 1) ? Wn : Ws;
    float* outm = (wvm == 0) ? xp : (wvm == 1) ? xn : xs;
    float w[32];
    #pragma unroll
    for (int k = 0; k < 32; k++) w[k] = W[k * 32 + j];
    __syncthreads();
    #pragma unroll 1
    for (int i = 0; i < 32; i++) {
        int nl = 2 * i + half;
        int n = base + nl;
        float a0 = 0.f, a1 = 0.f, a2 = 0.f, a3 = 0.f;
        #pragma unroll
        for (int q = 0; q < 8; q++) {
            float4 xv = *(const float4*)&sx[nl * 32 + q * 4];
            a0 += xv.x * w[q * 4 + 0];
            a1 += xv.y * w[q * 4 + 1];
            a2 += xv.z * w[q * 4 + 2];
            a3 += xv.w * w[q * 4 + 3];
        }
        if (n < NN) outm[(size_t)n * 32 + j] = (a0 + a1) + (a2 + a3);
    }
}

// ---- accumulate one relation's neighbors ----
__device__ __forceinline__ float pull_rel(const float* __restrict__ xsrc,
                                          const int* __restrict__ csr,
                                          int b0, int b1, int j, float acc) {
    for (int base = b0; base < b1; base += 32) {
        int rem = b1 - base;
        int cnt = min(rem, 32);
        int idx = (j < rem) ? csr[base + j] : 0;
        int i = 0;
        for (; i + 4 <= cnt; i += 4) {
            int s0 = __shfl(idx, i, 32);
            int s1 = __shfl(idx, i + 1, 32);
            int s2 = __shfl(idx, i + 2, 32);
            int s3 = __shfl(idx, i + 3, 32);
            float v0 = xsrc[(size_t)s0 * 32 + j];
            float v1 = xsrc[(size_t)s1 * 32 + j];
            float v2 = xsrc[(size_t)s2 * 32 + j];
            float v3 = xsrc[(size_t)s3 * 32 + j];
            acc += v0; acc += v1; acc += v2; acc += v3;
        }
        for (; i < cnt; i++) {
            int s = __shfl(idx, i, 32);
            acc += xsrc[(size_t)s * 32 + j];
        }
    }
    return acc;
}

// ---- pull aggregation + combine + tanh ----
__global__ __launch_bounds__(256) void k_pull(const float* __restrict__ xp,
                                              const float* __restrict__ xn,
                                              const float* __restrict__ xs,
                                              const int* __restrict__ rpP,
                                              const int* __restrict__ csrP,
                                              const int* __restrict__ rpN,
                                              const int* __restrict__ csrN,
                                              const float* __restrict__ bp,
                                              const float* __restrict__ bn,
                                              const float* __restrict__ bs,
                                              float* __restrict__ out) {
    int j = threadIdx.x & 31;
    int hw = (blockIdx.x * 256 + threadIdx.x) >> 5;
    const int nhw = (2048 * 256) >> 5;
    float bpj = bp[j], bnj = bn[j], bsj = bs[j];
    for (int n = hw; n < NN; n += nhw) {
        int p0 = rpP[n], p1 = rpP[n + 1];
        int n0 = rpN[n], n1 = rpN[n + 1];
        float acc = xs[(size_t)n * 32 + j] + bsj
                  + (float)(p1 - p0) * bpj + (float)(n1 - n0) * bnj;
        acc = pull_rel(xp, csrP, p0, p1, j, acc);
        acc = pull_rel(xn, csrN, n0, n1, j, acc);
        out[(size_t)n * 32 + j] = tanhf(acc);
    }
}

// ---- z = tanh(z2 @ Wl + bl): 32->64, 64-row tiles (output 0) ----
__global__ __launch_bounds__(256) __attribute__((amdgpu_waves_per_eu(2, 4)))
void k_wlin(const float* __restrict__ z2,
            const float* __restrict__ Wl,
            const float* __restrict__ bl,
            float* __restrict__ z) {
    __shared__ float sx[64 * 32];   // z2 tile (8KB)
    int base = blockIdx.x * 64;
    int tid = threadIdx.x;
    int lane = tid & 63;
    int wv = tid >> 6;
    {
        int row = tid >> 2, c4 = tid & 3;
        int n = base + row;
        #pragma unroll
        for (int m = 0; m < 2; m++) {
            int f = c4 + 4 * m;
            float4 v = (n < NN) ? *(const float4*)&z2[(size_t)n * 32 + f * 4]
                                : make_float4(0.f, 0.f, 0.f, 0.f);
            *(float4*)&sx[row * 32 + f * 4] = v;
        }
    }
    float wl[32];
    #pragma unroll
    for (int k = 0; k < 32; k++) wl[k] = Wl[k * 64 + lane];
    float blj = bl[lane];
    __syncthreads();
    #pragma unroll 1
    for (int i = 0; i < 16; i++) {
        int nl = i * 4 + wv;
        int n = base + nl;
        float a0 = 0.f, a1c = 0.f, a2 = 0.f, a3 = 0.f;
        #pragma unroll
        for (int q = 0; q < 8; q++) {
            float4 xv = *(const float4*)&sx[nl * 32 + q * 4];
            a0 += xv.x * wl[q * 4 + 0];
            a1c += xv.y * wl[q * 4 + 1];
            a2 += xv.z * wl[q * 4 + 2];
            a3 += xv.w * wl[q * 4 + 3];
        }
        if (n < NN) z[(size_t)n * 64 + lane] = tanhf(blj + ((a0 + a1c) + (a2 + a3)));
    }
}

// ---- MFMA MLP GEMM: out = [relu(in*a+c) or in] @ W + b, column stats ----
// 64-row tile, 4 waves x 16 rows; bf16 16x16x32 MFMA, K=64 = 2 insts, 4 col-tiles.
// Fragment k-map per 16x16x32: elem i<4 -> k=kg*4+i, i>=4 -> k=16+kg*4+(i-4), per 32-k half.
__global__ __launch_bounds__(256) __attribute__((amdgpu_waves_per_eu(2, 4)))
void k_mlp(const float* __restrict__ in,
           const float* __restrict__ a1,
           const float* __restrict__ c1,
           int doBN,
           const float* __restrict__ W,
           const float* __restrict__ b,
           float* __restrict__ out,
           float* __restrict__ colsum,
           float* __restrict__ colsq) {
    __shared__ float scol[64], ssq[64];
    int tid = threadIdx.x;
    if (tid < 64) { scol[tid] = 0.f; ssq[tid] = 0.f; }
    int wv = tid >> 6;
    int l = tid & 63;
    int r16 = l & 15, kg = l >> 4;
    int base = blockIdx.x * 64;
    int arow = base + wv * 16 + r16;       // A-fragment row
    bool rv = arow < NN;

    // B fragments: bf[ct][h][i] = W[h*32 + kmap(i)][ct*16 + r16]
    bf16x8 bf[4][2];
    #pragma unroll
    for (int ct = 0; ct < 4; ct++)
        #pragma unroll
        for (int h = 0; h < 2; h++)
            #pragma unroll
            for (int i = 0; i < 8; i++) {
                int k = h * 32 + ((i < 4) ? kg * 4 + i : 16 + kg * 4 + (i - 4));
                bf[ct][h][i] = f2bf(W[k * 64 + ct * 16 + r16]);
            }

    // A fragments (+ fused BN/ReLU), fp32 -> bf16
    bf16x8 af[2];
    #pragma unroll
    for (int h = 0; h < 2; h++) {
        int k0 = h * 32 + kg * 4;          // elems 0..3
        int k1 = h * 32 + 16 + kg * 4;     // elems 4..7
        float4 v0 = rv ? *(const float4*)&in[(size_t)arow * 64 + k0]
                       : make_float4(0.f, 0.f, 0.f, 0.f);
        float4 v1 = rv ? *(const float4*)&in[(size_t)arow * 64 + k1]
                       : make_float4(0.f, 0.f, 0.f, 0.f);
        if (doBN) {
            float4 a0v = *(const float4*)&a1[k0];
            float4 c0v = *(const float4*)&c1[k0];
            float4 a1v = *(const float4*)&a1[k1];
            float4 c1v = *(const float4*)&c1[k1];
            v0.x = fmaxf(v0.x * a0v.x + c0v.x, 0.f);
            v0.y = fmaxf(v0.y * a0v.y + c0v.y, 0.f);
            v0.z = fmaxf(v0.z * a0v.z + c0v.z, 0.f);
            v0.w = fmaxf(v0.w * a0v.w + c0v.w, 0.f);
            v1.x = fmaxf(v1.x * a1v.x + c1v.x, 0.f);
            v1.y = fmaxf(v1.y * a1v.y + c1v.y, 0.f);
            v1.z = fmaxf(v1.z * a1v.z + c1v.z, 0.f);
            v1.w = fmaxf(v1.w * a1v.w + c1v.w, 0.f);
        }
        af[h][0] = f2bf(v0.x); af[h][1] = f2bf(v0.y);
        af[h][2] = f2bf(v0.z); af[h][3] = f2bf(v0.w);
        af[h][4] = f2bf(v1.x); af[h][5] = f2bf(v1.y);
        af[h][6] = f2bf(v1.z); af[h][7] = f2bf(v1.w);
    }

    f32x4 acc[4];
    #pragma unroll
    for (int ct = 0; ct < 4; ct++) { acc[ct][0] = 0.f; acc[ct][1] = 0.f; acc[ct][2] = 0.f; acc[ct][3] = 0.f; }
    #pragma unroll
    for (int h = 0; h < 2; h++)
        #pragma unroll
        for (int ct = 0; ct < 4; ct++)
            acc[ct] = __builtin_amdgcn_mfma_f32_16x16x32_bf16(af[h], bf[ct][h], acc[ct], 0, 0, 0);

    __syncthreads();   // scol/ssq initialized
    #pragma unroll
    for (int ct = 0; ct < 4; ct++) {
        int col = ct * 16 + r16;
        float bj = b[col];
        float ls = 0.f, lq = 0.f;
        #pragma unroll
        for (int i = 0; i < 4; i++) {
            int orow = base + wv * 16 + kg * 4 + i;   // D: row=(l>>4)*4+reg
            if (orow < NN) {
                float s = acc[ct][i] + bj;
                out[(size_t)orow * 64 + col] = s;
                ls += s; lq += s * s;
            }
        }
        atomicAdd(&scol[col], ls);
        atomicAdd(&ssq[col], lq);
    }
    __syncthreads();
    if (tid < 64) {
        fatomic(&colsum[tid], scol[tid]);
        fatomic(&colsq[tid], ssq[tid]);
    }
}

// ---- BN stats -> affine coefficients a, c (h_norm = t*a + c) ----
__global__ void k_bnstats(const float* __restrict__ colsum, const float* __restrict__ colsq,
                          const float* __restrict__ g, const float* __restrict__ beta,
                          float* __restrict__ a, float* __restrict__ c) {
    int j = threadIdx.x;
    if (j < 64) {
        float m = colsum[j] * (1.f / NN);
        float v = colsq[j] * (1.f / NN) - m * m;
        float aj = g[j] * rsqrtf(v + EPSF);
        a[j] = aj;
        c[j] = beta[j] - m * aj;
    }
}

// ---- prob = sigmoid(relu(t2*a2+c2) @ m3_W + m3_b) ----
__global__ __launch_bounds__(256) void k_mlp3(const float* __restrict__ t2,
                                              const float* __restrict__ a2,
                                              const float* __restrict__ c2,
                                              const float* __restrict__ W3,
                                              const float* __restrict__ b3,
                                              float* __restrict__ prob) {
    int j = threadIdx.x & 63;
    int r = threadIdx.x >> 6;
    float aj = a2[j], cj = c2[j], wj = W3[j], bb = b3[0];
    for (int n = blockIdx.x * 4 + r; n < NN; n += 2048 * 4) {
        float h = fmaxf(t2[(size_t)n * 64 + j] * aj + cj, 0.f) * wj;
        #pragma unroll
        for (int off = 32; off > 0; off >>= 1) h += __shfl_xor(h, off, 64);
        if (j == 0) prob[n] = 1.f / (1.f + expf(-(h + bb)));
    }
}

extern "C" void kernel_launch(void* const* d_in, const int* in_sizes, int n_in,
                              void* d_out, int out_size, void* d_ws, size_t ws_size,
                              hipStream_t stream) {
    const float* init_emb = (const float*)d_in[0];
    const int* pe = (const int*)d_in[1];
    const int* ne = (const int*)d_in[2];
    const float* c1_Wp = (const float*)d_in[3];  const float* c1_bp = (const float*)d_in[4];
    const float* c1_Wn = (const float*)d_in[5];  const float* c1_bn = (const float*)d_in[6];
    const float* c1_Ws = (const float*)d_in[7];  const float* c1_bs = (const float*)d_in[8];
    const float* c2_Wp = (const float*)d_in[9];  const float* c2_bp = (const float*)d_in[10];
    const float* c2_Wn = (const float*)d_in[11]; const float* c2_bn = (const float*)d_in[12];
    const float* c2_Ws = (const float*)d_in[13]; const float* c2_bs = (const float*)d_in[14];
    const float* w_W = (const float*)d_in[15];   const float* w_b = (const float*)d_in[16];
    const float* m1_W = (const float*)d_in[17];  const float* m1_b = (const float*)d_in[18];
    const float* g1 = (const float*)d_in[19];    const float* b1 = (const float*)d_in[20];
    const float* m2_W = (const float*)d_in[21];  const float* m2_b = (const float*)d_in[22];
    const float* g2 = (const float*)d_in[23];    const float* b2 = (const float*)d_in[24];
    const float* m3_W = (const float*)d_in[25];  const float* m3_b = (const float*)d_in[26];

    // ---- workspace arena ----
    size_t off = 0;
    auto alloc = [&](size_t bytes) -> void* {
        void* r = (char*)d_ws + off;
        off += (bytes + 255) & ~(size_t)255;
        return r;
    };
    // zero region (front): only BN stat accumulators
    float* sums = (float*)alloc(256 * 4);               // colsum1, colsq1, colsum2, colsq2
    size_t zero_bytes = off;
    // CSR-build region (dead after second k_pull; t2 aliases it later)
    size_t csr_region = off;
    int*   hist = (int*)alloc((size_t)NBUK2 * NBLK * 4);        // 800KB
    int*   soff = (int*)alloc((size_t)NBUK2 * NBLK * 4);        // 800KB
    int*   part = (int*)alloc((size_t)1024 * 4);
    unsigned long long* staging = (unsigned long long*)alloc((size_t)2 * EE * 8);  // 16MB
    int*   csrAll = (int*)alloc((size_t)2 * EE * 4);            // 8MB
    // persistent
    int*   rpP  = (int*)alloc((size_t)(NN + 1) * 4);
    int*   rpN  = (int*)alloc((size_t)(NN + 1) * 4);
    float* R1   = (float*)alloc((size_t)NN * 96 * 4);   // {xp,xn,xs} layer1 -> layer2 -> t1
    float* z1   = (float*)alloc((size_t)NN * 32 * 4);
    float* z2   = (float*)alloc((size_t)NN * 32 * 4);
    float* abc  = (float*)alloc(256 * 4);               // a1, c1, a2, c2

    int* csrP = csrAll;
    int* csrN = csrAll + (size_t)EE;
    float* xp = R1;
    float* xn = R1 + (size_t)NN * 32;
    float* xs = R1 + (size_t)NN * 64;
    float* t1 = R1;                                     // dead xp/xn region after wlin
    float* t2 = (float*)((char*)d_ws + csr_region);     // aliases CSR-build scratch (25.6MB fits)

    float* z_out = (float*)d_out;                       // [N,64]
    float* prob  = (float*)d_out + (size_t)NN * 64;     // [N,1]

    hipMemsetAsync(d_ws, 0, zero_bytes, stream);

    // ---- CSR build: hist -> scan -> bin scatter -> per-bucket local build ----
    k_hist<<<NBLK, 256, 0, stream>>>(pe, ne, hist);
    k_gscan1<<<GSB, 256, 0, stream>>>(hist, soff, part);
    k_gscan2<<<1, 1024, 0, stream>>>(part);
    k_gscan3<<<GSB, 256, 0, stream>>>(part, soff);
    k_binscatter<<<NBLK, 256, 0, stream>>>(pe, ne, soff, staging);
    k_local<<<NBUK2, 256, 0, stream>>>(staging, soff, rpP, rpN, csrAll);

    // layer 1
    k_xf1<<<GTILES, 192, 0, stream>>>(init_emb, c1_Wp, c1_Wn, c1_Ws, xp, xn, xs);
    k_pull<<<2048, 256, 0, stream>>>(xp, xn, xs, rpP, csrP, rpN, csrN, c1_bp, c1_bn, c1_bs, z1);
    // layer 2
    k_xf2<<<GTILES, 192, 0, stream>>>(z1, c2_Wp, c2_Wn, c2_Ws, xp, xn, xs);
    k_pull<<<2048, 256, 0, stream>>>(xp, xn, xs, rpP, csrP, rpN, csrN, c2_bp, c2_bn, c2_bs, z2);
    // readout
    k_wlin<<<GTILES, 256, 0, stream>>>(z2, w_W, w_b, z_out);
    k_mlp<<<GTILES, 256, 0, stream>>>(z_out, nullptr, nullptr, 0, m1_W, m1_b, t1, sums + 0, sums + 64);
    k_bnstats<<<1, 64, 0, stream>>>(sums + 0, sums + 64, g1, b1, abc + 0, abc + 64);
    k_mlp<<<GTILES, 256, 0, stream>>>(t1, abc + 0, abc + 64, 1, m2_W, m2_b, t2, sums + 128, sums + 192);
    k_bnstats<<<1, 64, 0, stream>>>(sums + 128, sums + 192, g2, b2, abc + 128, abc + 192);
    k_mlp3<<<2048, 256, 0, stream>>>(t2, abc + 128, abc + 192, m3_W, m3_b, prob);
}

// Round 13
// 301.702 us; speedup vs baseline: 1.3729x; 1.1814x over previous
//
#include <hip/hip_runtime.h>
#include <cstdint>
#include <cstddef>

#define NN 100000
#define EE 1000000
#define EPSF 1e-5f
#define NBUK 391          // node buckets per relation: ceil(100000/256), dst>>8
#define NBUK2 (2*NBUK)    // both relations
#define NBLK 256          // edge-chunk blocks for hist/binscatter
#define EPB 7813          // ceil(2*EE / NBLK)
#define GSB 782           // scan blocks over NBUK2*NBLK entries (=200192/256)
#define GTILES ((NN + 63) / 64)   // 1563 64-node tiles
#define MLP_GRID 512      // persistent-ish: ~3 tiles/block, W-fragments amortized

typedef __attribute__((ext_vector_type(8))) short bf16x8;
typedef __attribute__((ext_vector_type(4))) float f32x4;

__device__ __forceinline__ void fatomic(float* p, float v) { unsafeAtomicAdd(p, v); }

__device__ __forceinline__ short f2bf(float f) {
    unsigned u = __float_as_uint(f);
    u += 0x7FFF + ((u >> 16) & 1);   // round-to-nearest-even
    return (short)(u >> 16);
}

// edge slot s in [0,2EE): rel 0 = pos, rel 1 = neg
__device__ __forceinline__ void edge_of(const int* __restrict__ pe, const int* __restrict__ ne,
                                        int s, int& src, int& dst, int& bucket) {
    if (s < EE) { src = pe[s]; dst = pe[EE + s]; bucket = dst >> 8; }
    else        { src = ne[s - EE]; dst = ne[s]; bucket = NBUK + (dst >> 8); }
}

// ---- pass 1: per-block bucket histogram ----
__global__ __launch_bounds__(256) void k_hist(const int* __restrict__ pe,
                                              const int* __restrict__ ne,
                                              int* __restrict__ hist) {
    __shared__ int lh[NBUK2];
    for (int i = threadIdx.x; i < NBUK2; i += 256) lh[i] = 0;
    __syncthreads();
    int start = blockIdx.x * EPB, end = min(start + EPB, 2 * EE);
    for (int s = start + threadIdx.x; s < end; s += 256) {
        int src, dst, bucket;
        edge_of(pe, ne, s, src, dst, bucket);
        atomicAdd(&lh[bucket], 1);
    }
    __syncthreads();
    for (int i = threadIdx.x; i < NBUK2; i += 256)
        hist[i * NBLK + blockIdx.x] = lh[i];   // bucket-major
}

// ---- generic hierarchical exclusive scan over NBUK2*NBLK ints ----
__global__ __launch_bounds__(256) void k_gscan1(const int* __restrict__ in,
                                                int* __restrict__ out,
                                                int* __restrict__ partials) {
    int i = blockIdx.x * 256 + threadIdx.x;
    int v = in[i];
    __shared__ int s[256];
    s[threadIdx.x] = v;
    __syncthreads();
    for (int off = 1; off < 256; off <<= 1) {
        int u = (threadIdx.x >= off) ? s[threadIdx.x - off] : 0;
        __syncthreads();
        s[threadIdx.x] += u;
        __syncthreads();
    }
    out[i] = s[threadIdx.x] - v;
    if (threadIdx.x == 255) partials[blockIdx.x] = s[255];
}

__global__ __launch_bounds__(1024) void k_gscan2(int* __restrict__ partials) {
    __shared__ int s[1024];
    int v = (threadIdx.x < GSB) ? partials[threadIdx.x] : 0;
    s[threadIdx.x] = v;
    __syncthreads();
    for (int off = 1; off < 1024; off <<= 1) {
        int u = (threadIdx.x >= off) ? s[threadIdx.x - off] : 0;
        __syncthreads();
        s[threadIdx.x] += u;
        __syncthreads();
    }
    if (threadIdx.x < GSB) partials[threadIdx.x] = s[threadIdx.x] - v;
}

__global__ __launch_bounds__(256) void k_gscan3(const int* __restrict__ partials,
                                                int* __restrict__ out) {
    out[blockIdx.x * 256 + threadIdx.x] += partials[blockIdx.x];
}

// ---- pass 2: scatter edges into bucket-grouped staging (block-exclusive runs) ----
__global__ __launch_bounds__(256) void k_binscatter(const int* __restrict__ pe,
                                                    const int* __restrict__ ne,
                                                    const int* __restrict__ soff,
                                                    unsigned long long* __restrict__ staging) {
    __shared__ int cur[NBUK2];
    for (int i = threadIdx.x; i < NBUK2; i += 256)
        cur[i] = soff[i * NBLK + blockIdx.x];
    __syncthreads();
    int start = blockIdx.x * EPB, end = min(start + EPB, 2 * EE);
    for (int s = start + threadIdx.x; s < end; s += 256) {
        int src, dst, bucket;
        edge_of(pe, ne, s, src, dst, bucket);
        int pos = atomicAdd(&cur[bucket], 1);
        staging[pos] = ((unsigned long long)(unsigned)dst << 32) | (unsigned)src;
    }
}

// ---- pass 3: per-bucket local build: rp (degree+scan in LDS) + csr scatter ----
__global__ __launch_bounds__(256) void k_local(const unsigned long long* __restrict__ staging,
                                               const int* __restrict__ soff,
                                               int* __restrict__ rpP,
                                               int* __restrict__ rpN,
                                               int* __restrict__ csrAll) {
    int bucket = blockIdx.x;
    int rel = bucket >= NBUK;
    int nodeBase = (bucket - rel * NBUK) << 8;
    int bstart = soff[bucket * NBLK];
    int bend = (bucket == NBUK2 - 1) ? 2 * EE : soff[(bucket + 1) * NBLK];
    int tid = threadIdx.x;
    __shared__ int deg[256], sc[256];
    deg[tid] = 0;
    __syncthreads();
    for (int i = bstart + tid; i < bend; i += 256) {
        int d = (int)(staging[i] >> 32) & 255;
        atomicAdd(&deg[d], 1);
    }
    __syncthreads();
    int dv = deg[tid];
    sc[tid] = dv;
    __syncthreads();
    for (int off = 1; off < 256; off <<= 1) {
        int u = (tid >= off) ? sc[tid - off] : 0;
        __syncthreads();
        sc[tid] += u;
        __syncthreads();
    }
    int lrp = sc[tid] - dv;  // bucket-local exclusive prefix
    int nCount = min(256, NN - nodeBase);
    int relbase = rel ? EE : 0;
    if (tid < nCount) (rel ? rpN : rpP)[nodeBase + tid] = bstart - relbase + lrp;
    if (bucket == NBUK - 1 && tid == 0) rpP[NN] = EE;
    if (bucket == NBUK2 - 1 && tid == 0) rpN[NN] = EE;
    deg[tid] = lrp;          // reuse as cursor
    __syncthreads();
    for (int i = bstart + tid; i < bend; i += 256) {
        unsigned long long v = staging[i];
        int d = (int)(v >> 32) & 255;
        int src = (int)(v & 0xffffffffu);
        int slot = atomicAdd(&deg[d], 1);
        csrAll[bstart + slot] = src;
    }
}

// ---- pre-transform 64->32 x3: xp=x@Wp, xn=x@Wn, xs=x@Ws ----
__global__ __launch_bounds__(192) __attribute__((amdgpu_waves_per_eu(2, 4)))
void k_xf1(const float* __restrict__ x,
           const float* __restrict__ Wp,
           const float* __restrict__ Wn,
           const float* __restrict__ Ws,
           float* __restrict__ xp,
           float* __restrict__ xn,
           float* __restrict__ xs) {
    __shared__ float sx[64 * 64];   // x tile (16KB)
    int base = blockIdx.x * 64;
    int tid = threadIdx.x;
    int wvm = tid >> 6;             // 0,1,2 -> matrix p,n,s
    int l = tid & 63;
    int j = l & 31;                 // output col
    int half = l >> 5;              // node parity
    for (int idx = tid; idx < 1024; idx += 192) {
        int row = idx >> 4, f = idx & 15;
        int n = base + row;
        float4 v = (n < NN) ? *(const float4*)&x[(size_t)n * 64 + f * 4]
                            : make_float4(0.f, 0.f, 0.f, 0.f);
        *(float4*)&sx[row * 64 + f * 4] = v;
    }
    const float* W = (wvm == 0) ? Wp : (wvm == 1) ? Wn : Ws;
    float* outm = (wvm == 0) ? xp : (wvm == 1) ? xn : xs;
    float w[64];
    #pragma unroll
    for (int k = 0; k < 64; k++) w[k] = W[k * 32 + j];
    __syncthreads();
    #pragma unroll 1
    for (int i = 0; i < 32; i++) {
        int nl = 2 * i + half;
        int n = base + nl;
        float a0 = 0.f, a1 = 0.f, a2 = 0.f, a3 = 0.f;
        #pragma unroll
        for (int q = 0; q < 16; q++) {
            float4 xv = *(const float4*)&sx[nl * 64 + q * 4];
            a0 += xv.x * w[q * 4 + 0];
            a1 += xv.y * w[q * 4 + 1];
            a2 += xv.z * w[q * 4 + 2];
            a3 += xv.w * w[q * 4 + 3];
        }
        if (n < NN) outm[(size_t)n * 32 + j] = (a0 + a1) + (a2 + a3);
    }
}

// ---- pre-transform 32->32 x3, same structure ----
__global__ __launch_bounds__(192) __attribute__((amdgpu_waves_per_eu(2, 4)))
void k_xf2(const float* __restrict__ z,
           const float* __restrict__ Wp,
           const float* __restrict__ Wn,
           const float* __restrict__ Ws,
           float* __restrict__ xp,
           float* __restrict__ xn,
           float* __restrict__ xs) {
    __shared__ float sx[64 * 32];   // z tile (8KB)
    int base = blockIdx.x * 64;
    int tid = threadIdx.x;
    int wvm = tid >> 6;
    int l = tid & 63;
    int j = l & 31;
    int half = l >> 5;
    for (int idx = tid; idx < 512; idx += 192) {
        int row = idx >> 3, f = idx & 7;
        int n = base + row;
        float4 v = (n < NN) ? *(const float4*)&z[(size_t)n * 32 + f * 4]
                            : make_float4(0.f, 0.f, 0.f, 0.f);
        *(float4*)&sx[row * 32 + f * 4] = v;
    }
    const float* W = (wvm == 0) ? Wp : (wvm == 1) ? Wn : Ws;
    float* outm = (wvm == 0) ? xp : (wvm == 1) ? xn : xs;
    float w[32];
    #pragma unroll
    for (int k = 0; k < 32; k++) w[k] = W[k * 32 + j];
    __syncthreads();
    #pragma unroll 1
    for (int i = 0; i < 32; i++) {
        int nl = 2 * i + half;
        int n = base + nl;
        float a0 = 0.f, a1 = 0.f, a2 = 0.f, a3 = 0.f;
        #pragma unroll
        for (int q = 0; q < 8; q++) {
            float4 xv = *(const float4*)&sx[nl * 32 + q * 4];
            a0 += xv.x * w[q * 4 + 0];
            a1 += xv.y * w[q * 4 + 1];
            a2 += xv.z * w[q * 4 + 2];
            a3 += xv.w * w[q * 4 + 3];
        }
        if (n < NN) outm[(size_t)n * 32 + j] = (a0 + a1) + (a2 + a3);
    }
}

// ---- accumulate one relation's neighbors ----
__device__ __forceinline__ float pull_rel(const float* __restrict__ xsrc,
                                          const int* __restrict__ csr,
                                          int b0, int b1, int j, float acc) {
    for (int base = b0; base < b1; base += 32) {
        int rem = b1 - base;
        int cnt = min(rem, 32);
        int idx = (j < rem) ? csr[base + j] : 0;
        int i = 0;
        for (; i + 4 <= cnt; i += 4) {
            int s0 = __shfl(idx, i, 32);
            int s1 = __shfl(idx, i + 1, 32);
            int s2 = __shfl(idx, i + 2, 32);
            int s3 = __shfl(idx, i + 3, 32);
            float v0 = xsrc[(size_t)s0 * 32 + j];
            float v1 = xsrc[(size_t)s1 * 32 + j];
            float v2 = xsrc[(size_t)s2 * 32 + j];
            float v3 = xsrc[(size_t)s3 * 32 + j];
            acc += v0; acc += v1; acc += v2; acc += v3;
        }
        for (; i < cnt; i++) {
            int s = __shfl(idx, i, 32);
            acc += xsrc[(size_t)s * 32 + j];
        }
    }
    return acc;
}

// ---- pull aggregation + combine + tanh ----
__global__ __launch_bounds__(256) void k_pull(const float* __restrict__ xp,
                                              const float* __restrict__ xn,
                                              const float* __restrict__ xs,
                                              const int* __restrict__ rpP,
                                              const int* __restrict__ csrP,
                                              const int* __restrict__ rpN,
                                              const int* __restrict__ csrN,
                                              const float* __restrict__ bp,
                                              const float* __restrict__ bn,
                                              const float* __restrict__ bs,
                                              float* __restrict__ out) {
    int j = threadIdx.x & 31;
    int hw = (blockIdx.x * 256 + threadIdx.x) >> 5;
    const int nhw = (2048 * 256) >> 5;
    float bpj = bp[j], bnj = bn[j], bsj = bs[j];
    for (int n = hw; n < NN; n += nhw) {
        int p0 = rpP[n], p1 = rpP[n + 1];
        int n0 = rpN[n], n1 = rpN[n + 1];
        float acc = xs[(size_t)n * 32 + j] + bsj
                  + (float)(p1 - p0) * bpj + (float)(n1 - n0) * bnj;
        acc = pull_rel(xp, csrP, p0, p1, j, acc);
        acc = pull_rel(xn, csrN, n0, n1, j, acc);
        out[(size_t)n * 32 + j] = tanhf(acc);
    }
}

// ---- z = tanh(z2 @ Wl + bl): 32->64, 64-row tiles (output 0) ----
__global__ __launch_bounds__(256) __attribute__((amdgpu_waves_per_eu(2, 4)))
void k_wlin(const float* __restrict__ z2,
            const float* __restrict__ Wl,
            const float* __restrict__ bl,
            float* __restrict__ z) {
    __shared__ float sx[64 * 32];   // z2 tile (8KB)
    int base = blockIdx.x * 64;
    int tid = threadIdx.x;
    int lane = tid & 63;
    int wv = tid >> 6;
    {
        int row = tid >> 2, c4 = tid & 3;
        int n = base + row;
        #pragma unroll
        for (int m = 0; m < 2; m++) {
            int f = c4 + 4 * m;
            float4 v = (n < NN) ? *(const float4*)&z2[(size_t)n * 32 + f * 4]
                                : make_float4(0.f, 0.f, 0.f, 0.f);
            *(float4*)&sx[row * 32 + f * 4] = v;
        }
    }
    float wl[32];
    #pragma unroll
    for (int k = 0; k < 32; k++) wl[k] = Wl[k * 64 + lane];
    float blj = bl[lane];
    __syncthreads();
    #pragma unroll 1
    for (int i = 0; i < 16; i++) {
        int nl = i * 4 + wv;
        int n = base + nl;
        float a0 = 0.f, a1c = 0.f, a2 = 0.f, a3 = 0.f;
        #pragma unroll
        for (int q = 0; q < 8; q++) {
            float4 xv = *(const float4*)&sx[nl * 32 + q * 4];
            a0 += xv.x * wl[q * 4 + 0];
            a1c += xv.y * wl[q * 4 + 1];
            a2 += xv.z * wl[q * 4 + 2];
            a3 += xv.w * wl[q * 4 + 3];
        }
        if (n < NN) z[(size_t)n * 64 + lane] = tanhf(blj + ((a0 + a1c) + (a2 + a3)));
    }
}

// ---- MFMA MLP GEMM, persistent tiles: out = [relu(in*a+c) or in] @ W + b, column stats ----
// W-fragments loaded ONCE per block; grid-stride over 64-row tiles (~3 tiles/block).
__global__ __launch_bounds__(256) __attribute__((amdgpu_waves_per_eu(2, 4)))
void k_mlp(const float* __restrict__ in,
           const float* __restrict__ a1,
           const float* __restrict__ c1,
           int doBN,
           const float* __restrict__ W,
           const float* __restrict__ b,
           float* __restrict__ out,
           float* __restrict__ colsum,
           float* __restrict__ colsq) {
    __shared__ float scol[64], ssq[64];
    int tid = threadIdx.x;
    if (tid < 64) { scol[tid] = 0.f; ssq[tid] = 0.f; }
    int wv = tid >> 6;
    int l = tid & 63;
    int r16 = l & 15, kg = l >> 4;

    // B fragments (invariant): bf[ct][h][i] = W[h*32 + kmap(i)][ct*16 + r16]
    bf16x8 bf[4][2];
    #pragma unroll
    for (int ct = 0; ct < 4; ct++)
        #pragma unroll
        for (int h = 0; h < 2; h++)
            #pragma unroll
            for (int i = 0; i < 8; i++) {
                int k = h * 32 + ((i < 4) ? kg * 4 + i : 16 + kg * 4 + (i - 4));
                bf[ct][h][i] = f2bf(W[k * 64 + ct * 16 + r16]);
            }
    float bj[4];
    #pragma unroll
    for (int ct = 0; ct < 4; ct++) bj[ct] = b[ct * 16 + r16];

    // BN coefficients for this thread's A-fragment k positions (invariant)
    float av0[2][4], cv0[2][4], av1[2][4], cv1[2][4];
    #pragma unroll
    for (int h = 0; h < 2; h++) {
        int k0 = h * 32 + kg * 4;
        int k1 = h * 32 + 16 + kg * 4;
        #pragma unroll
        for (int i = 0; i < 4; i++) {
            av0[h][i] = doBN ? a1[k0 + i] : 1.f;
            cv0[h][i] = doBN ? c1[k0 + i] : 0.f;
            av1[h][i] = doBN ? a1[k1 + i] : 1.f;
            cv1[h][i] = doBN ? c1[k1 + i] : 0.f;
        }
    }

    float lsum[4] = {0.f, 0.f, 0.f, 0.f}, lsq[4] = {0.f, 0.f, 0.f, 0.f};

    for (int tile = blockIdx.x; tile < GTILES; tile += MLP_GRID) {
        int base = tile * 64;
        int arow = base + wv * 16 + r16;
        bool rv = arow < NN;
        bf16x8 af[2];
        #pragma unroll
        for (int h = 0; h < 2; h++) {
            int k0 = h * 32 + kg * 4;
            int k1 = h * 32 + 16 + kg * 4;
            float4 v0 = rv ? *(const float4*)&in[(size_t)arow * 64 + k0]
                           : make_float4(0.f, 0.f, 0.f, 0.f);
            float4 v1 = rv ? *(const float4*)&in[(size_t)arow * 64 + k1]
                           : make_float4(0.f, 0.f, 0.f, 0.f);
            if (doBN) {
                v0.x = fmaxf(v0.x * av0[h][0] + cv0[h][0], 0.f);
                v0.y = fmaxf(v0.y * av0[h][1] + cv0[h][1], 0.f);
                v0.z = fmaxf(v0.z * av0[h][2] + cv0[h][2], 0.f);
                v0.w = fmaxf(v0.w * av0[h][3] + cv0[h][3], 0.f);
                v1.x = fmaxf(v1.x * av1[h][0] + cv1[h][0], 0.f);
                v1.y = fmaxf(v1.y * av1[h][1] + cv1[h][1], 0.f);
                v1.z = fmaxf(v1.z * av1[h][2] + cv1[h][2], 0.f);
                v1.w = fmaxf(v1.w * av1[h][3] + cv1[h][3], 0.f);
            }
            af[h][0] = f2bf(v0.x); af[h][1] = f2bf(v0.y);
            af[h][2] = f2bf(v0.z); af[h][3] = f2bf(v0.w);
            af[h][4] = f2bf(v1.x); af[h][5] = f2bf(v1.y);
            af[h][6] = f2bf(v1.z); af[h][7] = f2bf(v1.w);
        }

        f32x4 acc[4];
        #pragma unroll
        for (int ct = 0; ct < 4; ct++) { acc[ct][0] = 0.f; acc[ct][1] = 0.f; acc[ct][2] = 0.f; acc[ct][3] = 0.f; }
        #pragma unroll
        for (int h = 0; h < 2; h++)
            #pragma unroll
            for (int ct = 0; ct < 4; ct++)
                acc[ct] = __builtin_amdgcn_mfma_f32_16x16x32_bf16(af[h], bf[ct][h], acc[ct], 0, 0, 0);

        #pragma unroll
        for (int ct = 0; ct < 4; ct++) {
            int col = ct * 16 + r16;
            #pragma unroll
            for (int i = 0; i < 4; i++) {
                int orow = base + wv * 16 + kg * 4 + i;   // D: row=(l>>4)*4+reg
                if (orow < NN) {
                    float s = acc[ct][i] + bj[ct];
                    out[(size_t)orow * 64 + col] = s;
                    lsum[ct] += s; lsq[ct] += s * s;
                }
            }
        }
    }

    __syncthreads();   // scol/ssq init visible
    #pragma unroll
    for (int ct = 0; ct < 4; ct++) {
        atomicAdd(&scol[ct * 16 + r16], lsum[ct]);
        atomicAdd(&ssq[ct * 16 + r16], lsq[ct]);
    }
    __syncthreads();
    if (tid < 64) {
        fatomic(&colsum[tid], scol[tid]);
        fatomic(&colsq[tid], ssq[tid]);
    }
}

// ---- BN stats -> affine coefficients a, c (h_norm = t*a + c) ----
__global__ void k_bnstats(const float* __restrict__ colsum, const float* __restrict__ colsq,
                          const float* __restrict__ g, const float* __restrict__ beta,
                          float* __restrict__ a, float* __restrict__ c) {
    int j = threadIdx.x;
    if (j < 64) {
        float m = colsum[j] * (1.f / NN);
        float v = colsq[j] * (1.f / NN) - m * m;
        float aj = g[j] * rsqrtf(v + EPSF);
        a[j] = aj;
        c[j] = beta[j] - m * aj;
    }
}

// ---- prob = sigmoid(relu(t2*a2+c2) @ m3_W + m3_b) ----
__global__ __launch_bounds__(256) void k_mlp3(const float* __restrict__ t2,
                                              const float* __restrict__ a2,
                                              const float* __restrict__ c2,
                                              const float* __restrict__ W3,
                                              const float* __restrict__ b3,
                                              float* __restrict__ prob) {
    int j = threadIdx.x & 63;
    int r = threadIdx.x >> 6;
    float aj = a2[j], cj = c2[j], wj = W3[j], bb = b3[0];
    for (int n = blockIdx.x * 4 + r; n < NN; n += 2048 * 4) {
        float h = fmaxf(t2[(size_t)n * 64 + j] * aj + cj, 0.f) * wj;
        #pragma unroll
        for (int off = 32; off > 0; off >>= 1) h += __shfl_xor(h, off, 64);
        if (j == 0) prob[n] = 1.f / (1.f + expf(-(h + bb)));
    }
}

extern "C" void kernel_launch(void* const* d_in, const int* in_sizes, int n_in,
                              void* d_out, int out_size, void* d_ws, size_t ws_size,
                              hipStream_t stream) {
    const float* init_emb = (const float*)d_in[0];
    const int* pe = (const int*)d_in[1];
    const int* ne = (const int*)d_in[2];
    const float* c1_Wp = (const float*)d_in[3];  const float* c1_bp = (const float*)d_in[4];
    const float* c1_Wn = (const float*)d_in[5];  const float* c1_bn = (const float*)d_in[6];
    const float* c1_Ws = (const float*)d_in[7];  const float* c1_bs = (const float*)d_in[8];
    const float* c2_Wp = (const float*)d_in[9];  const float* c2_bp = (const float*)d_in[10];
    const float* c2_Wn = (const float*)d_in[11]; const float* c2_bn = (const float*)d_in[12];
    const float* c2_Ws = (const float*)d_in[13]; const float* c2_bs = (const float*)d_in[14];
    const float* w_W = (const float*)d_in[15];   const float* w_b = (const float*)d_in[16];
    const float* m1_W = (const float*)d_in[17];  const float* m1_b = (const float*)d_in[18];
    const float* g1 = (const float*)d_in[19];    const float* b1 = (const float*)d_in[20];
    const float* m2_W = (const float*)d_in[21];  const float* m2_b = (const float*)d_in[22];
    const float* g2 = (const float*)d_in[23];    const float* b2 = (const float*)d_in[24];
    const float* m3_W = (const float*)d_in[25];  const float* m3_b = (const float*)d_in[26];

    // ---- workspace arena ----
    size_t off = 0;
    auto alloc = [&](size_t bytes) -> void* {
        void* r = (char*)d_ws + off;
        off += (bytes + 255) & ~(size_t)255;
        return r;
    };
    // zero region (front): only BN stat accumulators
    float* sums = (float*)alloc(256 * 4);               // colsum1, colsq1, colsum2, colsq2
    size_t zero_bytes = off;
    // CSR-build region (dead after second k_pull; t2 aliases it later)
    size_t csr_region = off;
    int*   hist = (int*)alloc((size_t)NBUK2 * NBLK * 4);        // 800KB
    int*   soff = (int*)alloc((size_t)NBUK2 * NBLK * 4);        // 800KB
    int*   part = (int*)alloc((size_t)1024 * 4);
    unsigned long long* staging = (unsigned long long*)alloc((size_t)2 * EE * 8);  // 16MB
    int*   csrAll = (int*)alloc((size_t)2 * EE * 4);            // 8MB
    // persistent
    int*   rpP  = (int*)alloc((size_t)(NN + 1) * 4);
    int*   rpN  = (int*)alloc((size_t)(NN + 1) * 4);
    float* R1   = (float*)alloc((size_t)NN * 96 * 4);   // {xp,xn,xs} layer1 -> layer2 -> t1
    float* z1   = (float*)alloc((size_t)NN * 32 * 4);
    float* z2   = (float*)alloc((size_t)NN * 32 * 4);
    float* abc  = (float*)alloc(256 * 4);               // a1, c1, a2, c2

    int* csrP = csrAll;
    int* csrN = csrAll + (size_t)EE;
    float* xp = R1;
    float* xn = R1 + (size_t)NN * 32;
    float* xs = R1 + (size_t)NN * 64;
    float* t1 = R1;                                     // dead xp/xn region after wlin
    float* t2 = (float*)((char*)d_ws + csr_region);     // aliases CSR-build scratch (25.6MB fits)

    float* z_out = (float*)d_out;                       // [N,64]
    float* prob  = (float*)d_out + (size_t)NN * 64;     // [N,1]

    hipMemsetAsync(d_ws, 0, zero_bytes, stream);

    // ---- CSR build: hist -> scan -> bin scatter -> per-bucket local build ----
    k_hist<<<NBLK, 256, 0, stream>>>(pe, ne, hist);
    k_gscan1<<<GSB, 256, 0, stream>>>(hist, soff, part);
    k_gscan2<<<1, 1024, 0, stream>>>(part);
    k_gscan3<<<GSB, 256, 0, stream>>>(part, soff);
    k_binscatter<<<NBLK, 256, 0, stream>>>(pe, ne, soff, staging);
    k_local<<<NBUK2, 256, 0, stream>>>(staging, soff, rpP, rpN, csrAll);

    // layer 1
    k_xf1<<<GTILES, 192, 0, stream>>>(init_emb, c1_Wp, c1_Wn, c1_Ws, xp, xn, xs);
    k_pull<<<2048, 256, 0, stream>>>(xp, xn, xs, rpP, csrP, rpN, csrN, c1_bp, c1_bn, c1_bs, z1);
    // layer 2
    k_xf2<<<GTILES, 192, 0, stream>>>(z1, c2_Wp, c2_Wn, c2_Ws, xp, xn, xs);
    k_pull<<<2048, 256, 0, stream>>>(xp, xn, xs, rpP, csrP, rpN, csrN, c2_bp, c2_bn, c2_bs, z2);
    // readout
    k_wlin<<<GTILES, 256, 0, stream>>>(z2, w_W, w_b, z_out);
    k_mlp<<<MLP_GRID, 256, 0, stream>>>(z_out, nullptr, nullptr, 0, m1_W, m1_b, t1, sums + 0, sums + 64);
    k_bnstats<<<1, 64, 0, stream>>>(sums + 0, sums + 64, g1, b1, abc + 0, abc + 64);
    k_mlp<<<MLP_GRID, 256, 0, stream>>>(t1, abc + 0, abc + 64, 1, m2_W, m2_b, t2, sums + 128, sums + 192);
    k_bnstats<<<1, 64, 0, stream>>>(sums + 128, sums + 192, g2, b2, abc + 128, abc + 192);
    k_mlp3<<<2048, 256, 0, stream>>>(t2, abc + 128, abc + 192, m3_W, m3_b, prob);
}

// Round 14
// 268.471 us; speedup vs baseline: 1.5428x; 1.1238x over previous
//
#include <hip/hip_runtime.h>
#include <cstdint>
#include <cstddef>

#define NN 100000
#define EE 1000000
#define EPSF 1e-5f
#define NBUK 391          // node buckets per relation: ceil(100000/256), dst>>8
#define NBUK2 (2*NBUK)    // both relations
#define NBLK 256          // edge-chunk blocks for hist/binscatter
#define EPB 7813          // ceil(2*EE / NBLK)
#define GSB 782           // scan blocks over NBUK2*NBLK entries (=200192/256)
#define GTILES ((NN + 63) / 64)   // 1563 64-node tiles
#define MLP_GRID 512      // persistent-ish: ~3 tiles/block, W-fragments amortized
#define XFT (NN / 16)     // 6250 16-row tiles (NN % 16 == 0)
#define XF_GRID 512

typedef __attribute__((ext_vector_type(8))) short bf16x8;
typedef __attribute__((ext_vector_type(4))) float f32x4;

__device__ __forceinline__ void fatomic(float* p, float v) { unsafeAtomicAdd(p, v); }

__device__ __forceinline__ short f2bf(float f) {
    unsigned u = __float_as_uint(f);
    u += 0x7FFF + ((u >> 16) & 1);   // round-to-nearest-even
    return (short)(u >> 16);
}
__device__ __forceinline__ float bf2f(short s) {
    return __uint_as_float(((unsigned)(unsigned short)s) << 16);
}
// hi/lo split of 8 floats -> 2 bf16x8 (x ~= hi + lo to ~fp32 precision)
__device__ __forceinline__ void split8(const float4 v0, const float4 v1, bf16x8& hi, bf16x8& lo) {
    float a[8] = {v0.x, v0.y, v0.z, v0.w, v1.x, v1.y, v1.z, v1.w};
    #pragma unroll
    for (int i = 0; i < 8; i++) {
        short h = f2bf(a[i]);
        hi[i] = h;
        lo[i] = f2bf(a[i] - bf2f(h));
    }
}
__device__ __forceinline__ int kmap(int kg, int i) {   // 16x16x32 A/B fragment k index
    return (i < 4) ? kg * 4 + i : 16 + kg * 4 + (i - 4);
}

// edge slot s in [0,2EE): rel 0 = pos, rel 1 = neg
__device__ __forceinline__ void edge_of(const int* __restrict__ pe, const int* __restrict__ ne,
                                        int s, int& src, int& dst, int& bucket) {
    if (s < EE) { src = pe[s]; dst = pe[EE + s]; bucket = dst >> 8; }
    else        { src = ne[s - EE]; dst = ne[s]; bucket = NBUK + (dst >> 8); }
}

// ---- pass 1: per-block bucket histogram ----
__global__ __launch_bounds__(256) void k_hist(const int* __restrict__ pe,
                                              const int* __restrict__ ne,
                                              int* __restrict__ hist) {
    __shared__ int lh[NBUK2];
    for (int i = threadIdx.x; i < NBUK2; i += 256) lh[i] = 0;
    __syncthreads();
    int start = blockIdx.x * EPB, end = min(start + EPB, 2 * EE);
    for (int s = start + threadIdx.x; s < end; s += 256) {
        int src, dst, bucket;
        edge_of(pe, ne, s, src, dst, bucket);
        atomicAdd(&lh[bucket], 1);
    }
    __syncthreads();
    for (int i = threadIdx.x; i < NBUK2; i += 256)
        hist[i * NBLK + blockIdx.x] = lh[i];   // bucket-major
}

// ---- generic hierarchical exclusive scan over NBUK2*NBLK ints ----
__global__ __launch_bounds__(256) void k_gscan1(const int* __restrict__ in,
                                                int* __restrict__ out,
                                                int* __restrict__ partials) {
    int i = blockIdx.x * 256 + threadIdx.x;
    int v = in[i];
    __shared__ int s[256];
    s[threadIdx.x] = v;
    __syncthreads();
    for (int off = 1; off < 256; off <<= 1) {
        int u = (threadIdx.x >= off) ? s[threadIdx.x - off] : 0;
        __syncthreads();
        s[threadIdx.x] += u;
        __syncthreads();
    }
    out[i] = s[threadIdx.x] - v;
    if (threadIdx.x == 255) partials[blockIdx.x] = s[255];
}

__global__ __launch_bounds__(1024) void k_gscan2(int* __restrict__ partials) {
    __shared__ int s[1024];
    int v = (threadIdx.x < GSB) ? partials[threadIdx.x] : 0;
    s[threadIdx.x] = v;
    __syncthreads();
    for (int off = 1; off < 1024; off <<= 1) {
        int u = (threadIdx.x >= off) ? s[threadIdx.x - off] : 0;
        __syncthreads();
        s[threadIdx.x] += u;
        __syncthreads();
    }
    if (threadIdx.x < GSB) partials[threadIdx.x] = s[threadIdx.x] - v;
}

__global__ __launch_bounds__(256) void k_gscan3(const int* __restrict__ partials,
                                                int* __restrict__ out) {
    out[blockIdx.x * 256 + threadIdx.x] += partials[blockIdx.x];
}

// ---- pass 2: scatter edges into bucket-grouped staging (block-exclusive runs) ----
__global__ __launch_bounds__(256) void k_binscatter(const int* __restrict__ pe,
                                                    const int* __restrict__ ne,
                                                    const int* __restrict__ soff,
                                                    unsigned long long* __restrict__ staging) {
    __shared__ int cur[NBUK2];
    for (int i = threadIdx.x; i < NBUK2; i += 256)
        cur[i] = soff[i * NBLK + blockIdx.x];
    __syncthreads();
    int start = blockIdx.x * EPB, end = min(start + EPB, 2 * EE);
    for (int s = start + threadIdx.x; s < end; s += 256) {
        int src, dst, bucket;
        edge_of(pe, ne, s, src, dst, bucket);
        int pos = atomicAdd(&cur[bucket], 1);
        staging[pos] = ((unsigned long long)(unsigned)dst << 32) | (unsigned)src;
    }
}

// ---- pass 3: per-bucket local build: rp (degree+scan in LDS) + csr scatter ----
__global__ __launch_bounds__(256) void k_local(const unsigned long long* __restrict__ staging,
                                               const int* __restrict__ soff,
                                               int* __restrict__ rpP,
                                               int* __restrict__ rpN,
                                               int* __restrict__ csrAll) {
    int bucket = blockIdx.x;
    int rel = bucket >= NBUK;
    int nodeBase = (bucket - rel * NBUK) << 8;
    int bstart = soff[bucket * NBLK];
    int bend = (bucket == NBUK2 - 1) ? 2 * EE : soff[(bucket + 1) * NBLK];
    int tid = threadIdx.x;
    __shared__ int deg[256], sc[256];
    deg[tid] = 0;
    __syncthreads();
    for (int i = bstart + tid; i < bend; i += 256) {
        int d = (int)(staging[i] >> 32) & 255;
        atomicAdd(&deg[d], 1);
    }
    __syncthreads();
    int dv = deg[tid];
    sc[tid] = dv;
    __syncthreads();
    for (int off = 1; off < 256; off <<= 1) {
        int u = (tid >= off) ? sc[tid - off] : 0;
        __syncthreads();
        sc[tid] += u;
        __syncthreads();
    }
    int lrp = sc[tid] - dv;  // bucket-local exclusive prefix
    int nCount = min(256, NN - nodeBase);
    int relbase = rel ? EE : 0;
    if (tid < nCount) (rel ? rpN : rpP)[nodeBase + tid] = bstart - relbase + lrp;
    if (bucket == NBUK - 1 && tid == 0) rpP[NN] = EE;
    if (bucket == NBUK2 - 1 && tid == 0) rpN[NN] = EE;
    deg[tid] = lrp;          // reuse as cursor
    __syncthreads();
    for (int i = bstart + tid; i < bend; i += 256) {
        unsigned long long v = staging[i];
        int d = (int)(v >> 32) & 255;
        int src = (int)(v & 0xffffffffu);
        int slot = atomicAdd(&deg[d], 1);
        csrAll[bstart + slot] = src;
    }
}

// ---- xf1 via MFMA, persistent: xp=x@Wp, xn=x@Wn, xs=x@Ws (64->32), hi/lo split ----
// 192 thr = 3 waves; wave m owns matrix m. 16-row tiles (NN%16==0), grid-stride.
__global__ __launch_bounds__(192) __attribute__((amdgpu_waves_per_eu(2, 4)))
void k_xf1(const float* __restrict__ x,
           const float* __restrict__ Wp,
           const float* __restrict__ Wn,
           const float* __restrict__ Ws,
           float* __restrict__ xp,
           float* __restrict__ xn,
           float* __restrict__ xs) {
    int tid = threadIdx.x;
    int wvm = tid >> 6;
    int l = tid & 63;
    int r16 = l & 15, kg = l >> 4;
    const float* W = (wvm == 0) ? Wp : (wvm == 1) ? Wn : Ws;
    float* outm = (wvm == 0) ? xp : (wvm == 1) ? xn : xs;

    // invariant B fragments, hi/lo: [ct][h]
    bf16x8 bh[2][2], bl[2][2];
    #pragma unroll
    for (int ct = 0; ct < 2; ct++)
        #pragma unroll
        for (int h = 0; h < 2; h++)
            #pragma unroll
            for (int i = 0; i < 8; i++) {
                int k = h * 32 + kmap(kg, i);
                float w = W[k * 32 + ct * 16 + r16];
                short hi = f2bf(w);
                bh[ct][h][i] = hi;
                bl[ct][h][i] = f2bf(w - bf2f(hi));
            }

    for (int tile = blockIdx.x; tile < XFT; tile += XF_GRID) {
        int rbase = tile * 16;
        int arow = rbase + r16;
        bf16x8 ah[2], al[2];
        #pragma unroll
        for (int h = 0; h < 2; h++) {
            int k0 = h * 32 + kg * 4;
            int k1 = h * 32 + 16 + kg * 4;
            float4 v0 = *(const float4*)&x[(size_t)arow * 64 + k0];
            float4 v1 = *(const float4*)&x[(size_t)arow * 64 + k1];
            split8(v0, v1, ah[h], al[h]);
        }
        f32x4 acc[2];
        #pragma unroll
        for (int ct = 0; ct < 2; ct++) { acc[ct][0] = 0.f; acc[ct][1] = 0.f; acc[ct][2] = 0.f; acc[ct][3] = 0.f; }
        #pragma unroll
        for (int h = 0; h < 2; h++)
            #pragma unroll
            for (int ct = 0; ct < 2; ct++) {
                acc[ct] = __builtin_amdgcn_mfma_f32_16x16x32_bf16(ah[h], bh[ct][h], acc[ct], 0, 0, 0);
                acc[ct] = __builtin_amdgcn_mfma_f32_16x16x32_bf16(al[h], bh[ct][h], acc[ct], 0, 0, 0);
                acc[ct] = __builtin_amdgcn_mfma_f32_16x16x32_bf16(ah[h], bl[ct][h], acc[ct], 0, 0, 0);
            }
        #pragma unroll
        for (int ct = 0; ct < 2; ct++)
            #pragma unroll
            for (int i = 0; i < 4; i++)
                outm[(size_t)(rbase + kg * 4 + i) * 32 + ct * 16 + r16] = acc[ct][i];
    }
}

// ---- xf2 via MFMA, persistent: 32->32, K=32 (single k-half), hi/lo split ----
__global__ __launch_bounds__(192) __attribute__((amdgpu_waves_per_eu(2, 4)))
void k_xf2(const float* __restrict__ z,
           const float* __restrict__ Wp,
           const float* __restrict__ Wn,
           const float* __restrict__ Ws,
           float* __restrict__ xp,
           float* __restrict__ xn,
           float* __restrict__ xs) {
    int tid = threadIdx.x;
    int wvm = tid >> 6;
    int l = tid & 63;
    int r16 = l & 15, kg = l >> 4;
    const float* W = (wvm == 0) ? Wp : (wvm == 1) ? Wn : Ws;
    float* outm = (wvm == 0) ? xp : (wvm == 1) ? xn : xs;

    bf16x8 bh[2], bl[2];
    #pragma unroll
    for (int ct = 0; ct < 2; ct++)
        #pragma unroll
        for (int i = 0; i < 8; i++) {
            int k = kmap(kg, i);
            float w = W[k * 32 + ct * 16 + r16];
            short hi = f2bf(w);
            bh[ct][i] = hi;
            bl[ct][i] = f2bf(w - bf2f(hi));
        }

    for (int tile = blockIdx.x; tile < XFT; tile += XF_GRID) {
        int rbase = tile * 16;
        int arow = rbase + r16;
        float4 v0 = *(const float4*)&z[(size_t)arow * 32 + kg * 4];
        float4 v1 = *(const float4*)&z[(size_t)arow * 32 + 16 + kg * 4];
        bf16x8 ah, al;
        split8(v0, v1, ah, al);
        f32x4 acc[2];
        #pragma unroll
        for (int ct = 0; ct < 2; ct++) { acc[ct][0] = 0.f; acc[ct][1] = 0.f; acc[ct][2] = 0.f; acc[ct][3] = 0.f; }
        #pragma unroll
        for (int ct = 0; ct < 2; ct++) {
            acc[ct] = __builtin_amdgcn_mfma_f32_16x16x32_bf16(ah, bh[ct], acc[ct], 0, 0, 0);
            acc[ct] = __builtin_amdgcn_mfma_f32_16x16x32_bf16(al, bh[ct], acc[ct], 0, 0, 0);
            acc[ct] = __builtin_amdgcn_mfma_f32_16x16x32_bf16(ah, bl[ct], acc[ct], 0, 0, 0);
        }
        #pragma unroll
        for (int ct = 0; ct < 2; ct++)
            #pragma unroll
            for (int i = 0; i < 4; i++)
                outm[(size_t)(rbase + kg * 4 + i) * 32 + ct * 16 + r16] = acc[ct][i];
    }
}

// ---- accumulate one relation's neighbors ----
__device__ __forceinline__ float pull_rel(const float* __restrict__ xsrc,
                                          const int* __restrict__ csr,
                                          int b0, int b1, int j, float acc) {
    for (int base = b0; base < b1; base += 32) {
        int rem = b1 - base;
        int cnt = min(rem, 32);
        int idx = (j < rem) ? csr[base + j] : 0;
        int i = 0;
        for (; i + 4 <= cnt; i += 4) {
            int s0 = __shfl(idx, i, 32);
            int s1 = __shfl(idx, i + 1, 32);
            int s2 = __shfl(idx, i + 2, 32);
            int s3 = __shfl(idx, i + 3, 32);
            float v0 = xsrc[(size_t)s0 * 32 + j];
            float v1 = xsrc[(size_t)s1 * 32 + j];
            float v2 = xsrc[(size_t)s2 * 32 + j];
            float v3 = xsrc[(size_t)s3 * 32 + j];
            acc += v0; acc += v1; acc += v2; acc += v3;
        }
        for (; i < cnt; i++) {
            int s = __shfl(idx, i, 32);
            acc += xsrc[(size_t)s * 32 + j];
        }
    }
    return acc;
}

// ---- pull aggregation + combine + tanh ----
__global__ __launch_bounds__(256) void k_pull(const float* __restrict__ xp,
                                              const float* __restrict__ xn,
                                              const float* __restrict__ xs,
                                              const int* __restrict__ rpP,
                                              const int* __restrict__ csrP,
                                              const int* __restrict__ rpN,
                                              const int* __restrict__ csrN,
                                              const float* __restrict__ bp,
                                              const float* __restrict__ bn,
                                              const float* __restrict__ bs,
                                              float* __restrict__ out) {
    int j = threadIdx.x & 31;
    int hw = (blockIdx.x * 256 + threadIdx.x) >> 5;
    const int nhw = (2048 * 256) >> 5;
    float bpj = bp[j], bnj = bn[j], bsj = bs[j];
    for (int n = hw; n < NN; n += nhw) {
        int p0 = rpP[n], p1 = rpP[n + 1];
        int n0 = rpN[n], n1 = rpN[n + 1];
        float acc = xs[(size_t)n * 32 + j] + bsj
                  + (float)(p1 - p0) * bpj + (float)(n1 - n0) * bnj;
        acc = pull_rel(xp, csrP, p0, p1, j, acc);
        acc = pull_rel(xn, csrN, n0, n1, j, acc);
        out[(size_t)n * 32 + j] = tanhf(acc);
    }
}

// ---- z = tanh(z2 @ Wl + bl): 32->64, 64-row tiles (output 0) ----
__global__ __launch_bounds__(256) __attribute__((amdgpu_waves_per_eu(2, 4)))
void k_wlin(const float* __restrict__ z2,
            const float* __restrict__ Wl,
            const float* __restrict__ bl,
            float* __restrict__ z) {
    __shared__ float sx[64 * 32];   // z2 tile (8KB)
    int base = blockIdx.x * 64;
    int tid = threadIdx.x;
    int lane = tid & 63;
    int wv = tid >> 6;
    {
        int row = tid >> 2, c4 = tid & 3;
        int n = base + row;
        #pragma unroll
        for (int m = 0; m < 2; m++) {
            int f = c4 + 4 * m;
            float4 v = (n < NN) ? *(const float4*)&z2[(size_t)n * 32 + f * 4]
                                : make_float4(0.f, 0.f, 0.f, 0.f);
            *(float4*)&sx[row * 32 + f * 4] = v;
        }
    }
    float wl[32];
    #pragma unroll
    for (int k = 0; k < 32; k++) wl[k] = Wl[k * 64 + lane];
    float blj = bl[lane];
    __syncthreads();
    #pragma unroll 1
    for (int i = 0; i < 16; i++) {
        int nl = i * 4 + wv;
        int n = base + nl;
        float a0 = 0.f, a1c = 0.f, a2 = 0.f, a3 = 0.f;
        #pragma unroll
        for (int q = 0; q < 8; q++) {
            float4 xv = *(const float4*)&sx[nl * 32 + q * 4];
            a0 += xv.x * wl[q * 4 + 0];
            a1c += xv.y * wl[q * 4 + 1];
            a2 += xv.z * wl[q * 4 + 2];
            a3 += xv.w * wl[q * 4 + 3];
        }
        if (n < NN) z[(size_t)n * 64 + lane] = tanhf(blj + ((a0 + a1c) + (a2 + a3)));
    }
}

// ---- MFMA MLP GEMM, persistent tiles: out = [relu(in*a+c) or in] @ W + b, column stats ----
__global__ __launch_bounds__(256) __attribute__((amdgpu_waves_per_eu(2, 4)))
void k_mlp(const float* __restrict__ in,
           const float* __restrict__ a1,
           const float* __restrict__ c1,
           int doBN,
           const float* __restrict__ W,
           const float* __restrict__ b,
           float* __restrict__ out,
           float* __restrict__ colsum,
           float* __restrict__ colsq) {
    __shared__ float scol[64], ssq[64];
    int tid = threadIdx.x;
    if (tid < 64) { scol[tid] = 0.f; ssq[tid] = 0.f; }
    int wv = tid >> 6;
    int l = tid & 63;
    int r16 = l & 15, kg = l >> 4;

    // B fragments (invariant): bf[ct][h][i] = W[h*32 + kmap(i)][ct*16 + r16]
    bf16x8 bf[4][2];
    #pragma unroll
    for (int ct = 0; ct < 4; ct++)
        #pragma unroll
        for (int h = 0; h < 2; h++)
            #pragma unroll
            for (int i = 0; i < 8; i++) {
                int k = h * 32 + kmap(kg, i);
                bf[ct][h][i] = f2bf(W[k * 64 + ct * 16 + r16]);
            }
    float bj[4];
    #pragma unroll
    for (int ct = 0; ct < 4; ct++) bj[ct] = b[ct * 16 + r16];

    // BN coefficients for this thread's A-fragment k positions (invariant)
    float av0[2][4], cv0[2][4], av1[2][4], cv1[2][4];
    #pragma unroll
    for (int h = 0; h < 2; h++) {
        int k0 = h * 32 + kg * 4;
        int k1 = h * 32 + 16 + kg * 4;
        #pragma unroll
        for (int i = 0; i < 4; i++) {
            av0[h][i] = doBN ? a1[k0 + i] : 1.f;
            cv0[h][i] = doBN ? c1[k0 + i] : 0.f;
            av1[h][i] = doBN ? a1[k1 + i] : 1.f;
            cv1[h][i] = doBN ? c1[k1 + i] : 0.f;
        }
    }

    float lsum[4] = {0.f, 0.f, 0.f, 0.f}, lsq[4] = {0.f, 0.f, 0.f, 0.f};

    for (int tile = blockIdx.x; tile < GTILES; tile += MLP_GRID) {
        int base = tile * 64;
        int arow = base + wv * 16 + r16;
        bool rv = arow < NN;
        bf16x8 af[2];
        #pragma unroll
        for (int h = 0; h < 2; h++) {
            int k0 = h * 32 + kg * 4;
            int k1 = h * 32 + 16 + kg * 4;
            float4 v0 = rv ? *(const float4*)&in[(size_t)arow * 64 + k0]
                           : make_float4(0.f, 0.f, 0.f, 0.f);
            float4 v1 = rv ? *(const float4*)&in[(size_t)arow * 64 + k1]
                           : make_float4(0.f, 0.f, 0.f, 0.f);
            if (doBN) {
                v0.x = fmaxf(v0.x * av0[h][0] + cv0[h][0], 0.f);
                v0.y = fmaxf(v0.y * av0[h][1] + cv0[h][1], 0.f);
                v0.z = fmaxf(v0.z * av0[h][2] + cv0[h][2], 0.f);
                v0.w = fmaxf(v0.w * av0[h][3] + cv0[h][3], 0.f);
                v1.x = fmaxf(v1.x * av1[h][0] + cv1[h][0], 0.f);
                v1.y = fmaxf(v1.y * av1[h][1] + cv1[h][1], 0.f);
                v1.z = fmaxf(v1.z * av1[h][2] + cv1[h][2], 0.f);
                v1.w = fmaxf(v1.w * av1[h][3] + cv1[h][3], 0.f);
            }
            af[h][0] = f2bf(v0.x); af[h][1] = f2bf(v0.y);
            af[h][2] = f2bf(v0.z); af[h][3] = f2bf(v0.w);
            af[h][4] = f2bf(v1.x); af[h][5] = f2bf(v1.y);
            af[h][6] = f2bf(v1.z); af[h][7] = f2bf(v1.w);
        }

        f32x4 acc[4];
        #pragma unroll
        for (int ct = 0; ct < 4; ct++) { acc[ct][0] = 0.f; acc[ct][1] = 0.f; acc[ct][2] = 0.f; acc[ct][3] = 0.f; }
        #pragma unroll
        for (int h = 0; h < 2; h++)
            #pragma unroll
            for (int ct = 0; ct < 4; ct++)
                acc[ct] = __builtin_amdgcn_mfma_f32_16x16x32_bf16(af[h], bf[ct][h], acc[ct], 0, 0, 0);

        #pragma unroll
        for (int ct = 0; ct < 4; ct++) {
            int col = ct * 16 + r16;
            #pragma unroll
            for (int i = 0; i < 4; i++) {
                int orow = base + wv * 16 + kg * 4 + i;   // D: row=(l>>4)*4+reg
                if (orow < NN) {
                    float s = acc[ct][i] + bj[ct];
                    out[(size_t)orow * 64 + col] = s;
                    lsum[ct] += s; lsq[ct] += s * s;
                }
            }
        }
    }

    __syncthreads();   // scol/ssq init visible
    #pragma unroll
    for (int ct = 0; ct < 4; ct++) {
        atomicAdd(&scol[ct * 16 + r16], lsum[ct]);
        atomicAdd(&ssq[ct * 16 + r16], lsq[ct]);
    }
    __syncthreads();
    if (tid < 64) {
        fatomic(&colsum[tid], scol[tid]);
        fatomic(&colsq[tid], ssq[tid]);
    }
}

// ---- BN stats -> affine coefficients a, c (h_norm = t*a + c) ----
__global__ void k_bnstats(const float* __restrict__ colsum, const float* __restrict__ colsq,
                          const float* __restrict__ g, const float* __restrict__ beta,
                          float* __restrict__ a, float* __restrict__ c) {
    int j = threadIdx.x;
    if (j < 64) {
        float m = colsum[j] * (1.f / NN);
        float v = colsq[j] * (1.f / NN) - m * m;
        float aj = g[j] * rsqrtf(v + EPSF);
        a[j] = aj;
        c[j] = beta[j] - m * aj;
    }
}

// ---- prob = sigmoid(relu(t2*a2+c2) @ m3_W + m3_b) ----
__global__ __launch_bounds__(256) void k_mlp3(const float* __restrict__ t2,
                                              const float* __restrict__ a2,
                                              const float* __restrict__ c2,
                                              const float* __restrict__ W3,
                                              const float* __restrict__ b3,
                                              float* __restrict__ prob) {
    int j = threadIdx.x & 63;
    int r = threadIdx.x >> 6;
    float aj = a2[j], cj = c2[j], wj = W3[j], bb = b3[0];
    for (int n = blockIdx.x * 4 + r; n < NN; n += 2048 * 4) {
        float h = fmaxf(t2[(size_t)n * 64 + j] * aj + cj, 0.f) * wj;
        #pragma unroll
        for (int off = 32; off > 0; off >>= 1) h += __shfl_xor(h, off, 64);
        if (j == 0) prob[n] = 1.f / (1.f + expf(-(h + bb)));
    }
}

extern "C" void kernel_launch(void* const* d_in, const int* in_sizes, int n_in,
                              void* d_out, int out_size, void* d_ws, size_t ws_size,
                              hipStream_t stream) {
    const float* init_emb = (const float*)d_in[0];
    const int* pe = (const int*)d_in[1];
    const int* ne = (const int*)d_in[2];
    const float* c1_Wp = (const float*)d_in[3];  const float* c1_bp = (const float*)d_in[4];
    const float* c1_Wn = (const float*)d_in[5];  const float* c1_bn = (const float*)d_in[6];
    const float* c1_Ws = (const float*)d_in[7];  const float* c1_bs = (const float*)d_in[8];
    const float* c2_Wp = (const float*)d_in[9];  const float* c2_bp = (const float*)d_in[10];
    const float* c2_Wn = (const float*)d_in[11]; const float* c2_bn = (const float*)d_in[12];
    const float* c2_Ws = (const float*)d_in[13]; const float* c2_bs = (const float*)d_in[14];
    const float* w_W = (const float*)d_in[15];   const float* w_b = (const float*)d_in[16];
    const float* m1_W = (const float*)d_in[17];  const float* m1_b = (const float*)d_in[18];
    const float* g1 = (const float*)d_in[19];    const float* b1 = (const float*)d_in[20];
    const float* m2_W = (const float*)d_in[21];  const float* m2_b = (const float*)d_in[22];
    const float* g2 = (const float*)d_in[23];    const float* b2 = (const float*)d_in[24];
    const float* m3_W = (const float*)d_in[25];  const float* m3_b = (const float*)d_in[26];

    // ---- workspace arena ----
    size_t off = 0;
    auto alloc = [&](size_t bytes) -> void* {
        void* r = (char*)d_ws + off;
        off += (bytes + 255) & ~(size_t)255;
        return r;
    };
    // zero region (front): only BN stat accumulators
    float* sums = (float*)alloc(256 * 4);               // colsum1, colsq1, colsum2, colsq2
    size_t zero_bytes = off;
    // CSR-build region (dead after second k_pull; t2 aliases it later)
    size_t csr_region = off;
    int*   hist = (int*)alloc((size_t)NBUK2 * NBLK * 4);        // 800KB
    int*   soff = (int*)alloc((size_t)NBUK2 * NBLK * 4);        // 800KB
    int*   part = (int*)alloc((size_t)1024 * 4);
    unsigned long long* staging = (unsigned long long*)alloc((size_t)2 * EE * 8);  // 16MB
    int*   csrAll = (int*)alloc((size_t)2 * EE * 4);            // 8MB
    // persistent
    int*   rpP  = (int*)alloc((size_t)(NN + 1) * 4);
    int*   rpN  = (int*)alloc((size_t)(NN + 1) * 4);
    float* R1   = (float*)alloc((size_t)NN * 96 * 4);   // {xp,xn,xs} layer1 -> layer2 -> t1
    float* z1   = (float*)alloc((size_t)NN * 32 * 4);
    float* z2   = (float*)alloc((size_t)NN * 32 * 4);
    float* abc  = (float*)alloc(256 * 4);               // a1, c1, a2, c2

    int* csrP = csrAll;
    int* csrN = csrAll + (size_t)EE;
    float* xp = R1;
    float* xn = R1 + (size_t)NN * 32;
    float* xs = R1 + (size_t)NN * 64;
    float* t1 = R1;                                     // dead xp/xn region after wlin
    float* t2 = (float*)((char*)d_ws + csr_region);     // aliases CSR-build scratch (25.6MB fits)

    float* z_out = (float*)d_out;                       // [N,64]
    float* prob  = (float*)d_out + (size_t)NN * 64;     // [N,1]

    hipMemsetAsync(d_ws, 0, zero_bytes, stream);

    // ---- CSR build: hist -> scan -> bin scatter -> per-bucket local build ----
    k_hist<<<NBLK, 256, 0, stream>>>(pe, ne, hist);
    k_gscan1<<<GSB, 256, 0, stream>>>(hist, soff, part);
    k_gscan2<<<1, 1024, 0, stream>>>(part);
    k_gscan3<<<GSB, 256, 0, stream>>>(part, soff);
    k_binscatter<<<NBLK, 256, 0, stream>>>(pe, ne, soff, staging);
    k_local<<<NBUK2, 256, 0, stream>>>(staging, soff, rpP, rpN, csrAll);

    // layer 1
    k_xf1<<<XF_GRID, 192, 0, stream>>>(init_emb, c1_Wp, c1_Wn, c1_Ws, xp, xn, xs);
    k_pull<<<2048, 256, 0, stream>>>(xp, xn, xs, rpP, csrP, rpN, csrN, c1_bp, c1_bn, c1_bs, z1);
    // layer 2
    k_xf2<<<XF_GRID, 192, 0, stream>>>(z1, c2_Wp, c2_Wn, c2_Ws, xp, xn, xs);
    k_pull<<<2048, 256, 0, stream>>>(xp, xn, xs, rpP, csrP, rpN, csrN, c2_bp, c2_bn, c2_bs, z2);
    // readout
    k_wlin<<<GTILES, 256, 0, stream>>>(z2, w_W, w_b, z_out);
    k_mlp<<<MLP_GRID, 256, 0, stream>>>(z_out, nullptr, nullptr, 0, m1_W, m1_b, t1, sums + 0, sums + 64);
    k_bnstats<<<1, 64, 0, stream>>>(sums + 0, sums + 64, g1, b1, abc + 0, abc + 64);
    k_mlp<<<MLP_GRID, 256, 0, stream>>>(t1, abc + 0, abc + 64, 1, m2_W, m2_b, t2, sums + 128, sums + 192);
    k_bnstats<<<1, 64, 0, stream>>>(sums + 128, sums + 192, g2, b2, abc + 128, abc + 192);
    k_mlp3<<<2048, 256, 0, stream>>>(t2, abc + 128, abc + 192, m3_W, m3_b, prob);
}

// Round 15
// 261.315 us; speedup vs baseline: 1.5851x; 1.0274x over previous
//
#include <hip/hip_runtime.h>
#include <cstdint>
#include <cstddef>

#define NN 100000
#define EE 1000000
#define EPSF 1e-5f
#define NBUK 391          // node buckets per relation: ceil(100000/256), dst>>8
#define NBUK2 (2*NBUK)    // both relations
#define NBLK 256          // edge-chunk blocks for hist/binscatter
#define EPB 7813          // ceil(2*EE / NBLK)
#define GSB 782           // scan blocks over NBUK2*NBLK entries (=200192/256)
#define GTILES ((NN + 63) / 64)   // 1563 64-node tiles
#define MLP_GRID 512      // persistent-ish: ~3 tiles/block, W-fragments amortized
#define XFT (NN / 16)     // 6250 16-row tiles (NN % 16 == 0)
#define XF_GRID 512

typedef __attribute__((ext_vector_type(8))) short bf16x8;
typedef __attribute__((ext_vector_type(4))) float f32x4;

__device__ __forceinline__ void fatomic(float* p, float v) { unsafeAtomicAdd(p, v); }

__device__ __forceinline__ short f2bf(float f) {
    unsigned u = __float_as_uint(f);
    u += 0x7FFF + ((u >> 16) & 1);   // round-to-nearest-even
    return (short)(u >> 16);
}
__device__ __forceinline__ float bf2f(short s) {
    return __uint_as_float(((unsigned)(unsigned short)s) << 16);
}
// hi/lo split of 8 floats -> 2 bf16x8 (x ~= hi + lo to ~fp32 precision)
__device__ __forceinline__ void split8(const float4 v0, const float4 v1, bf16x8& hi, bf16x8& lo) {
    float a[8] = {v0.x, v0.y, v0.z, v0.w, v1.x, v1.y, v1.z, v1.w};
    #pragma unroll
    for (int i = 0; i < 8; i++) {
        short h = f2bf(a[i]);
        hi[i] = h;
        lo[i] = f2bf(a[i] - bf2f(h));
    }
}
__device__ __forceinline__ int kmap(int kg, int i) {   // 16x16x32 A/B fragment k index
    return (i < 4) ? kg * 4 + i : 16 + kg * 4 + (i - 4);
}

// edge slot s in [0,2EE): rel 0 = pos, rel 1 = neg
__device__ __forceinline__ void edge_of(const int* __restrict__ pe, const int* __restrict__ ne,
                                        int s, int& src, int& dst, int& bucket) {
    if (s < EE) { src = pe[s]; dst = pe[EE + s]; bucket = dst >> 8; }
    else        { src = ne[s - EE]; dst = ne[s]; bucket = NBUK + (dst >> 8); }
}

// ---- pass 1: per-block bucket histogram ----
__global__ __launch_bounds__(256) void k_hist(const int* __restrict__ pe,
                                              const int* __restrict__ ne,
                                              int* __restrict__ hist) {
    __shared__ int lh[NBUK2];
    for (int i = threadIdx.x; i < NBUK2; i += 256) lh[i] = 0;
    __syncthreads();
    int start = blockIdx.x * EPB, end = min(start + EPB, 2 * EE);
    for (int s = start + threadIdx.x; s < end; s += 256) {
        int src, dst, bucket;
        edge_of(pe, ne, s, src, dst, bucket);
        atomicAdd(&lh[bucket], 1);
    }
    __syncthreads();
    for (int i = threadIdx.x; i < NBUK2; i += 256)
        hist[i * NBLK + blockIdx.x] = lh[i];   // bucket-major
}

// ---- generic hierarchical exclusive scan over NBUK2*NBLK ints ----
__global__ __launch_bounds__(256) void k_gscan1(const int* __restrict__ in,
                                                int* __restrict__ out,
                                                int* __restrict__ partials) {
    int i = blockIdx.x * 256 + threadIdx.x;
    int v = in[i];
    __shared__ int s[256];
    s[threadIdx.x] = v;
    __syncthreads();
    for (int off = 1; off < 256; off <<= 1) {
        int u = (threadIdx.x >= off) ? s[threadIdx.x - off] : 0;
        __syncthreads();
        s[threadIdx.x] += u;
        __syncthreads();
    }
    out[i] = s[threadIdx.x] - v;
    if (threadIdx.x == 255) partials[blockIdx.x] = s[255];
}

__global__ __launch_bounds__(1024) void k_gscan2(int* __restrict__ partials) {
    __shared__ int s[1024];
    int v = (threadIdx.x < GSB) ? partials[threadIdx.x] : 0;
    s[threadIdx.x] = v;
    __syncthreads();
    for (int off = 1; off < 1024; off <<= 1) {
        int u = (threadIdx.x >= off) ? s[threadIdx.x - off] : 0;
        __syncthreads();
        s[threadIdx.x] += u;
        __syncthreads();
    }
    if (threadIdx.x < GSB) partials[threadIdx.x] = s[threadIdx.x] - v;
}

__global__ __launch_bounds__(256) void k_gscan3(const int* __restrict__ partials,
                                                int* __restrict__ out) {
    out[blockIdx.x * 256 + threadIdx.x] += partials[blockIdx.x];
}

// ---- pass 2: scatter edges into bucket-grouped staging (block-exclusive runs) ----
// packed 32-bit: (dst&255)<<20 | src   (src < 2^17, halves staging traffic)
__global__ __launch_bounds__(256) void k_binscatter(const int* __restrict__ pe,
                                                    const int* __restrict__ ne,
                                                    const int* __restrict__ soff,
                                                    unsigned* __restrict__ staging) {
    __shared__ int cur[NBUK2];
    for (int i = threadIdx.x; i < NBUK2; i += 256)
        cur[i] = soff[i * NBLK + blockIdx.x];
    __syncthreads();
    int start = blockIdx.x * EPB, end = min(start + EPB, 2 * EE);
    for (int s = start + threadIdx.x; s < end; s += 256) {
        int src, dst, bucket;
        edge_of(pe, ne, s, src, dst, bucket);
        int pos = atomicAdd(&cur[bucket], 1);
        staging[pos] = ((unsigned)(dst & 255) << 20) | (unsigned)src;
    }
}

// ---- pass 3: per-bucket local build: rp (degree+scan in LDS) + csr scatter ----
__global__ __launch_bounds__(256) void k_local(const unsigned* __restrict__ staging,
                                               const int* __restrict__ soff,
                                               int* __restrict__ rpP,
                                               int* __restrict__ rpN,
                                               int* __restrict__ csrAll) {
    int bucket = blockIdx.x;
    int rel = bucket >= NBUK;
    int nodeBase = (bucket - rel * NBUK) << 8;
    int bstart = soff[bucket * NBLK];
    int bend = (bucket == NBUK2 - 1) ? 2 * EE : soff[(bucket + 1) * NBLK];
    int tid = threadIdx.x;
    __shared__ int deg[256], sc[256];
    deg[tid] = 0;
    __syncthreads();
    for (int i = bstart + tid; i < bend; i += 256) {
        int d = (int)(staging[i] >> 20);
        atomicAdd(&deg[d], 1);
    }
    __syncthreads();
    int dv = deg[tid];
    sc[tid] = dv;
    __syncthreads();
    for (int off = 1; off < 256; off <<= 1) {
        int u = (tid >= off) ? sc[tid - off] : 0;
        __syncthreads();
        sc[tid] += u;
        __syncthreads();
    }
    int lrp = sc[tid] - dv;  // bucket-local exclusive prefix
    int nCount = min(256, NN - nodeBase);
    int relbase = rel ? EE : 0;
    if (tid < nCount) (rel ? rpN : rpP)[nodeBase + tid] = bstart - relbase + lrp;
    if (bucket == NBUK - 1 && tid == 0) rpP[NN] = EE;
    if (bucket == NBUK2 - 1 && tid == 0) rpN[NN] = EE;
    deg[tid] = lrp;          // reuse as cursor
    __syncthreads();
    for (int i = bstart + tid; i < bend; i += 256) {
        unsigned v = staging[i];
        int d = (int)(v >> 20);
        int src = (int)(v & 0xFFFFFu);
        int slot = atomicAdd(&deg[d], 1);
        csrAll[bstart + slot] = src;
    }
}

// ---- xf1 via MFMA, persistent: xp=x@Wp, xn=x@Wn, xs=x@Ws (64->32), hi/lo split ----
__global__ __launch_bounds__(192) __attribute__((amdgpu_waves_per_eu(2, 4)))
void k_xf1(const float* __restrict__ x,
           const float* __restrict__ Wp,
           const float* __restrict__ Wn,
           const float* __restrict__ Ws,
           float* __restrict__ xp,
           float* __restrict__ xn,
           float* __restrict__ xs) {
    int tid = threadIdx.x;
    int wvm = tid >> 6;
    int l = tid & 63;
    int r16 = l & 15, kg = l >> 4;
    const float* W = (wvm == 0) ? Wp : (wvm == 1) ? Wn : Ws;
    float* outm = (wvm == 0) ? xp : (wvm == 1) ? xn : xs;

    bf16x8 bh[2][2], bl[2][2];
    #pragma unroll
    for (int ct = 0; ct < 2; ct++)
        #pragma unroll
        for (int h = 0; h < 2; h++)
            #pragma unroll
            for (int i = 0; i < 8; i++) {
                int k = h * 32 + kmap(kg, i);
                float w = W[k * 32 + ct * 16 + r16];
                short hi = f2bf(w);
                bh[ct][h][i] = hi;
                bl[ct][h][i] = f2bf(w - bf2f(hi));
            }

    for (int tile = blockIdx.x; tile < XFT; tile += XF_GRID) {
        int rbase = tile * 16;
        int arow = rbase + r16;
        bf16x8 ah[2], al[2];
        #pragma unroll
        for (int h = 0; h < 2; h++) {
            int k0 = h * 32 + kg * 4;
            int k1 = h * 32 + 16 + kg * 4;
            float4 v0 = *(const float4*)&x[(size_t)arow * 64 + k0];
            float4 v1 = *(const float4*)&x[(size_t)arow * 64 + k1];
            split8(v0, v1, ah[h], al[h]);
        }
        f32x4 acc[2];
        #pragma unroll
        for (int ct = 0; ct < 2; ct++) { acc[ct][0] = 0.f; acc[ct][1] = 0.f; acc[ct][2] = 0.f; acc[ct][3] = 0.f; }
        #pragma unroll
        for (int h = 0; h < 2; h++)
            #pragma unroll
            for (int ct = 0; ct < 2; ct++) {
                acc[ct] = __builtin_amdgcn_mfma_f32_16x16x32_bf16(ah[h], bh[ct][h], acc[ct], 0, 0, 0);
                acc[ct] = __builtin_amdgcn_mfma_f32_16x16x32_bf16(al[h], bh[ct][h], acc[ct], 0, 0, 0);
                acc[ct] = __builtin_amdgcn_mfma_f32_16x16x32_bf16(ah[h], bl[ct][h], acc[ct], 0, 0, 0);
            }
        #pragma unroll
        for (int ct = 0; ct < 2; ct++)
            #pragma unroll
            for (int i = 0; i < 4; i++)
                outm[(size_t)(rbase + kg * 4 + i) * 32 + ct * 16 + r16] = acc[ct][i];
    }
}

// ---- xf2 via MFMA, persistent: 32->32, K=32 ----
__global__ __launch_bounds__(192) __attribute__((amdgpu_waves_per_eu(2, 4)))
void k_xf2(const float* __restrict__ z,
           const float* __restrict__ Wp,
           const float* __restrict__ Wn,
           const float* __restrict__ Ws,
           float* __restrict__ xp,
           float* __restrict__ xn,
           float* __restrict__ xs) {
    int tid = threadIdx.x;
    int wvm = tid >> 6;
    int l = tid & 63;
    int r16 = l & 15, kg = l >> 4;
    const float* W = (wvm == 0) ? Wp : (wvm == 1) ? Wn : Ws;
    float* outm = (wvm == 0) ? xp : (wvm == 1) ? xn : xs;

    bf16x8 bh[2], bl[2];
    #pragma unroll
    for (int ct = 0; ct < 2; ct++)
        #pragma unroll
        for (int i = 0; i < 8; i++) {
            int k = kmap(kg, i);
            float w = W[k * 32 + ct * 16 + r16];
            short hi = f2bf(w);
            bh[ct][i] = hi;
            bl[ct][i] = f2bf(w - bf2f(hi));
        }

    for (int tile = blockIdx.x; tile < XFT; tile += XF_GRID) {
        int rbase = tile * 16;
        int arow = rbase + r16;
        float4 v0 = *(const float4*)&z[(size_t)arow * 32 + kg * 4];
        float4 v1 = *(const float4*)&z[(size_t)arow * 32 + 16 + kg * 4];
        bf16x8 ah, al;
        split8(v0, v1, ah, al);
        f32x4 acc[2];
        #pragma unroll
        for (int ct = 0; ct < 2; ct++) { acc[ct][0] = 0.f; acc[ct][1] = 0.f; acc[ct][2] = 0.f; acc[ct][3] = 0.f; }
        #pragma unroll
        for (int ct = 0; ct < 2; ct++) {
            acc[ct] = __builtin_amdgcn_mfma_f32_16x16x32_bf16(ah, bh[ct], acc[ct], 0, 0, 0);
            acc[ct] = __builtin_amdgcn_mfma_f32_16x16x32_bf16(al, bh[ct], acc[ct], 0, 0, 0);
            acc[ct] = __builtin_amdgcn_mfma_f32_16x16x32_bf16(ah, bl[ct], acc[ct], 0, 0, 0);
        }
        #pragma unroll
        for (int ct = 0; ct < 2; ct++)
            #pragma unroll
            for (int i = 0; i < 4; i++)
                outm[(size_t)(rbase + kg * 4 + i) * 32 + ct * 16 + r16] = acc[ct][i];
    }
}

// ---- accumulate one relation's neighbors ----
__device__ __forceinline__ float pull_rel(const float* __restrict__ xsrc,
                                          const int* __restrict__ csr,
                                          int b0, int b1, int j, float acc) {
    for (int base = b0; base < b1; base += 32) {
        int rem = b1 - base;
        int cnt = min(rem, 32);
        int idx = (j < rem) ? csr[base + j] : 0;
        int i = 0;
        for (; i + 4 <= cnt; i += 4) {
            int s0 = __shfl(idx, i, 32);
            int s1 = __shfl(idx, i + 1, 32);
            int s2 = __shfl(idx, i + 2, 32);
            int s3 = __shfl(idx, i + 3, 32);
            float v0 = xsrc[(size_t)s0 * 32 + j];
            float v1 = xsrc[(size_t)s1 * 32 + j];
            float v2 = xsrc[(size_t)s2 * 32 + j];
            float v3 = xsrc[(size_t)s3 * 32 + j];
            acc += v0; acc += v1; acc += v2; acc += v3;
        }
        for (; i < cnt; i++) {
            int s = __shfl(idx, i, 32);
            acc += xsrc[(size_t)s * 32 + j];
        }
    }
    return acc;
}

// ---- pull aggregation + combine + tanh ----
__global__ __launch_bounds__(256) void k_pull(const float* __restrict__ xp,
                                              const float* __restrict__ xn,
                                              const float* __restrict__ xs,
                                              const int* __restrict__ rpP,
                                              const int* __restrict__ csrP,
                                              const int* __restrict__ rpN,
                                              const int* __restrict__ csrN,
                                              const float* __restrict__ bp,
                                              const float* __restrict__ bn,
                                              const float* __restrict__ bs,
                                              float* __restrict__ out) {
    int j = threadIdx.x & 31;
    int hw = (blockIdx.x * 256 + threadIdx.x) >> 5;
    const int nhw = (2048 * 256) >> 5;
    float bpj = bp[j], bnj = bn[j], bsj = bs[j];
    for (int n = hw; n < NN; n += nhw) {
        int p0 = rpP[n], p1 = rpP[n + 1];
        int n0 = rpN[n], n1 = rpN[n + 1];
        float acc = xs[(size_t)n * 32 + j] + bsj
                  + (float)(p1 - p0) * bpj + (float)(n1 - n0) * bnj;
        acc = pull_rel(xp, csrP, p0, p1, j, acc);
        acc = pull_rel(xn, csrN, n0, n1, j, acc);
        out[(size_t)n * 32 + j] = tanhf(acc);
    }
}

// ---- wlin via MFMA, persistent: z = tanh(z2 @ Wl + bl), 32->64, hi/lo split ----
// 256 thr = 4 waves; each wave owns its own 16-row tile stream.
__global__ __launch_bounds__(256) __attribute__((amdgpu_waves_per_eu(2, 4)))
void k_wlin(const float* __restrict__ z2,
            const float* __restrict__ Wl,
            const float* __restrict__ bl,
            float* __restrict__ z) {
    int tid = threadIdx.x;
    int wv = tid >> 6;
    int l = tid & 63;
    int r16 = l & 15, kg = l >> 4;

    bf16x8 bh[4], blo[4];
    #pragma unroll
    for (int ct = 0; ct < 4; ct++)
        #pragma unroll
        for (int i = 0; i < 8; i++) {
            int k = kmap(kg, i);
            float w = Wl[k * 64 + ct * 16 + r16];
            short hi = f2bf(w);
            bh[ct][i] = hi;
            blo[ct][i] = f2bf(w - bf2f(hi));
        }
    float bj[4];
    #pragma unroll
    for (int ct = 0; ct < 4; ct++) bj[ct] = bl[ct * 16 + r16];

    for (int tile = blockIdx.x * 4 + wv; tile < XFT; tile += XF_GRID * 4) {
        int rbase = tile * 16;
        int arow = rbase + r16;
        float4 v0 = *(const float4*)&z2[(size_t)arow * 32 + kg * 4];
        float4 v1 = *(const float4*)&z2[(size_t)arow * 32 + 16 + kg * 4];
        bf16x8 ah, al;
        split8(v0, v1, ah, al);
        f32x4 acc[4];
        #pragma unroll
        for (int ct = 0; ct < 4; ct++) { acc[ct][0] = 0.f; acc[ct][1] = 0.f; acc[ct][2] = 0.f; acc[ct][3] = 0.f; }
        #pragma unroll
        for (int ct = 0; ct < 4; ct++) {
            acc[ct] = __builtin_amdgcn_mfma_f32_16x16x32_bf16(ah, bh[ct], acc[ct], 0, 0, 0);
            acc[ct] = __builtin_amdgcn_mfma_f32_16x16x32_bf16(al, bh[ct], acc[ct], 0, 0, 0);
            acc[ct] = __builtin_amdgcn_mfma_f32_16x16x32_bf16(ah, blo[ct], acc[ct], 0, 0, 0);
        }
        #pragma unroll
        for (int ct = 0; ct < 4; ct++)
            #pragma unroll
            for (int i = 0; i < 4; i++)
                z[(size_t)(rbase + kg * 4 + i) * 64 + ct * 16 + r16] = tanhf(acc[ct][i] + bj[ct]);
    }
}

// ---- MFMA MLP GEMM, persistent tiles: out = [relu(in*a+c) or in] @ W + b, column stats ----
__global__ __launch_bounds__(256) __attribute__((amdgpu_waves_per_eu(2, 4)))
void k_mlp(const float* __restrict__ in,
           const float* __restrict__ a1,
           const float* __restrict__ c1,
           int doBN,
           const float* __restrict__ W,
           const float* __restrict__ b,
           float* __restrict__ out,
           float* __restrict__ colsum,
           float* __restrict__ colsq) {
    __shared__ float scol[64], ssq[64];
    int tid = threadIdx.x;
    if (tid < 64) { scol[tid] = 0.f; ssq[tid] = 0.f; }
    int wv = tid >> 6;
    int l = tid & 63;
    int r16 = l & 15, kg = l >> 4;

    bf16x8 bf[4][2];
    #pragma unroll
    for (int ct = 0; ct < 4; ct++)
        #pragma unroll
        for (int h = 0; h < 2; h++)
            #pragma unroll
            for (int i = 0; i < 8; i++) {
                int k = h * 32 + kmap(kg, i);
                bf[ct][h][i] = f2bf(W[k * 64 + ct * 16 + r16]);
            }
    float bj[4];
    #pragma unroll
    for (int ct = 0; ct < 4; ct++) bj[ct] = b[ct * 16 + r16];

    float av0[2][4], cv0[2][4], av1[2][4], cv1[2][4];
    #pragma unroll
    for (int h = 0; h < 2; h++) {
        int k0 = h * 32 + kg * 4;
        int k1 = h * 32 + 16 + kg * 4;
        #pragma unroll
        for (int i = 0; i < 4; i++) {
            av0[h][i] = doBN ? a1[k0 + i] : 1.f;
            cv0[h][i] = doBN ? c1[k0 + i] : 0.f;
            av1[h][i] = doBN ? a1[k1 + i] : 1.f;
            cv1[h][i] = doBN ? c1[k1 + i] : 0.f;
        }
    }

    float lsum[4] = {0.f, 0.f, 0.f, 0.f}, lsq[4] = {0.f, 0.f, 0.f, 0.f};

    for (int tile = blockIdx.x; tile < GTILES; tile += MLP_GRID) {
        int base = tile * 64;
        int arow = base + wv * 16 + r16;
        bool rv = arow < NN;
        bf16x8 af[2];
        #pragma unroll
        for (int h = 0; h < 2; h++) {
            int k0 = h * 32 + kg * 4;
            int k1 = h * 32 + 16 + kg * 4;
            float4 v0 = rv ? *(const float4*)&in[(size_t)arow * 64 + k0]
                           : make_float4(0.f, 0.f, 0.f, 0.f);
            float4 v1 = rv ? *(const float4*)&in[(size_t)arow * 64 + k1]
                           : make_float4(0.f, 0.f, 0.f, 0.f);
            if (doBN) {
                v0.x = fmaxf(v0.x * av0[h][0] + cv0[h][0], 0.f);
                v0.y = fmaxf(v0.y * av0[h][1] + cv0[h][1], 0.f);
                v0.z = fmaxf(v0.z * av0[h][2] + cv0[h][2], 0.f);
                v0.w = fmaxf(v0.w * av0[h][3] + cv0[h][3], 0.f);
                v1.x = fmaxf(v1.x * av1[h][0] + cv1[h][0], 0.f);
                v1.y = fmaxf(v1.y * av1[h][1] + cv1[h][1], 0.f);
                v1.z = fmaxf(v1.z * av1[h][2] + cv1[h][2], 0.f);
                v1.w = fmaxf(v1.w * av1[h][3] + cv1[h][3], 0.f);
            }
            af[h][0] = f2bf(v0.x); af[h][1] = f2bf(v0.y);
            af[h][2] = f2bf(v0.z); af[h][3] = f2bf(v0.w);
            af[h][4] = f2bf(v1.x); af[h][5] = f2bf(v1.y);
            af[h][6] = f2bf(v1.z); af[h][7] = f2bf(v1.w);
        }

        f32x4 acc[4];
        #pragma unroll
        for (int ct = 0; ct < 4; ct++) { acc[ct][0] = 0.f; acc[ct][1] = 0.f; acc[ct][2] = 0.f; acc[ct][3] = 0.f; }
        #pragma unroll
        for (int h = 0; h < 2; h++)
            #pragma unroll
            for (int ct = 0; ct < 4; ct++)
                acc[ct] = __builtin_amdgcn_mfma_f32_16x16x32_bf16(af[h], bf[ct][h], acc[ct], 0, 0, 0);

        #pragma unroll
        for (int ct = 0; ct < 4; ct++) {
            int col = ct * 16 + r16;
            #pragma unroll
            for (int i = 0; i < 4; i++) {
                int orow = base + wv * 16 + kg * 4 + i;
                if (orow < NN) {
                    float s = acc[ct][i] + bj[ct];
                    out[(size_t)orow * 64 + col] = s;
                    lsum[ct] += s; lsq[ct] += s * s;
                }
            }
        }
    }

    __syncthreads();
    #pragma unroll
    for (int ct = 0; ct < 4; ct++) {
        atomicAdd(&scol[ct * 16 + r16], lsum[ct]);
        atomicAdd(&ssq[ct * 16 + r16], lsq[ct]);
    }
    __syncthreads();
    if (tid < 64) {
        fatomic(&colsum[tid], scol[tid]);
        fatomic(&colsq[tid], ssq[tid]);
    }
}

// ---- BN stats -> affine coefficients a, c (h_norm = t*a + c) ----
__global__ void k_bnstats(const float* __restrict__ colsum, const float* __restrict__ colsq,
                          const float* __restrict__ g, const float* __restrict__ beta,
                          float* __restrict__ a, float* __restrict__ c) {
    int j = threadIdx.x;
    if (j < 64) {
        float m = colsum[j] * (1.f / NN);
        float v = colsq[j] * (1.f / NN) - m * m;
        float aj = g[j] * rsqrtf(v + EPSF);
        a[j] = aj;
        c[j] = beta[j] - m * aj;
    }
}

// ---- prob = sigmoid(relu(t2*a2+c2) @ m3_W + m3_b) ----
__global__ __launch_bounds__(256) void k_mlp3(const float* __restrict__ t2,
                                              const float* __restrict__ a2,
                                              const float* __restrict__ c2,
                                              const float* __restrict__ W3,
                                              const float* __restrict__ b3,
                                              float* __restrict__ prob) {
    int j = threadIdx.x & 63;
    int r = threadIdx.x >> 6;
    float aj = a2[j], cj = c2[j], wj = W3[j], bb = b3[0];
    for (int n = blockIdx.x * 4 + r; n < NN; n += 2048 * 4) {
        float h = fmaxf(t2[(size_t)n * 64 + j] * aj + cj, 0.f) * wj;
        #pragma unroll
        for (int off = 32; off > 0; off >>= 1) h += __shfl_xor(h, off, 64);
        if (j == 0) prob[n] = 1.f / (1.f + expf(-(h + bb)));
    }
}

extern "C" void kernel_launch(void* const* d_in, const int* in_sizes, int n_in,
                              void* d_out, int out_size, void* d_ws, size_t ws_size,
                              hipStream_t stream) {
    const float* init_emb = (const float*)d_in[0];
    const int* pe = (const int*)d_in[1];
    const int* ne = (const int*)d_in[2];
    const float* c1_Wp = (const float*)d_in[3];  const float* c1_bp = (const float*)d_in[4];
    const float* c1_Wn = (const float*)d_in[5];  const float* c1_bn = (const float*)d_in[6];
    const float* c1_Ws = (const float*)d_in[7];  const float* c1_bs = (const float*)d_in[8];
    const float* c2_Wp = (const float*)d_in[9];  const float* c2_bp = (const float*)d_in[10];
    const float* c2_Wn = (const float*)d_in[11]; const float* c2_bn = (const float*)d_in[12];
    const float* c2_Ws = (const float*)d_in[13]; const float* c2_bs = (const float*)d_in[14];
    const float* w_W = (const float*)d_in[15];   const float* w_b = (const float*)d_in[16];
    const float* m1_W = (const float*)d_in[17];  const float* m1_b = (const float*)d_in[18];
    const float* g1 = (const float*)d_in[19];    const float* b1 = (const float*)d_in[20];
    const float* m2_W = (const float*)d_in[21];  const float* m2_b = (const float*)d_in[22];
    const float* g2 = (const float*)d_in[23];    const float* b2 = (const float*)d_in[24];
    const float* m3_W = (const float*)d_in[25];  const float* m3_b = (const float*)d_in[26];

    // ---- workspace arena ----
    size_t off = 0;
    auto alloc = [&](size_t bytes) -> void* {
        void* r = (char*)d_ws + off;
        off += (bytes + 255) & ~(size_t)255;
        return r;
    };
    // zero region (front): only BN stat accumulators
    float* sums = (float*)alloc(256 * 4);               // colsum1, colsq1, colsum2, colsq2
    size_t zero_bytes = off;
    // CSR-build region (dead after second k_pull; t2 aliases it later)
    size_t csr_region = off;
    int*   hist = (int*)alloc((size_t)NBUK2 * NBLK * 4);        // 800KB
    int*   soff = (int*)alloc((size_t)NBUK2 * NBLK * 4);        // 800KB
    int*   part = (int*)alloc((size_t)1024 * 4);
    unsigned* staging = (unsigned*)alloc((size_t)2 * EE * 8);   // 16MB reserved (8MB used, keeps t2 alias valid)
    int*   csrAll = (int*)alloc((size_t)2 * EE * 4);            // 8MB
    // persistent
    int*   rpP  = (int*)alloc((size_t)(NN + 1) * 4);
    int*   rpN  = (int*)alloc((size_t)(NN + 1) * 4);
    float* R1   = (float*)alloc((size_t)NN * 96 * 4);   // {xp,xn,xs} layer1 -> layer2 -> t1
    float* z1   = (float*)alloc((size_t)NN * 32 * 4);
    float* z2   = (float*)alloc((size_t)NN * 32 * 4);
    float* abc  = (float*)alloc(256 * 4);               // a1, c1, a2, c2

    int* csrP = csrAll;
    int* csrN = csrAll + (size_t)EE;
    float* xp = R1;
    float* xn = R1 + (size_t)NN * 32;
    float* xs = R1 + (size_t)NN * 64;
    float* t1 = R1;                                     // dead xp/xn region after wlin
    float* t2 = (float*)((char*)d_ws + csr_region);     // aliases CSR-build scratch (25.6MB fits)

    float* z_out = (float*)d_out;                       // [N,64]
    float* prob  = (float*)d_out + (size_t)NN * 64;     // [N,1]

    hipMemsetAsync(d_ws, 0, zero_bytes, stream);

    // ---- CSR build: hist -> scan -> bin scatter -> per-bucket local build ----
    k_hist<<<NBLK, 256, 0, stream>>>(pe, ne, hist);
    k_gscan1<<<GSB, 256, 0, stream>>>(hist, soff, part);
    k_gscan2<<<1, 1024, 0, stream>>>(part);
    k_gscan3<<<GSB, 256, 0, stream>>>(part, soff);
    k_binscatter<<<NBLK, 256, 0, stream>>>(pe, ne, soff, staging);
    k_local<<<NBUK2, 256, 0, stream>>>(staging, soff, rpP, rpN, csrAll);

    // layer 1
    k_xf1<<<XF_GRID, 192, 0, stream>>>(init_emb, c1_Wp, c1_Wn, c1_Ws, xp, xn, xs);
    k_pull<<<2048, 256, 0, stream>>>(xp, xn, xs, rpP, csrP, rpN, csrN, c1_bp, c1_bn, c1_bs, z1);
    // layer 2
    k_xf2<<<XF_GRID, 192, 0, stream>>>(z1, c2_Wp, c2_Wn, c2_Ws, xp, xn, xs);
    k_pull<<<2048, 256, 0, stream>>>(xp, xn, xs, rpP, csrP, rpN, csrN, c2_bp, c2_bn, c2_bs, z2);
    // readout
    k_wlin<<<XF_GRID, 256, 0, stream>>>(z2, w_W, w_b, z_out);
    k_mlp<<<MLP_GRID, 256, 0, stream>>>(z_out, nullptr, nullptr, 0, m1_W, m1_b, t1, sums + 0, sums + 64);
    k_bnstats<<<1, 64, 0, stream>>>(sums + 0, sums + 64, g1, b1, abc + 0, abc + 64);
    k_mlp<<<MLP_GRID, 256, 0, stream>>>(t1, abc + 0, abc + 64, 1, m2_W, m2_b, t2, sums + 128, sums + 192);
    k_bnstats<<<1, 64, 0, stream>>>(sums + 128, sums + 192, g2, b2, abc + 128, abc + 192);
    k_mlp3<<<2048, 256, 0, stream>>>(t2, abc + 128, abc + 192, m3_W, m3_b, prob);
}

// Round 16
// 247.047 us; speedup vs baseline: 1.6766x; 1.0578x over previous
//
#include <hip/hip_runtime.h>
#include <cstdint>
#include <cstddef>

#define NN 100000
#define EE 1000000
#define EPSF 1e-5f
#define NBUK 391          // node buckets per relation: ceil(100000/256), dst>>8
#define NBUK2 (2*NBUK)    // both relations
#define NBLK 256          // edge-chunk blocks for hist/binscatter
#define EPB 7813          // ceil(2*EE / NBLK)
#define GSB 782           // scan blocks over NBUK2*NBLK entries (=200192/256)
#define GTILES ((NN + 63) / 64)   // 1563 64-node tiles
#define MLP_GRID 512      // persistent-ish: ~3 tiles/block, W-fragments amortized
#define XFT (NN / 16)     // 6250 16-row tiles (NN % 16 == 0)
#define XF_GRID 512

typedef __attribute__((ext_vector_type(8))) short bf16x8;
typedef __attribute__((ext_vector_type(4))) float f32x4;

__device__ __forceinline__ void fatomic(float* p, float v) { unsafeAtomicAdd(p, v); }

__device__ __forceinline__ short f2bf(float f) {
    unsigned u = __float_as_uint(f);
    u += 0x7FFF + ((u >> 16) & 1);   // round-to-nearest-even
    return (short)(u >> 16);
}
__device__ __forceinline__ float bf2f(short s) {
    return __uint_as_float(((unsigned)(unsigned short)s) << 16);
}
// hi/lo split of 8 floats -> 2 bf16x8 (x ~= hi + lo to ~fp32 precision)
__device__ __forceinline__ void split8(const float4 v0, const float4 v1, bf16x8& hi, bf16x8& lo) {
    float a[8] = {v0.x, v0.y, v0.z, v0.w, v1.x, v1.y, v1.z, v1.w};
    #pragma unroll
    for (int i = 0; i < 8; i++) {
        short h = f2bf(a[i]);
        hi[i] = h;
        lo[i] = f2bf(a[i] - bf2f(h));
    }
}
__device__ __forceinline__ int kmap(int kg, int i) {   // 16x16x32 A/B fragment k index
    return (i < 4) ? kg * 4 + i : 16 + kg * 4 + (i - 4);
}

// edge slot s in [0,2EE): rel 0 = pos, rel 1 = neg
__device__ __forceinline__ void edge_of(const int* __restrict__ pe, const int* __restrict__ ne,
                                        int s, int& src, int& dst, int& bucket) {
    if (s < EE) { src = pe[s]; dst = pe[EE + s]; bucket = dst >> 8; }
    else        { src = ne[s - EE]; dst = ne[s]; bucket = NBUK + (dst >> 8); }
}

// ---- pass 1: per-block bucket histogram ----
__global__ __launch_bounds__(256) void k_hist(const int* __restrict__ pe,
                                              const int* __restrict__ ne,
                                              int* __restrict__ hist) {
    __shared__ int lh[NBUK2];
    for (int i = threadIdx.x; i < NBUK2; i += 256) lh[i] = 0;
    __syncthreads();
    int start = blockIdx.x * EPB, end = min(start + EPB, 2 * EE);
    for (int s = start + threadIdx.x; s < end; s += 256) {
        int src, dst, bucket;
        edge_of(pe, ne, s, src, dst, bucket);
        atomicAdd(&lh[bucket], 1);
    }
    __syncthreads();
    for (int i = threadIdx.x; i < NBUK2; i += 256)
        hist[i * NBLK + blockIdx.x] = lh[i];   // bucket-major
}

// ---- generic hierarchical exclusive scan over NBUK2*NBLK ints ----
__global__ __launch_bounds__(256) void k_gscan1(const int* __restrict__ in,
                                                int* __restrict__ out,
                                                int* __restrict__ partials) {
    int i = blockIdx.x * 256 + threadIdx.x;
    int v = in[i];
    __shared__ int s[256];
    s[threadIdx.x] = v;
    __syncthreads();
    for (int off = 1; off < 256; off <<= 1) {
        int u = (threadIdx.x >= off) ? s[threadIdx.x - off] : 0;
        __syncthreads();
        s[threadIdx.x] += u;
        __syncthreads();
    }
    out[i] = s[threadIdx.x] - v;
    if (threadIdx.x == 255) partials[blockIdx.x] = s[255];
}

__global__ __launch_bounds__(1024) void k_gscan2(int* __restrict__ partials) {
    __shared__ int s[1024];
    int v = (threadIdx.x < GSB) ? partials[threadIdx.x] : 0;
    s[threadIdx.x] = v;
    __syncthreads();
    for (int off = 1; off < 1024; off <<= 1) {
        int u = (threadIdx.x >= off) ? s[threadIdx.x - off] : 0;
        __syncthreads();
        s[threadIdx.x] += u;
        __syncthreads();
    }
    if (threadIdx.x < GSB) partials[threadIdx.x] = s[threadIdx.x] - v;
}

__global__ __launch_bounds__(256) void k_gscan3(const int* __restrict__ partials,
                                                int* __restrict__ out) {
    out[blockIdx.x * 256 + threadIdx.x] += partials[blockIdx.x];
}

// ---- pass 2: scatter edges into bucket-grouped staging (block-exclusive runs) ----
// packed 32-bit: (dst&255)<<20 | src
__global__ __launch_bounds__(256) void k_binscatter(const int* __restrict__ pe,
                                                    const int* __restrict__ ne,
                                                    const int* __restrict__ soff,
                                                    unsigned* __restrict__ staging) {
    __shared__ int cur[NBUK2];
    for (int i = threadIdx.x; i < NBUK2; i += 256)
        cur[i] = soff[i * NBLK + blockIdx.x];
    __syncthreads();
    int start = blockIdx.x * EPB, end = min(start + EPB, 2 * EE);
    for (int s = start + threadIdx.x; s < end; s += 256) {
        int src, dst, bucket;
        edge_of(pe, ne, s, src, dst, bucket);
        int pos = atomicAdd(&cur[bucket], 1);
        staging[pos] = ((unsigned)(dst & 255) << 20) | (unsigned)src;
    }
}

// ---- pass 3: per-bucket local build: rp (degree+scan in LDS) + csr scatter ----
__global__ __launch_bounds__(256) void k_local(const unsigned* __restrict__ staging,
                                               const int* __restrict__ soff,
                                               int* __restrict__ rpP,
                                               int* __restrict__ rpN,
                                               int* __restrict__ csrAll) {
    int bucket = blockIdx.x;
    int rel = bucket >= NBUK;
    int nodeBase = (bucket - rel * NBUK) << 8;
    int bstart = soff[bucket * NBLK];
    int bend = (bucket == NBUK2 - 1) ? 2 * EE : soff[(bucket + 1) * NBLK];
    int tid = threadIdx.x;
    __shared__ int deg[256], sc[256];
    deg[tid] = 0;
    __syncthreads();
    for (int i = bstart + tid; i < bend; i += 256) {
        int d = (int)(staging[i] >> 20);
        atomicAdd(&deg[d], 1);
    }
    __syncthreads();
    int dv = deg[tid];
    sc[tid] = dv;
    __syncthreads();
    for (int off = 1; off < 256; off <<= 1) {
        int u = (tid >= off) ? sc[tid - off] : 0;
        __syncthreads();
        sc[tid] += u;
        __syncthreads();
    }
    int lrp = sc[tid] - dv;  // bucket-local exclusive prefix
    int nCount = min(256, NN - nodeBase);
    int relbase = rel ? EE : 0;
    if (tid < nCount) (rel ? rpN : rpP)[nodeBase + tid] = bstart - relbase + lrp;
    if (bucket == NBUK - 1 && tid == 0) rpP[NN] = EE;
    if (bucket == NBUK2 - 1 && tid == 0) rpN[NN] = EE;
    deg[tid] = lrp;          // reuse as cursor
    __syncthreads();
    for (int i = bstart + tid; i < bend; i += 256) {
        unsigned v = staging[i];
        int d = (int)(v >> 20);
        int src = (int)(v & 0xFFFFFu);
        int slot = atomicAdd(&deg[d], 1);
        csrAll[bstart + slot] = src;
    }
}

// ---- xf1 via MFMA, persistent: xp=x@Wp, xn=x@Wn, xs=x@Ws (64->32), hi/lo split ----
__global__ __launch_bounds__(192) __attribute__((amdgpu_waves_per_eu(2, 4)))
void k_xf1(const float* __restrict__ x,
           const float* __restrict__ Wp,
           const float* __restrict__ Wn,
           const float* __restrict__ Ws,
           float* __restrict__ xp,
           float* __restrict__ xn,
           float* __restrict__ xs) {
    int tid = threadIdx.x;
    int wvm = tid >> 6;
    int l = tid & 63;
    int r16 = l & 15, kg = l >> 4;
    const float* W = (wvm == 0) ? Wp : (wvm == 1) ? Wn : Ws;
    float* outm = (wvm == 0) ? xp : (wvm == 1) ? xn : xs;

    bf16x8 bh[2][2], bl[2][2];
    #pragma unroll
    for (int ct = 0; ct < 2; ct++)
        #pragma unroll
        for (int h = 0; h < 2; h++)
            #pragma unroll
            for (int i = 0; i < 8; i++) {
                int k = h * 32 + kmap(kg, i);
                float w = W[k * 32 + ct * 16 + r16];
                short hi = f2bf(w);
                bh[ct][h][i] = hi;
                bl[ct][h][i] = f2bf(w - bf2f(hi));
            }

    for (int tile = blockIdx.x; tile < XFT; tile += XF_GRID) {
        int rbase = tile * 16;
        int arow = rbase + r16;
        bf16x8 ah[2], al[2];
        #pragma unroll
        for (int h = 0; h < 2; h++) {
            int k0 = h * 32 + kg * 4;
            int k1 = h * 32 + 16 + kg * 4;
            float4 v0 = *(const float4*)&x[(size_t)arow * 64 + k0];
            float4 v1 = *(const float4*)&x[(size_t)arow * 64 + k1];
            split8(v0, v1, ah[h], al[h]);
        }
        f32x4 acc[2];
        #pragma unroll
        for (int ct = 0; ct < 2; ct++) { acc[ct][0] = 0.f; acc[ct][1] = 0.f; acc[ct][2] = 0.f; acc[ct][3] = 0.f; }
        #pragma unroll
        for (int h = 0; h < 2; h++)
            #pragma unroll
            for (int ct = 0; ct < 2; ct++) {
                acc[ct] = __builtin_amdgcn_mfma_f32_16x16x32_bf16(ah[h], bh[ct][h], acc[ct], 0, 0, 0);
                acc[ct] = __builtin_amdgcn_mfma_f32_16x16x32_bf16(al[h], bh[ct][h], acc[ct], 0, 0, 0);
                acc[ct] = __builtin_amdgcn_mfma_f32_16x16x32_bf16(ah[h], bl[ct][h], acc[ct], 0, 0, 0);
            }
        #pragma unroll
        for (int ct = 0; ct < 2; ct++)
            #pragma unroll
            for (int i = 0; i < 4; i++)
                outm[(size_t)(rbase + kg * 4 + i) * 32 + ct * 16 + r16] = acc[ct][i];
    }
}

// ---- xf2 via MFMA, persistent: 32->32, K=32 ----
__global__ __launch_bounds__(192) __attribute__((amdgpu_waves_per_eu(2, 4)))
void k_xf2(const float* __restrict__ z,
           const float* __restrict__ Wp,
           const float* __restrict__ Wn,
           const float* __restrict__ Ws,
           float* __restrict__ xp,
           float* __restrict__ xn,
           float* __restrict__ xs) {
    int tid = threadIdx.x;
    int wvm = tid >> 6;
    int l = tid & 63;
    int r16 = l & 15, kg = l >> 4;
    const float* W = (wvm == 0) ? Wp : (wvm == 1) ? Wn : Ws;
    float* outm = (wvm == 0) ? xp : (wvm == 1) ? xn : xs;

    bf16x8 bh[2], bl[2];
    #pragma unroll
    for (int ct = 0; ct < 2; ct++)
        #pragma unroll
        for (int i = 0; i < 8; i++) {
            int k = kmap(kg, i);
            float w = W[k * 32 + ct * 16 + r16];
            short hi = f2bf(w);
            bh[ct][i] = hi;
            bl[ct][i] = f2bf(w - bf2f(hi));
        }

    for (int tile = blockIdx.x; tile < XFT; tile += XF_GRID) {
        int rbase = tile * 16;
        int arow = rbase + r16;
        float4 v0 = *(const float4*)&z[(size_t)arow * 32 + kg * 4];
        float4 v1 = *(const float4*)&z[(size_t)arow * 32 + 16 + kg * 4];
        bf16x8 ah, al;
        split8(v0, v1, ah, al);
        f32x4 acc[2];
        #pragma unroll
        for (int ct = 0; ct < 2; ct++) { acc[ct][0] = 0.f; acc[ct][1] = 0.f; acc[ct][2] = 0.f; acc[ct][3] = 0.f; }
        #pragma unroll
        for (int ct = 0; ct < 2; ct++) {
            acc[ct] = __builtin_amdgcn_mfma_f32_16x16x32_bf16(ah, bh[ct], acc[ct], 0, 0, 0);
            acc[ct] = __builtin_amdgcn_mfma_f32_16x16x32_bf16(al, bh[ct], acc[ct], 0, 0, 0);
            acc[ct] = __builtin_amdgcn_mfma_f32_16x16x32_bf16(ah, bl[ct], acc[ct], 0, 0, 0);
        }
        #pragma unroll
        for (int ct = 0; ct < 2; ct++)
            #pragma unroll
            for (int i = 0; i < 4; i++)
                outm[(size_t)(rbase + kg * 4 + i) * 32 + ct * 16 + r16] = acc[ct][i];
    }
}

// ---- accumulate one relation's neighbors, float4 lanes, 4 neighbor slots ----
// j32 = lane&31; q = j32&7 (float4 col), slot = j32>>3 (neighbor subset)
__device__ __forceinline__ float4 pull_rel4(const float* __restrict__ xsrc,
                                            const int* __restrict__ csr,
                                            int b0, int b1, int j32, int q, int slot,
                                            float4 acc) {
    for (int base = b0; base < b1; base += 32) {
        int rem = b1 - base;
        int cnt = min(rem, 32);
        int idx = (j32 < rem) ? csr[base + j32] : 0;
        int gmax = (cnt + 3) >> 2;   // uniform across the 32-lane half
        for (int g = 0; g < gmax; g++) {
            int nb = 4 * g + slot;
            int s = __shfl(idx, nb, 32);
            bool ok = nb < cnt;
            int ss = ok ? s : 0;
            float4 v = *(const float4*)&xsrc[(size_t)ss * 32 + q * 4];
            if (ok) { acc.x += v.x; acc.y += v.y; acc.z += v.z; acc.w += v.w; }
        }
    }
    return acc;
}

__device__ __forceinline__ float4 xor_reduce4(float4 a, int mask) {
    a.x += __shfl_xor(a.x, mask, 32);
    a.y += __shfl_xor(a.y, mask, 32);
    a.z += __shfl_xor(a.z, mask, 32);
    a.w += __shfl_xor(a.w, mask, 32);
    return a;
}

// ---- pull aggregation + combine + tanh ----
__global__ __launch_bounds__(256) void k_pull(const float* __restrict__ xp,
                                              const float* __restrict__ xn,
                                              const float* __restrict__ xs,
                                              const int* __restrict__ rpP,
                                              const int* __restrict__ csrP,
                                              const int* __restrict__ rpN,
                                              const int* __restrict__ csrN,
                                              const float* __restrict__ bp,
                                              const float* __restrict__ bn,
                                              const float* __restrict__ bs,
                                              float* __restrict__ out) {
    int j32 = threadIdx.x & 31;
    int q = j32 & 7;
    int slot = j32 >> 3;
    int hw = (blockIdx.x * 256 + threadIdx.x) >> 5;
    const int nhw = (2048 * 256) >> 5;
    float4 bp4 = *(const float4*)&bp[q * 4];
    float4 bn4 = *(const float4*)&bn[q * 4];
    float4 bs4 = *(const float4*)&bs[q * 4];
    for (int n = hw; n < NN; n += nhw) {
        int p0 = rpP[n], p1 = rpP[n + 1];
        int n0 = rpN[n], n1 = rpN[n + 1];
        float4 acc = make_float4(0.f, 0.f, 0.f, 0.f);
        acc = pull_rel4(xp, csrP, p0, p1, j32, q, slot, acc);
        acc = pull_rel4(xn, csrN, n0, n1, j32, q, slot, acc);
        acc = xor_reduce4(acc, 8);
        acc = xor_reduce4(acc, 16);
        if (slot == 0) {
            float4 xs4 = *(const float4*)&xs[(size_t)n * 32 + q * 4];
            float dp = (float)(p1 - p0), dn = (float)(n1 - n0);
            float4 r;
            r.x = tanhf(acc.x + xs4.x + dp * bp4.x + dn * bn4.x + bs4.x);
            r.y = tanhf(acc.y + xs4.y + dp * bp4.y + dn * bn4.y + bs4.y);
            r.z = tanhf(acc.z + xs4.z + dp * bp4.z + dn * bn4.z + bs4.z);
            r.w = tanhf(acc.w + xs4.w + dp * bp4.w + dn * bn4.w + bs4.w);
            *(float4*)&out[(size_t)n * 32 + q * 4] = r;
        }
    }
}

// ---- fused: z = tanh(z2@Wl + bl) (hi/lo MFMA), t1 = z@W1 + b1 (bf16 MFMA), BN stats ----
// persistent 16-row tiles; z bounced via per-wave padded LDS tile (stride 68)
__global__ __launch_bounds__(256) __attribute__((amdgpu_waves_per_eu(2, 3)))
void k_wlin_mlp1(const float* __restrict__ z2,
                 const float* __restrict__ Wl, const float* __restrict__ blv,
                 const float* __restrict__ W1, const float* __restrict__ b1v,
                 float* __restrict__ z, float* __restrict__ t1,
                 float* __restrict__ colsum, float* __restrict__ colsq) {
    __shared__ float zl[4][16 * 68];
    __shared__ float scol[64], ssq[64];
    int tid = threadIdx.x;
    if (tid < 64) { scol[tid] = 0.f; ssq[tid] = 0.f; }
    int wv = tid >> 6, l = tid & 63, r16 = l & 15, kg = l >> 4;
    float* myz = &zl[wv][0];

    // Wl (32x64) hi/lo fragments
    bf16x8 bh[4], blo[4];
    #pragma unroll
    for (int ct = 0; ct < 4; ct++)
        #pragma unroll
        for (int i = 0; i < 8; i++) {
            int k = kmap(kg, i);
            float w = Wl[k * 64 + ct * 16 + r16];
            short hi = f2bf(w);
            bh[ct][i] = hi;
            blo[ct][i] = f2bf(w - bf2f(hi));
        }
    float bjl[4];
    #pragma unroll
    for (int ct = 0; ct < 4; ct++) bjl[ct] = blv[ct * 16 + r16];

    // W1 (64x64) bf16 fragments
    bf16x8 b1f[4][2];
    #pragma unroll
    for (int ct = 0; ct < 4; ct++)
        #pragma unroll
        for (int h = 0; h < 2; h++)
            #pragma unroll
            for (int i = 0; i < 8; i++) {
                int k = h * 32 + kmap(kg, i);
                b1f[ct][h][i] = f2bf(W1[k * 64 + ct * 16 + r16]);
            }
    float bj1[4];
    #pragma unroll
    for (int ct = 0; ct < 4; ct++) bj1[ct] = b1v[ct * 16 + r16];

    float lsum[4] = {0.f, 0.f, 0.f, 0.f}, lsq[4] = {0.f, 0.f, 0.f, 0.f};

    for (int tile = blockIdx.x * 4 + wv; tile < XFT; tile += XF_GRID * 4) {
        int rbase = tile * 16;
        int arow = rbase + r16;
        // GEMM1: z2 row frag (K=32), hi/lo
        float4 v0 = *(const float4*)&z2[(size_t)arow * 32 + kg * 4];
        float4 v1 = *(const float4*)&z2[(size_t)arow * 32 + 16 + kg * 4];
        bf16x8 ah, al;
        split8(v0, v1, ah, al);
        f32x4 acc[4];
        #pragma unroll
        for (int ct = 0; ct < 4; ct++) { acc[ct][0] = 0.f; acc[ct][1] = 0.f; acc[ct][2] = 0.f; acc[ct][3] = 0.f; }
        #pragma unroll
        for (int ct = 0; ct < 4; ct++) {
            acc[ct] = __builtin_amdgcn_mfma_f32_16x16x32_bf16(ah, bh[ct], acc[ct], 0, 0, 0);
            acc[ct] = __builtin_amdgcn_mfma_f32_16x16x32_bf16(al, bh[ct], acc[ct], 0, 0, 0);
            acc[ct] = __builtin_amdgcn_mfma_f32_16x16x32_bf16(ah, blo[ct], acc[ct], 0, 0, 0);
        }
        // z = tanh(...): write global + per-wave LDS
        #pragma unroll
        for (int ct = 0; ct < 4; ct++)
            #pragma unroll
            for (int i = 0; i < 4; i++) {
                float zv = tanhf(acc[ct][i] + bjl[ct]);
                z[(size_t)(rbase + kg * 4 + i) * 64 + ct * 16 + r16] = zv;
                myz[(kg * 4 + i) * 68 + ct * 16 + r16] = zv;
            }
        // GEMM2: A frags from LDS (same wave; compiler inserts lgkmcnt)
        bf16x8 af[2];
        #pragma unroll
        for (int h = 0; h < 2; h++) {
            float4 u0 = *(const float4*)&myz[r16 * 68 + h * 32 + kg * 4];
            float4 u1 = *(const float4*)&myz[r16 * 68 + h * 32 + 16 + kg * 4];
            af[h][0] = f2bf(u0.x); af[h][1] = f2bf(u0.y);
            af[h][2] = f2bf(u0.z); af[h][3] = f2bf(u0.w);
            af[h][4] = f2bf(u1.x); af[h][5] = f2bf(u1.y);
            af[h][6] = f2bf(u1.z); af[h][7] = f2bf(u1.w);
        }
        f32x4 acc2[4];
        #pragma unroll
        for (int ct = 0; ct < 4; ct++) { acc2[ct][0] = 0.f; acc2[ct][1] = 0.f; acc2[ct][2] = 0.f; acc2[ct][3] = 0.f; }
        #pragma unroll
        for (int h = 0; h < 2; h++)
            #pragma unroll
            for (int ct = 0; ct < 4; ct++)
                acc2[ct] = __builtin_amdgcn_mfma_f32_16x16x32_bf16(af[h], b1f[ct][h], acc2[ct], 0, 0, 0);
        #pragma unroll
        for (int ct = 0; ct < 4; ct++)
            #pragma unroll
            for (int i = 0; i < 4; i++) {
                float t = acc2[ct][i] + bj1[ct];
                t1[(size_t)(rbase + kg * 4 + i) * 64 + ct * 16 + r16] = t;
                lsum[ct] += t; lsq[ct] += t * t;
            }
    }

    __syncthreads();
    #pragma unroll
    for (int ct = 0; ct < 4; ct++) {
        atomicAdd(&scol[ct * 16 + r16], lsum[ct]);
        atomicAdd(&ssq[ct * 16 + r16], lsq[ct]);
    }
    __syncthreads();
    if (tid < 64) {
        fatomic(&colsum[tid], scol[tid]);
        fatomic(&colsq[tid], ssq[tid]);
    }
}

// ---- MFMA MLP2, persistent; BN coefficients computed inline from stats ----
__global__ __launch_bounds__(256) __attribute__((amdgpu_waves_per_eu(2, 4)))
void k_mlp(const float* __restrict__ in,
           const float* __restrict__ csIn,   // colsum of in
           const float* __restrict__ cqIn,   // colsq of in
           const float* __restrict__ g,
           const float* __restrict__ beta,
           const float* __restrict__ W,
           const float* __restrict__ b,
           float* __restrict__ out,
           float* __restrict__ colsum,
           float* __restrict__ colsq) {
    __shared__ float scol[64], ssq[64];
    int tid = threadIdx.x;
    if (tid < 64) { scol[tid] = 0.f; ssq[tid] = 0.f; }
    int wv = tid >> 6;
    int l = tid & 63;
    int r16 = l & 15, kg = l >> 4;
    const float inv = 1.f / NN;

    bf16x8 bf[4][2];
    #pragma unroll
    for (int ct = 0; ct < 4; ct++)
        #pragma unroll
        for (int h = 0; h < 2; h++)
            #pragma unroll
            for (int i = 0; i < 8; i++) {
                int k = h * 32 + kmap(kg, i);
                bf[ct][h][i] = f2bf(W[k * 64 + ct * 16 + r16]);
            }
    float bj[4];
    #pragma unroll
    for (int ct = 0; ct < 4; ct++) bj[ct] = b[ct * 16 + r16];

    // inline BN coefficients for this thread's A-fragment k positions
    float av0[2][4], cv0[2][4], av1[2][4], cv1[2][4];
    #pragma unroll
    for (int h = 0; h < 2; h++)
        #pragma unroll
        for (int i = 0; i < 4; i++) {
            int k0 = h * 32 + kg * 4 + i;
            float m = csIn[k0] * inv;
            float vv = cqIn[k0] * inv - m * m;
            float a = g[k0] * rsqrtf(vv + EPSF);
            av0[h][i] = a; cv0[h][i] = beta[k0] - m * a;
            int k1 = k0 + 16;
            m = csIn[k1] * inv;
            vv = cqIn[k1] * inv - m * m;
            a = g[k1] * rsqrtf(vv + EPSF);
            av1[h][i] = a; cv1[h][i] = beta[k1] - m * a;
        }

    float lsum[4] = {0.f, 0.f, 0.f, 0.f}, lsq[4] = {0.f, 0.f, 0.f, 0.f};

    for (int tile = blockIdx.x; tile < GTILES; tile += MLP_GRID) {
        int base = tile * 64;
        int arow = base + wv * 16 + r16;
        bool rv = arow < NN;
        bf16x8 af[2];
        #pragma unroll
        for (int h = 0; h < 2; h++) {
            int k0 = h * 32 + kg * 4;
            int k1 = h * 32 + 16 + kg * 4;
            float4 v0 = rv ? *(const float4*)&in[(size_t)arow * 64 + k0]
                           : make_float4(0.f, 0.f, 0.f, 0.f);
            float4 v1 = rv ? *(const float4*)&in[(size_t)arow * 64 + k1]
                           : make_float4(0.f, 0.f, 0.f, 0.f);
            v0.x = fmaxf(v0.x * av0[h][0] + cv0[h][0], 0.f);
            v0.y = fmaxf(v0.y * av0[h][1] + cv0[h][1], 0.f);
            v0.z = fmaxf(v0.z * av0[h][2] + cv0[h][2], 0.f);
            v0.w = fmaxf(v0.w * av0[h][3] + cv0[h][3], 0.f);
            v1.x = fmaxf(v1.x * av1[h][0] + cv1[h][0], 0.f);
            v1.y = fmaxf(v1.y * av1[h][1] + cv1[h][1], 0.f);
            v1.z = fmaxf(v1.z * av1[h][2] + cv1[h][2], 0.f);
            v1.w = fmaxf(v1.w * av1[h][3] + cv1[h][3], 0.f);
            af[h][0] = f2bf(v0.x); af[h][1] = f2bf(v0.y);
            af[h][2] = f2bf(v0.z); af[h][3] = f2bf(v0.w);
            af[h][4] = f2bf(v1.x); af[h][5] = f2bf(v1.y);
            af[h][6] = f2bf(v1.z); af[h][7] = f2bf(v1.w);
        }

        f32x4 acc[4];
        #pragma unroll
        for (int ct = 0; ct < 4; ct++) { acc[ct][0] = 0.f; acc[ct][1] = 0.f; acc[ct][2] = 0.f; acc[ct][3] = 0.f; }
        #pragma unroll
        for (int h = 0; h < 2; h++)
            #pragma unroll
            for (int ct = 0; ct < 4; ct++)
                acc[ct] = __builtin_amdgcn_mfma_f32_16x16x32_bf16(af[h], bf[ct][h], acc[ct], 0, 0, 0);

        #pragma unroll
        for (int ct = 0; ct < 4; ct++) {
            int col = ct * 16 + r16;
            #pragma unroll
            for (int i = 0; i < 4; i++) {
                int orow = base + wv * 16 + kg * 4 + i;
                if (orow < NN) {
                    float s = acc[ct][i] + bj[ct];
                    out[(size_t)orow * 64 + col] = s;
                    lsum[ct] += s; lsq[ct] += s * s;
                }
            }
        }
    }

    __syncthreads();
    #pragma unroll
    for (int ct = 0; ct < 4; ct++) {
        atomicAdd(&scol[ct * 16 + r16], lsum[ct]);
        atomicAdd(&ssq[ct * 16 + r16], lsq[ct]);
    }
    __syncthreads();
    if (tid < 64) {
        fatomic(&colsum[tid], scol[tid]);
        fatomic(&colsq[tid], ssq[tid]);
    }
}

// ---- prob = sigmoid(relu(t2*a2+c2) @ m3_W + m3_b); BN coeffs inline ----
__global__ __launch_bounds__(256) void k_mlp3(const float* __restrict__ t2,
                                              const float* __restrict__ cs,
                                              const float* __restrict__ cq,
                                              const float* __restrict__ g,
                                              const float* __restrict__ beta,
                                              const float* __restrict__ W3,
                                              const float* __restrict__ b3,
                                              float* __restrict__ prob) {
    int j = threadIdx.x & 63;
    int r = threadIdx.x >> 6;
    const float inv = 1.f / NN;
    float m = cs[j] * inv;
    float vv = cq[j] * inv - m * m;
    float aj = g[j] * rsqrtf(vv + EPSF);
    float cj = beta[j] - m * aj;
    float wj = W3[j], bb = b3[0];
    for (int n = blockIdx.x * 4 + r; n < NN; n += 2048 * 4) {
        float h = fmaxf(t2[(size_t)n * 64 + j] * aj + cj, 0.f) * wj;
        #pragma unroll
        for (int off = 32; off > 0; off >>= 1) h += __shfl_xor(h, off, 64);
        if (j == 0) prob[n] = 1.f / (1.f + expf(-(h + bb)));
    }
}

extern "C" void kernel_launch(void* const* d_in, const int* in_sizes, int n_in,
                              void* d_out, int out_size, void* d_ws, size_t ws_size,
                              hipStream_t stream) {
    const float* init_emb = (const float*)d_in[0];
    const int* pe = (const int*)d_in[1];
    const int* ne = (const int*)d_in[2];
    const float* c1_Wp = (const float*)d_in[3];  const float* c1_bp = (const float*)d_in[4];
    const float* c1_Wn = (const float*)d_in[5];  const float* c1_bn = (const float*)d_in[6];
    const float* c1_Ws = (const float*)d_in[7];  const float* c1_bs = (const float*)d_in[8];
    const float* c2_Wp = (const float*)d_in[9];  const float* c2_bp = (const float*)d_in[10];
    const float* c2_Wn = (const float*)d_in[11]; const float* c2_bn = (const float*)d_in[12];
    const float* c2_Ws = (const float*)d_in[13]; const float* c2_bs = (const float*)d_in[14];
    const float* w_W = (const float*)d_in[15];   const float* w_b = (const float*)d_in[16];
    const float* m1_W = (const float*)d_in[17];  const float* m1_b = (const float*)d_in[18];
    const float* g1 = (const float*)d_in[19];    const float* b1 = (const float*)d_in[20];
    const float* m2_W = (const float*)d_in[21];  const float* m2_b = (const float*)d_in[22];
    const float* g2 = (const float*)d_in[23];    const float* b2 = (const float*)d_in[24];
    const float* m3_W = (const float*)d_in[25];  const float* m3_b = (const float*)d_in[26];

    // ---- workspace arena ----
    size_t off = 0;
    auto alloc = [&](size_t bytes) -> void* {
        void* r = (char*)d_ws + off;
        off += (bytes + 255) & ~(size_t)255;
        return r;
    };
    // zero region (front): only BN stat accumulators
    float* sums = (float*)alloc(256 * 4);               // colsum1, colsq1, colsum2, colsq2
    size_t zero_bytes = off;
    // CSR-build region (dead after second k_pull; t2 aliases it later)
    size_t csr_region = off;
    int*   hist = (int*)alloc((size_t)NBUK2 * NBLK * 4);        // 800KB
    int*   soff = (int*)alloc((size_t)NBUK2 * NBLK * 4);        // 800KB
    int*   part = (int*)alloc((size_t)1024 * 4);
    unsigned* staging = (unsigned*)alloc((size_t)2 * EE * 8);   // 16MB reserved (8MB used, keeps t2 alias valid)
    int*   csrAll = (int*)alloc((size_t)2 * EE * 4);            // 8MB
    // persistent
    int*   rpP  = (int*)alloc((size_t)(NN + 1) * 4);
    int*   rpN  = (int*)alloc((size_t)(NN + 1) * 4);
    float* R1   = (float*)alloc((size_t)NN * 96 * 4);   // {xp,xn,xs} layer1 -> layer2 -> t1
    float* z1   = (float*)alloc((size_t)NN * 32 * 4);
    float* z2   = (float*)alloc((size_t)NN * 32 * 4);

    int* csrP = csrAll;
    int* csrN = csrAll + (size_t)EE;
    float* xp = R1;
    float* xn = R1 + (size_t)NN * 32;
    float* xs = R1 + (size_t)NN * 64;
    float* t1 = R1;                                     // dead xp/xn region after wlin_mlp1
    float* t2 = (float*)((char*)d_ws + csr_region);     // aliases CSR-build scratch (25.6MB fits)

    float* z_out = (float*)d_out;                       // [N,64]
    float* prob  = (float*)d_out + (size_t)NN * 64;     // [N,1]

    hipMemsetAsync(d_ws, 0, zero_bytes, stream);

    // ---- CSR build: hist -> scan -> bin scatter -> per-bucket local build ----
    k_hist<<<NBLK, 256, 0, stream>>>(pe, ne, hist);
    k_gscan1<<<GSB, 256, 0, stream>>>(hist, soff, part);
    k_gscan2<<<1, 1024, 0, stream>>>(part);
    k_gscan3<<<GSB, 256, 0, stream>>>(part, soff);
    k_binscatter<<<NBLK, 256, 0, stream>>>(pe, ne, soff, staging);
    k_local<<<NBUK2, 256, 0, stream>>>(staging, soff, rpP, rpN, csrAll);

    // layer 1
    k_xf1<<<XF_GRID, 192, 0, stream>>>(init_emb, c1_Wp, c1_Wn, c1_Ws, xp, xn, xs);
    k_pull<<<2048, 256, 0, stream>>>(xp, xn, xs, rpP, csrP, rpN, csrN, c1_bp, c1_bn, c1_bs, z1);
    // layer 2
    k_xf2<<<XF_GRID, 192, 0, stream>>>(z1, c2_Wp, c2_Wn, c2_Ws, xp, xn, xs);
    k_pull<<<2048, 256, 0, stream>>>(xp, xn, xs, rpP, csrP, rpN, csrN, c2_bp, c2_bn, c2_bs, z2);
    // readout
    k_wlin_mlp1<<<XF_GRID, 256, 0, stream>>>(z2, w_W, w_b, m1_W, m1_b, z_out, t1, sums + 0, sums + 64);
    k_mlp<<<MLP_GRID, 256, 0, stream>>>(t1, sums + 0, sums + 64, g1, b1, m2_W, m2_b, t2, sums + 128, sums + 192);
    k_mlp3<<<2048, 256, 0, stream>>>(t2, sums + 128, sums + 192, g2, b2, m3_W, m3_b, prob);
}